// Round 4
// baseline (1472.145 us; speedup 1.0000x reference)
//
#include <hip/hip_runtime.h>
#include <hip/hip_bf16.h>

// Problem constants (from reference)
constexpr int NN = 90000;   // total nodes
constexpr int NP = 60000;   // paper nodes
constexpr int NM = 30000;   // mesh nodes
constexpr int ET = 2000000; // train edges
constexpr int ED = 400000;  // decode edges (each of pos/neg)

// ---------------------------------------------------------------------------
// Detect whether int arrays are int64 or int32 (verified int32 on this harness;
// detector kept as zero-cost insurance). Under int64 (LE, values < 2^31), odd
// int32 words are all 0; under int32 they are uniform indices in [0, 90000).
__global__ void detect_kernel(const int* __restrict__ tei, int* __restrict__ flag) {
    if (blockIdx.x == 0 && threadIdx.x == 0) {
        int allzero = 1;
        for (int i = 0; i < 16; i++)
            if (tei[2 * i + 1] != 0) allzero = 0;
        flag[0] = allzero; // 1 => int64 => index shift 1
    }
}

// ---------------------------------------------------------------------------
// Degree count per (relation, dst)
__global__ void count_deg_kernel(const int* __restrict__ ei, const int* __restrict__ et,
                                 int* __restrict__ cnt, const int* __restrict__ dflag) {
    int e = blockIdx.x * blockDim.x + threadIdx.x;
    if (e < ET) {
        int sft = dflag[0];
        int d = ei[(size_t)(ET + e) << sft];
        int r = et[(size_t)e << sft];
        atomicAdd(&cnt[r * NN + d], 1);
    }
}

__global__ void inv_kernel(const int* __restrict__ cnt, float* __restrict__ inv) {
    int i = blockIdx.x * blockDim.x + threadIdx.x;
    if (i < 2 * NN) {
        int c = cnt[i];
        inv[i] = 1.0f / (float)(c > 1 ? c : 1);
    }
}

// ---------------------------------------------------------------------------
// Input embed: out[n] = X[n] (128, fp32) @ W (128x16, fp32) + b
__global__ void embed_kernel(const float* __restrict__ X, int rows,
                             const float* __restrict__ W,
                             const float* __restrict__ b,
                             float* __restrict__ out) {
    __shared__ float Wl[128 * 16];
    __shared__ float bl[16];
    for (int i = threadIdx.x; i < 128 * 16; i += blockDim.x) Wl[i] = W[i];
    if (threadIdx.x < 16) bl[threadIdx.x] = b[threadIdx.x];
    __syncthreads();
    int n = blockIdx.x * blockDim.x + threadIdx.x;
    if (n >= rows) return;
    float acc[16];
#pragma unroll
    for (int j = 0; j < 16; j++) acc[j] = bl[j];
    const float4* row = (const float4*)(X + (size_t)n * 128);
    for (int k4 = 0; k4 < 32; k4++) {
        float4 xv = row[k4];
        int k = k4 * 4;
#pragma unroll
        for (int j = 0; j < 16; j++) {
            float a = acc[j];
            a = fmaf(xv.x, Wl[(k + 0) * 16 + j], a);
            a = fmaf(xv.y, Wl[(k + 1) * 16 + j], a);
            a = fmaf(xv.z, Wl[(k + 2) * 16 + j], a);
            a = fmaf(xv.w, Wl[(k + 3) * 16 + j], a);
            acc[j] = a;
        }
    }
    float* o = out + (size_t)n * 16;
#pragma unroll
    for (int j = 0; j < 16; j++) o[j] = acc[j];
}

// ---------------------------------------------------------------------------
// Combine bases with comp into per-relation W, plus copies of root/bias.
// Wbuf layout: [W0 (sz) | W1 (sz) | root (sz) | bias (dout)],  sz = din*dout
__global__ void prep_weights_kernel(const float* __restrict__ bases,
                                    const float* __restrict__ comp,
                                    const float* __restrict__ root,
                                    const float* __restrict__ bias,
                                    float* __restrict__ Wbuf, int din, int dout) {
    int sz = din * dout;
    int i = blockIdx.x * blockDim.x + threadIdx.x;
    if (i < sz) {
        float b0 = bases[i];
        float b1 = bases[sz + i];
        float b2 = bases[2 * sz + i];
        float b3 = bases[3 * sz + i];
        for (int r = 0; r < 2; r++) {
            Wbuf[r * sz + i] = comp[r * 4 + 0] * b0 + comp[r * 4 + 1] * b1 +
                               comp[r * 4 + 2] * b2 + comp[r * 4 + 3] * b3;
        }
        Wbuf[2 * sz + i] = root[i];
    }
    if (i < dout) Wbuf[3 * sz + i] = bias[i];
}

// ---------------------------------------------------------------------------
// Node transform: out = relu?(x) @ root + bias ; h0 = relu?(x) @ W0 ; h1 = relu?(x) @ W1
__global__ void transform_kernel(const float* __restrict__ x, float* __restrict__ out,
                                 float* __restrict__ h0, float* __restrict__ h1,
                                 const float* __restrict__ Wbuf, int din, int dout,
                                 int relu) {
    __shared__ float Wl[3 * 1024 + 32];
    int sz = din * dout;
    int tot = 3 * sz + dout;
    for (int i = threadIdx.x; i < tot; i += blockDim.x) Wl[i] = Wbuf[i];
    __syncthreads();
    int n = blockIdx.x * blockDim.x + threadIdx.x;
    if (n >= NN) return;
    float xr[32];
    const float* xp = x + (size_t)n * din;
    for (int k = 0; k < din; k++) {
        float v = xp[k];
        xr[k] = relu ? fmaxf(v, 0.0f) : v;
    }
    const float* W0 = Wl;
    const float* W1 = Wl + sz;
    const float* R  = Wl + 2 * sz;
    const float* B  = Wl + 3 * sz;
    float* o  = out + (size_t)n * dout;
    float* p0 = h0 + (size_t)n * dout;
    float* p1 = h1 + (size_t)n * dout;
    for (int j = 0; j < dout; j++) {
        float a0 = 0.0f, a1 = 0.0f, ar = B[j];
        for (int k = 0; k < din; k++) {
            float xv = xr[k];
            a0 = fmaf(xv, W0[k * dout + j], a0);
            a1 = fmaf(xv, W1[k * dout + j], a1);
            ar = fmaf(xv, R[k * dout + j], ar);
        }
        p0[j] = a0;
        p1[j] = a1;
        o[j]  = ar;
    }
}

// ---------------------------------------------------------------------------
// Edge scatter: out[dst][j] += h_{r}[src][j] * inv_r[dst]
// One thread per (edge, j); dout = 1<<shift.
__global__ void scatter_kernel(const int* __restrict__ ei, const int* __restrict__ et,
                               const float* __restrict__ h0, const float* __restrict__ h1,
                               const float* __restrict__ inv, float* __restrict__ out,
                               int shift, const int* __restrict__ dflag) {
    long t = (long)blockIdx.x * blockDim.x + threadIdx.x;
    int e = (int)(t >> shift);
    if (e >= ET) return;
    int sft = dflag[0];
    int j = (int)t & ((1 << shift) - 1);
    int s = ei[(size_t)e << sft];
    int d = ei[(size_t)(ET + e) << sft];
    int r = et[(size_t)e << sft];
    const float* h = r ? h1 : h0;
    float v = h[((size_t)s << shift) + j] * inv[r * NN + d];
    atomicAdd(&out[((size_t)d << shift) + j], v);
}

// ---------------------------------------------------------------------------
// Decode prep: y0 = z @ Wd0 + bd0 ; y1 = z @ Wd1 + bd1   (all 16-dim)
__global__ void decode_prep_kernel(const float* __restrict__ z,
                                   const float* __restrict__ Wd0,
                                   const float* __restrict__ bd0,
                                   const float* __restrict__ Wd1,
                                   const float* __restrict__ bd1,
                                   float* __restrict__ y0, float* __restrict__ y1) {
    __shared__ float W0l[256], W1l[256], B0[16], B1[16];
    for (int i = threadIdx.x; i < 256; i += blockDim.x) {
        W0l[i] = Wd0[i];
        W1l[i] = Wd1[i];
    }
    if (threadIdx.x < 16) {
        B0[threadIdx.x] = bd0[threadIdx.x];
        B1[threadIdx.x] = bd1[threadIdx.x];
    }
    __syncthreads();
    int n = blockIdx.x * blockDim.x + threadIdx.x;
    if (n >= NN) return;
    float zr[16];
    const float* zp = z + (size_t)n * 16;
#pragma unroll
    for (int k = 0; k < 16; k++) zr[k] = zp[k];
    float* o0 = y0 + (size_t)n * 16;
    float* o1 = y1 + (size_t)n * 16;
    for (int j = 0; j < 16; j++) {
        float a0 = B0[j], a1 = B1[j];
#pragma unroll
        for (int k = 0; k < 16; k++) {
            a0 = fmaf(zr[k], W0l[k * 16 + j], a0);
            a1 = fmaf(zr[k], W1l[k * 16 + j], a1);
        }
        o0[j] = a0;
        o1[j] = a1;
    }
}

// ---------------------------------------------------------------------------
// Decode: out[i] = dot( y_{et}[src], z[dst] )   (pos edges then neg edges)
// Output dtype: fp32 (reference returns float32).
__global__ void decode_kernel(const float* __restrict__ y0, const float* __restrict__ y1,
                              const float* __restrict__ z,
                              const int* __restrict__ pei, const int* __restrict__ pet,
                              const int* __restrict__ nei, const int* __restrict__ net_,
                              float* __restrict__ out,
                              const int* __restrict__ dflag) {
    int i = blockIdx.x * blockDim.x + threadIdx.x;
    if (i >= 2 * ED) return;
    int sft = dflag[0];
    const int* ei;
    const int* et;
    int e;
    if (i < ED) { ei = pei; et = pet; e = i; }
    else        { ei = nei; et = net_; e = i - ED; }
    int s = ei[(size_t)e << sft];
    int d = ei[(size_t)(ED + e) << sft];
    int r = et[(size_t)e << sft];
    const float4* yv = (const float4*)((r ? y1 : y0) + ((size_t)s << 4));
    const float4* zv = (const float4*)(z + ((size_t)d << 4));
    float acc = 0.0f;
#pragma unroll
    for (int q = 0; q < 4; q++) {
        float4 a = yv[q];
        float4 b = zv[q];
        acc += a.x * b.x + a.y * b.y + a.z * b.z + a.w * b.w;
    }
    out[i] = acc;
}

// ---------------------------------------------------------------------------
extern "C" void kernel_launch(void* const* d_in, const int* in_sizes, int n_in,
                              void* d_out, int out_size, void* d_ws, size_t ws_size,
                              hipStream_t stream) {
    const float* x_paper = (const float*)d_in[0];
    const float* x_mesh  = (const float*)d_in[1];
    const int* tei  = (const int*)d_in[2];
    const int* tet  = (const int*)d_in[3];
    const int* pei  = (const int*)d_in[4];
    const int* pet  = (const int*)d_in[5];
    const int* nei  = (const int*)d_in[6];
    const int* net_ = (const int*)d_in[7];
    const float* Wp  = (const float*)d_in[8];
    const float* bp  = (const float*)d_in[9];
    const float* Wm  = (const float*)d_in[10];
    const float* bm  = (const float*)d_in[11];
    const float* Wd0 = (const float*)d_in[12];
    const float* bd0 = (const float*)d_in[13];
    const float* Wd1 = (const float*)d_in[14];
    const float* bd1 = (const float*)d_in[15];
    const float* basesL[4] = {(const float*)d_in[16], (const float*)d_in[20],
                              (const float*)d_in[24], (const float*)d_in[28]};
    const float* compL[4]  = {(const float*)d_in[17], (const float*)d_in[21],
                              (const float*)d_in[25], (const float*)d_in[29]};
    const float* rootL[4]  = {(const float*)d_in[18], (const float*)d_in[22],
                              (const float*)d_in[26], (const float*)d_in[30]};
    const float* biasL[4]  = {(const float*)d_in[19], (const float*)d_in[23],
                              (const float*)d_in[27], (const float*)d_in[31]};

    // Workspace carve-up (fp32 elements) — ~47.6 MB total
    float* ws = (float*)d_ws;
    size_t o = 0;
    float* bufA = ws + o; o += (size_t)NN * 32;
    float* bufB = ws + o; o += (size_t)NN * 32;
    float* h0   = ws + o; o += (size_t)NN * 32;
    float* h1   = ws + o; o += (size_t)NN * 32;
    float* inv  = ws + o; o += (size_t)2 * NN;
    int*   cnt  = (int*)(ws + o); o += (size_t)2 * NN;
    float* Wbuf = ws + o; o += 4096;
    int*   dflag = (int*)(ws + o); o += 16;

    // 0. Detect int32 vs int64 edge arrays (device-side; graph-capture safe)
    detect_kernel<<<1, 64, 0, stream>>>(tei, dflag);

    // 1. Per-relation in-degree (computed once, reused by all 4 layers)
    hipMemsetAsync(cnt, 0, (size_t)2 * NN * sizeof(int), stream);
    count_deg_kernel<<<(ET + 255) / 256, 256, 0, stream>>>(tei, tet, cnt, dflag);
    inv_kernel<<<(2 * NN + 255) / 256, 256, 0, stream>>>(cnt, inv);

    // 2. Input embed -> bufA [NN,16]
    embed_kernel<<<(NP + 255) / 256, 256, 0, stream>>>(x_paper, NP, Wp, bp, bufA);
    embed_kernel<<<(NM + 255) / 256, 256, 0, stream>>>(x_mesh, NM, Wm, bm,
                                                       bufA + (size_t)NP * 16);

    // 3. Four RGCN layers (ping-pong bufA/bufB)
    int dims[5] = {16, 32, 32, 32, 16};
    float* xin = bufA;
    float* xout = bufB;
    for (int l = 0; l < 4; l++) {
        int din = dims[l], dout = dims[l + 1];
        int sz = din * dout;
        prep_weights_kernel<<<(sz + 255) / 256, 256, 0, stream>>>(
            basesL[l], compL[l], rootL[l], biasL[l], Wbuf, din, dout);
        transform_kernel<<<(NN + 255) / 256, 256, 0, stream>>>(
            xin, xout, h0, h1, Wbuf, din, dout, l > 0 ? 1 : 0);
        int shift = (dout == 32) ? 5 : 4;
        long total = (long)ET << shift;
        scatter_kernel<<<(int)((total + 255) / 256), 256, 0, stream>>>(
            tei, tet, h0, h1, inv, xout, shift, dflag);
        float* t = xin; xin = xout; xout = t;
    }
    // z = bufA [NN,16]

    // 4. Decode
    decode_prep_kernel<<<(NN + 255) / 256, 256, 0, stream>>>(xin, Wd0, bd0, Wd1, bd1,
                                                             h0, h1);
    decode_kernel<<<(2 * ED + 255) / 256, 256, 0, stream>>>(
        h0, h1, xin, pei, pet, nei, net_, (float*)d_out, dflag);
}

// Round 5
// 1281.509 us; speedup vs baseline: 1.1488x; 1.1488x over previous
//
#include <hip/hip_runtime.h>
#include <hip/hip_bf16.h>

// Problem constants (from reference)
constexpr int NN = 90000;   // total nodes
constexpr int NP = 60000;   // paper nodes
constexpr int NM = 30000;   // mesh nodes
constexpr int ET = 2000000; // train edges
constexpr int ED = 400000;  // decode edges (each of pos/neg)
constexpr int TWO_NN = 2 * NN;
constexpr int SCAN_BLKS = (TWO_NN + 1023) / 1024; // 176

// ---------------------------------------------------------------------------
// Detect whether int arrays are int64 or int32 (verified int32 on this harness;
// kept as zero-cost insurance).
__global__ void detect_kernel(const int* __restrict__ tei, int* __restrict__ flag) {
    if (blockIdx.x == 0 && threadIdx.x == 0) {
        int allzero = 1;
        for (int i = 0; i < 16; i++)
            if (tei[2 * i + 1] != 0) allzero = 0;
        flag[0] = allzero; // 1 => int64 => index shift 1
    }
}

// ---------------------------------------------------------------------------
// Degree count per (relation, dst)
__global__ void count_deg_kernel(const int* __restrict__ ei, const int* __restrict__ et,
                                 int* __restrict__ cnt, const int* __restrict__ dflag) {
    int e = blockIdx.x * blockDim.x + threadIdx.x;
    if (e < ET) {
        int sft = dflag[0];
        int d = ei[(size_t)(ET + e) << sft];
        int r = et[(size_t)e << sft];
        atomicAdd(&cnt[r * NN + d], 1);
    }
}

__global__ void inv_kernel(const int* __restrict__ cnt, float* __restrict__ inv) {
    int i = blockIdx.x * blockDim.x + threadIdx.x;
    if (i < TWO_NN) {
        int c = cnt[i];
        inv[i] = 1.0f / (float)(c > 1 ? c : 1);
    }
}

// ---------------------------------------------------------------------------
// CSR build: hierarchical exclusive scan of cnt[0..2NN) -> off, cursor
// Step 1: per-block (1024 elems) totals
__global__ void scan_block_kernel(const int* __restrict__ cnt, int* __restrict__ bsum) {
    __shared__ int lds[256];
    int base = blockIdx.x * 1024;
    int t = threadIdx.x;
    int s = 0;
#pragma unroll
    for (int q = 0; q < 4; q++) {
        int i = base + t * 4 + q;
        s += (i < TWO_NN) ? cnt[i] : 0;
    }
    lds[t] = s;
    __syncthreads();
    for (int st = 128; st > 0; st >>= 1) {
        if (t < st) lds[t] += lds[t + st];
        __syncthreads();
    }
    if (t == 0) bsum[blockIdx.x] = lds[0];
}

// Step 2: exclusive scan of block sums (single block)
__global__ void scan_bsum_kernel(int* __restrict__ bsum, int nb) {
    __shared__ int lds[256];
    int t = threadIdx.x;
    lds[t] = (t < nb) ? bsum[t] : 0;
    __syncthreads();
    for (int st = 1; st < 256; st <<= 1) {
        int v = (t >= st) ? lds[t - st] : 0;
        __syncthreads();
        lds[t] += v;
        __syncthreads();
    }
    if (t < nb) bsum[t] = (t > 0) ? lds[t - 1] : 0;
}

// Step 3: per-element exclusive offsets (+ cursor copy)
__global__ void scan_final_kernel(const int* __restrict__ cnt, const int* __restrict__ bsum,
                                  int* __restrict__ off, int* __restrict__ cursor) {
    __shared__ int lds[256];
    int base = blockIdx.x * 1024;
    int t = threadIdx.x;
    int v[4];
    int s = 0;
#pragma unroll
    for (int q = 0; q < 4; q++) {
        int i = base + t * 4 + q;
        v[q] = (i < TWO_NN) ? cnt[i] : 0;
        s += v[q];
    }
    lds[t] = s;
    __syncthreads();
    for (int st = 1; st < 256; st <<= 1) {
        int u = (t >= st) ? lds[t - st] : 0;
        __syncthreads();
        lds[t] += u;
        __syncthreads();
    }
    int run = bsum[blockIdx.x] + lds[t] - s; // exclusive prefix for this thread
#pragma unroll
    for (int q = 0; q < 4; q++) {
        int i = base + t * 4 + q;
        if (i < TWO_NN) {
            off[i] = run;
            cursor[i] = run;
        }
        run += v[q];
    }
    if (blockIdx.x == 0 && t == 0) off[TWO_NN] = ET; // total
}

// Step 4: fill CSR source lists via atomic cursors
__global__ void csr_fill_kernel(const int* __restrict__ ei, const int* __restrict__ et,
                                int* __restrict__ cursor, int* __restrict__ csr,
                                const int* __restrict__ dflag) {
    int e = blockIdx.x * blockDim.x + threadIdx.x;
    if (e >= ET) return;
    int sft = dflag[0];
    int s = ei[(size_t)e << sft];
    int d = ei[(size_t)(ET + e) << sft];
    int r = et[(size_t)e << sft];
    int pos = atomicAdd(&cursor[r * NN + d], 1);
    csr[pos] = s;
}

// ---------------------------------------------------------------------------
// Input embed: out[n] = X[n] (128, fp32) @ W (128x16, fp32) + b
__global__ void embed_kernel(const float* __restrict__ X, int rows,
                             const float* __restrict__ W,
                             const float* __restrict__ b,
                             float* __restrict__ out) {
    __shared__ float Wl[128 * 16];
    __shared__ float bl[16];
    for (int i = threadIdx.x; i < 128 * 16; i += blockDim.x) Wl[i] = W[i];
    if (threadIdx.x < 16) bl[threadIdx.x] = b[threadIdx.x];
    __syncthreads();
    int n = blockIdx.x * blockDim.x + threadIdx.x;
    if (n >= rows) return;
    float acc[16];
#pragma unroll
    for (int j = 0; j < 16; j++) acc[j] = bl[j];
    const float4* row = (const float4*)(X + (size_t)n * 128);
    for (int k4 = 0; k4 < 32; k4++) {
        float4 xv = row[k4];
        int k = k4 * 4;
#pragma unroll
        for (int j = 0; j < 16; j++) {
            float a = acc[j];
            a = fmaf(xv.x, Wl[(k + 0) * 16 + j], a);
            a = fmaf(xv.y, Wl[(k + 1) * 16 + j], a);
            a = fmaf(xv.z, Wl[(k + 2) * 16 + j], a);
            a = fmaf(xv.w, Wl[(k + 3) * 16 + j], a);
            acc[j] = a;
        }
    }
    float* o = out + (size_t)n * 16;
#pragma unroll
    for (int j = 0; j < 16; j++) o[j] = acc[j];
}

// ---------------------------------------------------------------------------
// Combine bases with comp into per-relation W, plus copies of root/bias.
// Wbuf layout: [W0 (sz) | W1 (sz) | root (sz) | bias (dout)],  sz = din*dout
__global__ void prep_weights_kernel(const float* __restrict__ bases,
                                    const float* __restrict__ comp,
                                    const float* __restrict__ root,
                                    const float* __restrict__ bias,
                                    float* __restrict__ Wbuf, int din, int dout) {
    int sz = din * dout;
    int i = blockIdx.x * blockDim.x + threadIdx.x;
    if (i < sz) {
        float b0 = bases[i];
        float b1 = bases[sz + i];
        float b2 = bases[2 * sz + i];
        float b3 = bases[3 * sz + i];
        for (int r = 0; r < 2; r++) {
            Wbuf[r * sz + i] = comp[r * 4 + 0] * b0 + comp[r * 4 + 1] * b1 +
                               comp[r * 4 + 2] * b2 + comp[r * 4 + 3] * b3;
        }
        Wbuf[2 * sz + i] = root[i];
    }
    if (i < dout) Wbuf[3 * sz + i] = bias[i];
}

// ---------------------------------------------------------------------------
// Node transform: out = relu?(x) @ root + bias ; h0 = relu?(x) @ W0 ; h1 = relu?(x) @ W1
__global__ void transform_kernel(const float* __restrict__ x, float* __restrict__ out,
                                 float* __restrict__ h0, float* __restrict__ h1,
                                 const float* __restrict__ Wbuf, int din, int dout,
                                 int relu) {
    __shared__ float Wl[3 * 1024 + 32];
    int sz = din * dout;
    int tot = 3 * sz + dout;
    for (int i = threadIdx.x; i < tot; i += blockDim.x) Wl[i] = Wbuf[i];
    __syncthreads();
    int n = blockIdx.x * blockDim.x + threadIdx.x;
    if (n >= NN) return;
    float xr[32];
    const float* xp = x + (size_t)n * din;
    for (int k = 0; k < din; k++) {
        float v = xp[k];
        xr[k] = relu ? fmaxf(v, 0.0f) : v;
    }
    const float* W0 = Wl;
    const float* W1 = Wl + sz;
    const float* R  = Wl + 2 * sz;
    const float* B  = Wl + 3 * sz;
    float* o  = out + (size_t)n * dout;
    float* p0 = h0 + (size_t)n * dout;
    float* p1 = h1 + (size_t)n * dout;
    for (int j = 0; j < dout; j++) {
        float a0 = 0.0f, a1 = 0.0f, ar = B[j];
        for (int k = 0; k < din; k++) {
            float xv = xr[k];
            a0 = fmaf(xv, W0[k * dout + j], a0);
            a1 = fmaf(xv, W1[k * dout + j], a1);
            ar = fmaf(xv, R[k * dout + j], ar);
        }
        p0[j] = a0;
        p1[j] = a1;
        o[j]  = ar;
    }
}

// ---------------------------------------------------------------------------
// Pull-mode aggregation: (1<<shift) lanes per dst walk its CSR edge lists.
// out[dst][j] += (sum_{e in r0} h0[src][j]) * inv0[dst]
//             +  (sum_{e in r1} h1[src][j]) * inv1[dst]
// Non-atomic: each (dst, j) owned by exactly one thread.
__global__ void aggregate_kernel(const int* __restrict__ off, const int* __restrict__ csr,
                                 const float* __restrict__ h0, const float* __restrict__ h1,
                                 const float* __restrict__ inv, float* __restrict__ out,
                                 int shift) {
    int gid = blockIdx.x * blockDim.x + threadIdx.x;
    int d = gid >> shift;
    if (d >= NN) return;
    int j = gid & ((1 << shift) - 1);
    float acc0 = 0.0f, acc1 = 0.0f;
    int b0 = off[d], e0 = off[d + 1];
    for (int k = b0; k < e0; k++) {
        int s = csr[k];
        acc0 += h0[((size_t)s << shift) + j];
    }
    int b1 = off[NN + d], e1 = off[NN + d + 1];
    for (int k = b1; k < e1; k++) {
        int s = csr[k];
        acc1 += h1[((size_t)s << shift) + j];
    }
    out[((size_t)d << shift) + j] += acc0 * inv[d] + acc1 * inv[NN + d];
}

// ---------------------------------------------------------------------------
// Decode prep: y0 = z @ Wd0 + bd0 ; y1 = z @ Wd1 + bd1   (all 16-dim)
__global__ void decode_prep_kernel(const float* __restrict__ z,
                                   const float* __restrict__ Wd0,
                                   const float* __restrict__ bd0,
                                   const float* __restrict__ Wd1,
                                   const float* __restrict__ bd1,
                                   float* __restrict__ y0, float* __restrict__ y1) {
    __shared__ float W0l[256], W1l[256], B0[16], B1[16];
    for (int i = threadIdx.x; i < 256; i += blockDim.x) {
        W0l[i] = Wd0[i];
        W1l[i] = Wd1[i];
    }
    if (threadIdx.x < 16) {
        B0[threadIdx.x] = bd0[threadIdx.x];
        B1[threadIdx.x] = bd1[threadIdx.x];
    }
    __syncthreads();
    int n = blockIdx.x * blockDim.x + threadIdx.x;
    if (n >= NN) return;
    float zr[16];
    const float* zp = z + (size_t)n * 16;
#pragma unroll
    for (int k = 0; k < 16; k++) zr[k] = zp[k];
    float* o0 = y0 + (size_t)n * 16;
    float* o1 = y1 + (size_t)n * 16;
    for (int j = 0; j < 16; j++) {
        float a0 = B0[j], a1 = B1[j];
#pragma unroll
        for (int k = 0; k < 16; k++) {
            a0 = fmaf(zr[k], W0l[k * 16 + j], a0);
            a1 = fmaf(zr[k], W1l[k * 16 + j], a1);
        }
        o0[j] = a0;
        o1[j] = a1;
    }
}

// ---------------------------------------------------------------------------
// Decode: out[i] = dot( y_{et}[src], z[dst] )  — fp32 output
__global__ void decode_kernel(const float* __restrict__ y0, const float* __restrict__ y1,
                              const float* __restrict__ z,
                              const int* __restrict__ pei, const int* __restrict__ pet,
                              const int* __restrict__ nei, const int* __restrict__ net_,
                              float* __restrict__ out,
                              const int* __restrict__ dflag) {
    int i = blockIdx.x * blockDim.x + threadIdx.x;
    if (i >= 2 * ED) return;
    int sft = dflag[0];
    const int* ei;
    const int* et;
    int e;
    if (i < ED) { ei = pei; et = pet; e = i; }
    else        { ei = nei; et = net_; e = i - ED; }
    int s = ei[(size_t)e << sft];
    int d = ei[(size_t)(ED + e) << sft];
    int r = et[(size_t)e << sft];
    const float4* yv = (const float4*)((r ? y1 : y0) + ((size_t)s << 4));
    const float4* zv = (const float4*)(z + ((size_t)d << 4));
    float acc = 0.0f;
#pragma unroll
    for (int q = 0; q < 4; q++) {
        float4 a = yv[q];
        float4 b = zv[q];
        acc += a.x * b.x + a.y * b.y + a.z * b.z + a.w * b.w;
    }
    out[i] = acc;
}

// ---------------------------------------------------------------------------
extern "C" void kernel_launch(void* const* d_in, const int* in_sizes, int n_in,
                              void* d_out, int out_size, void* d_ws, size_t ws_size,
                              hipStream_t stream) {
    const float* x_paper = (const float*)d_in[0];
    const float* x_mesh  = (const float*)d_in[1];
    const int* tei  = (const int*)d_in[2];
    const int* tet  = (const int*)d_in[3];
    const int* pei  = (const int*)d_in[4];
    const int* pet  = (const int*)d_in[5];
    const int* nei  = (const int*)d_in[6];
    const int* net_ = (const int*)d_in[7];
    const float* Wp  = (const float*)d_in[8];
    const float* bp  = (const float*)d_in[9];
    const float* Wm  = (const float*)d_in[10];
    const float* bm  = (const float*)d_in[11];
    const float* Wd0 = (const float*)d_in[12];
    const float* bd0 = (const float*)d_in[13];
    const float* Wd1 = (const float*)d_in[14];
    const float* bd1 = (const float*)d_in[15];
    const float* basesL[4] = {(const float*)d_in[16], (const float*)d_in[20],
                              (const float*)d_in[24], (const float*)d_in[28]};
    const float* compL[4]  = {(const float*)d_in[17], (const float*)d_in[21],
                              (const float*)d_in[25], (const float*)d_in[29]};
    const float* rootL[4]  = {(const float*)d_in[18], (const float*)d_in[22],
                              (const float*)d_in[26], (const float*)d_in[30]};
    const float* biasL[4]  = {(const float*)d_in[19], (const float*)d_in[23],
                              (const float*)d_in[27], (const float*)d_in[31]};

    // Workspace carve-up (fp32/int32 elements) — ~58 MB total
    float* ws = (float*)d_ws;
    size_t o = 0;
    float* bufA = ws + o; o += (size_t)NN * 32;
    float* bufB = ws + o; o += (size_t)NN * 32;
    float* h0   = ws + o; o += (size_t)NN * 32;
    float* h1   = ws + o; o += (size_t)NN * 32;
    float* inv  = ws + o; o += (size_t)TWO_NN;
    int*   cnt    = (int*)(ws + o); o += (size_t)TWO_NN;
    int*   off    = (int*)(ws + o); o += (size_t)TWO_NN + 4;
    int*   cursor = (int*)(ws + o); o += (size_t)TWO_NN;
    int*   bsum   = (int*)(ws + o); o += 256;
    int*   csr    = (int*)(ws + o); o += (size_t)ET;
    float* Wbuf = ws + o; o += 4096;
    int*   dflag = (int*)(ws + o); o += 16;

    // 0. Dtype detect (verified int32; zero-cost insurance)
    detect_kernel<<<1, 64, 0, stream>>>(tei, dflag);

    // 1. Degree histogram + inverse (edge structure is layer-invariant)
    hipMemsetAsync(cnt, 0, (size_t)TWO_NN * sizeof(int), stream);
    count_deg_kernel<<<(ET + 255) / 256, 256, 0, stream>>>(tei, tet, cnt, dflag);
    inv_kernel<<<(TWO_NN + 255) / 256, 256, 0, stream>>>(cnt, inv);

    // 2. CSR build (once): scan cnt -> off/cursor, then fill src lists
    scan_block_kernel<<<SCAN_BLKS, 256, 0, stream>>>(cnt, bsum);
    scan_bsum_kernel<<<1, 256, 0, stream>>>(bsum, SCAN_BLKS);
    scan_final_kernel<<<SCAN_BLKS, 256, 0, stream>>>(cnt, bsum, off, cursor);
    csr_fill_kernel<<<(ET + 255) / 256, 256, 0, stream>>>(tei, tet, cursor, csr, dflag);

    // 3. Input embed -> bufA [NN,16]
    embed_kernel<<<(NP + 255) / 256, 256, 0, stream>>>(x_paper, NP, Wp, bp, bufA);
    embed_kernel<<<(NM + 255) / 256, 256, 0, stream>>>(x_mesh, NM, Wm, bm,
                                                       bufA + (size_t)NP * 16);

    // 4. Four RGCN layers (ping-pong bufA/bufB), pull-mode aggregation
    int dims[5] = {16, 32, 32, 32, 16};
    float* xin = bufA;
    float* xout = bufB;
    for (int l = 0; l < 4; l++) {
        int din = dims[l], dout = dims[l + 1];
        int sz = din * dout;
        prep_weights_kernel<<<(sz + 255) / 256, 256, 0, stream>>>(
            basesL[l], compL[l], rootL[l], biasL[l], Wbuf, din, dout);
        transform_kernel<<<(NN + 255) / 256, 256, 0, stream>>>(
            xin, xout, h0, h1, Wbuf, din, dout, l > 0 ? 1 : 0);
        int shift = (dout == 32) ? 5 : 4;
        long total = (long)NN << shift;
        aggregate_kernel<<<(int)((total + 255) / 256), 256, 0, stream>>>(
            off, csr, h0, h1, inv, xout, shift);
        float* t = xin; xin = xout; xout = t;
    }
    // z = xin [NN,16]

    // 5. Decode
    decode_prep_kernel<<<(NN + 255) / 256, 256, 0, stream>>>(xin, Wd0, bd0, Wd1, bd1,
                                                             h0, h1);
    decode_kernel<<<(2 * ED + 255) / 256, 256, 0, stream>>>(
        h0, h1, xin, pei, pet, nei, net_, (float*)d_out, dflag);
}

// Round 6
// 1204.673 us; speedup vs baseline: 1.2220x; 1.0638x over previous
//
#include <hip/hip_runtime.h>
#include <hip/hip_bf16.h>

// Problem constants (from reference)
constexpr int NN = 90000;   // total nodes
constexpr int NP = 60000;   // paper nodes
constexpr int NM = 30000;   // mesh nodes
constexpr int ET = 2000000; // train edges
constexpr int ED = 400000;  // decode edges (each of pos/neg)
constexpr int TWO_NN = 2 * NN;
constexpr int SCAN_BLKS = (TWO_NN + 1023) / 1024; // 176

// ---------------------------------------------------------------------------
// Detect whether int arrays are int64 or int32 (verified int32 on this harness;
// kept as zero-cost insurance).
__global__ void detect_kernel(const int* __restrict__ tei, int* __restrict__ flag) {
    if (blockIdx.x == 0 && threadIdx.x == 0) {
        int allzero = 1;
        for (int i = 0; i < 16; i++)
            if (tei[2 * i + 1] != 0) allzero = 0;
        flag[0] = allzero; // 1 => int64 => index shift 1
    }
}

// ---------------------------------------------------------------------------
// Degree count per (relation, dst)
__global__ void count_deg_kernel(const int* __restrict__ ei, const int* __restrict__ et,
                                 int* __restrict__ cnt, const int* __restrict__ dflag) {
    int e = blockIdx.x * blockDim.x + threadIdx.x;
    if (e < ET) {
        int sft = dflag[0];
        int d = ei[(size_t)(ET + e) << sft];
        int r = et[(size_t)e << sft];
        atomicAdd(&cnt[r * NN + d], 1);
    }
}

__global__ void inv_kernel(const int* __restrict__ cnt, float* __restrict__ inv) {
    int i = blockIdx.x * blockDim.x + threadIdx.x;
    if (i < TWO_NN) {
        int c = cnt[i];
        inv[i] = 1.0f / (float)(c > 1 ? c : 1);
    }
}

// ---------------------------------------------------------------------------
// CSR build: hierarchical exclusive scan of cnt[0..2NN) -> off, cursor
__global__ void scan_block_kernel(const int* __restrict__ cnt, int* __restrict__ bsum) {
    __shared__ int lds[256];
    int base = blockIdx.x * 1024;
    int t = threadIdx.x;
    int s = 0;
#pragma unroll
    for (int q = 0; q < 4; q++) {
        int i = base + t * 4 + q;
        s += (i < TWO_NN) ? cnt[i] : 0;
    }
    lds[t] = s;
    __syncthreads();
    for (int st = 128; st > 0; st >>= 1) {
        if (t < st) lds[t] += lds[t + st];
        __syncthreads();
    }
    if (t == 0) bsum[blockIdx.x] = lds[0];
}

__global__ void scan_bsum_kernel(int* __restrict__ bsum, int nb) {
    __shared__ int lds[256];
    int t = threadIdx.x;
    lds[t] = (t < nb) ? bsum[t] : 0;
    __syncthreads();
    for (int st = 1; st < 256; st <<= 1) {
        int v = (t >= st) ? lds[t - st] : 0;
        __syncthreads();
        lds[t] += v;
        __syncthreads();
    }
    if (t < nb) bsum[t] = (t > 0) ? lds[t - 1] : 0;
}

__global__ void scan_final_kernel(const int* __restrict__ cnt, const int* __restrict__ bsum,
                                  int* __restrict__ off, int* __restrict__ cursor) {
    __shared__ int lds[256];
    int base = blockIdx.x * 1024;
    int t = threadIdx.x;
    int v[4];
    int s = 0;
#pragma unroll
    for (int q = 0; q < 4; q++) {
        int i = base + t * 4 + q;
        v[q] = (i < TWO_NN) ? cnt[i] : 0;
        s += v[q];
    }
    lds[t] = s;
    __syncthreads();
    for (int st = 1; st < 256; st <<= 1) {
        int u = (t >= st) ? lds[t - st] : 0;
        __syncthreads();
        lds[t] += u;
        __syncthreads();
    }
    int run = bsum[blockIdx.x] + lds[t] - s;
#pragma unroll
    for (int q = 0; q < 4; q++) {
        int i = base + t * 4 + q;
        if (i < TWO_NN) {
            off[i] = run;
            cursor[i] = run;
        }
        run += v[q];
    }
    if (blockIdx.x == 0 && t == 0) off[TWO_NN] = ET;
}

// Fill CSR src lists. atomicExch for the data store: memory-side 4B-granular
// write, avoids the 17x dirty-line amplification of a plain scattered store
// (R5 counters: WRITE_SIZE 139MB for an 8MB array).
__global__ void csr_fill_kernel(const int* __restrict__ ei, const int* __restrict__ et,
                                int* __restrict__ cursor, int* __restrict__ csr,
                                const int* __restrict__ dflag) {
    int e = blockIdx.x * blockDim.x + threadIdx.x;
    if (e >= ET) return;
    int sft = dflag[0];
    int s = ei[(size_t)e << sft];
    int d = ei[(size_t)(ET + e) << sft];
    int r = et[(size_t)e << sft];
    int pos = atomicAdd(&cursor[r * NN + d], 1);
    atomicExch(&csr[pos], s);
}

// ---------------------------------------------------------------------------
// Input embed: out[n] = X[n] (128, fp32) @ W (128x16, fp32) + b
__global__ void embed_kernel(const float* __restrict__ X, int rows,
                             const float* __restrict__ W,
                             const float* __restrict__ b,
                             float* __restrict__ out) {
    __shared__ float Wl[128 * 16];
    __shared__ float bl[16];
    for (int i = threadIdx.x; i < 128 * 16; i += blockDim.x) Wl[i] = W[i];
    if (threadIdx.x < 16) bl[threadIdx.x] = b[threadIdx.x];
    __syncthreads();
    int n = blockIdx.x * blockDim.x + threadIdx.x;
    if (n >= rows) return;
    float acc[16];
#pragma unroll
    for (int j = 0; j < 16; j++) acc[j] = bl[j];
    const float4* row = (const float4*)(X + (size_t)n * 128);
    for (int k4 = 0; k4 < 32; k4++) {
        float4 xv = row[k4];
        int k = k4 * 4;
#pragma unroll
        for (int j = 0; j < 16; j++) {
            float a = acc[j];
            a = fmaf(xv.x, Wl[(k + 0) * 16 + j], a);
            a = fmaf(xv.y, Wl[(k + 1) * 16 + j], a);
            a = fmaf(xv.z, Wl[(k + 2) * 16 + j], a);
            a = fmaf(xv.w, Wl[(k + 3) * 16 + j], a);
            acc[j] = a;
        }
    }
    float* o = out + (size_t)n * 16;
#pragma unroll
    for (int j = 0; j < 16; j++) o[j] = acc[j];
}

// ---------------------------------------------------------------------------
// Combine bases with comp into per-relation W, plus copies of root/bias.
__global__ void prep_weights_kernel(const float* __restrict__ bases,
                                    const float* __restrict__ comp,
                                    const float* __restrict__ root,
                                    const float* __restrict__ bias,
                                    float* __restrict__ Wbuf, int din, int dout) {
    int sz = din * dout;
    int i = blockIdx.x * blockDim.x + threadIdx.x;
    if (i < sz) {
        float b0 = bases[i];
        float b1 = bases[sz + i];
        float b2 = bases[2 * sz + i];
        float b3 = bases[3 * sz + i];
        for (int r = 0; r < 2; r++) {
            Wbuf[r * sz + i] = comp[r * 4 + 0] * b0 + comp[r * 4 + 1] * b1 +
                               comp[r * 4 + 2] * b2 + comp[r * 4 + 3] * b3;
        }
        Wbuf[2 * sz + i] = root[i];
    }
    if (i < dout) Wbuf[3 * sz + i] = bias[i];
}

// ---------------------------------------------------------------------------
// Node transform: out = relu?(x) @ root + bias ; h0 = relu?(x) @ W0 ; h1 = relu?(x) @ W1
__global__ void transform_kernel(const float* __restrict__ x, float* __restrict__ out,
                                 float* __restrict__ h0, float* __restrict__ h1,
                                 const float* __restrict__ Wbuf, int din, int dout,
                                 int relu) {
    __shared__ float Wl[3 * 1024 + 32];
    int sz = din * dout;
    int tot = 3 * sz + dout;
    for (int i = threadIdx.x; i < tot; i += blockDim.x) Wl[i] = Wbuf[i];
    __syncthreads();
    int n = blockIdx.x * blockDim.x + threadIdx.x;
    if (n >= NN) return;
    float xr[32];
    const float* xp = x + (size_t)n * din;
    for (int k = 0; k < din; k++) {
        float v = xp[k];
        xr[k] = relu ? fmaxf(v, 0.0f) : v;
    }
    const float* W0 = Wl;
    const float* W1 = Wl + sz;
    const float* R  = Wl + 2 * sz;
    const float* B  = Wl + 3 * sz;
    float* o  = out + (size_t)n * dout;
    float* p0 = h0 + (size_t)n * dout;
    float* p1 = h1 + (size_t)n * dout;
    for (int j = 0; j < dout; j++) {
        float a0 = 0.0f, a1 = 0.0f, ar = B[j];
        for (int k = 0; k < din; k++) {
            float xv = xr[k];
            a0 = fmaf(xv, W0[k * dout + j], a0);
            a1 = fmaf(xv, W1[k * dout + j], a1);
            ar = fmaf(xv, R[k * dout + j], ar);
        }
        p0[j] = a0;
        p1[j] = a1;
        o[j]  = ar;
    }
}

// ---------------------------------------------------------------------------
// Pull-mode aggregation, both relations in parallel within one wave.
// F = 1<<shift features; thread group of F lanes walks one (dst, relation)
// CSR segment; r0/r1 partials combined via shfl_down(F). Non-atomic writes.
__global__ void aggregate_kernel(const int* __restrict__ off, const int* __restrict__ csr,
                                 const float* __restrict__ h0, const float* __restrict__ h1,
                                 const float* __restrict__ inv, float* __restrict__ out,
                                 int shift) {
    int gid = blockIdx.x * blockDim.x + threadIdx.x;
    int d = gid >> (shift + 1);
    if (d >= NN) return;
    int F = 1 << shift;
    int rj = gid & (2 * F - 1);
    int r = rj >> shift;
    int j = rj & (F - 1);
    const float* h = r ? h1 : h0;
    int b = off[r * NN + d];
    int e = off[r * NN + d + 1];
    float acc_a = 0.0f, acc_b = 0.0f;
    int k = b;
    for (; k + 1 < e; k += 2) {
        int s0 = csr[k];
        int s1 = csr[k + 1];
        acc_a += h[((size_t)s0 << shift) + j];
        acc_b += h[((size_t)s1 << shift) + j];
    }
    if (k < e) acc_a += h[((size_t)csr[k] << shift) + j];
    float scaled = (acc_a + acc_b) * inv[r * NN + d];
    float partner = __shfl_down(scaled, F, 64);
    if (r == 0) out[((size_t)d << shift) + j] += scaled + partner;
}

// ---------------------------------------------------------------------------
// Decode prep: y0 = z @ Wd0 + bd0 ; y1 = z @ Wd1 + bd1   (all 16-dim)
__global__ void decode_prep_kernel(const float* __restrict__ z,
                                   const float* __restrict__ Wd0,
                                   const float* __restrict__ bd0,
                                   const float* __restrict__ Wd1,
                                   const float* __restrict__ bd1,
                                   float* __restrict__ y0, float* __restrict__ y1) {
    __shared__ float W0l[256], W1l[256], B0[16], B1[16];
    for (int i = threadIdx.x; i < 256; i += blockDim.x) {
        W0l[i] = Wd0[i];
        W1l[i] = Wd1[i];
    }
    if (threadIdx.x < 16) {
        B0[threadIdx.x] = bd0[threadIdx.x];
        B1[threadIdx.x] = bd1[threadIdx.x];
    }
    __syncthreads();
    int n = blockIdx.x * blockDim.x + threadIdx.x;
    if (n >= NN) return;
    float zr[16];
    const float* zp = z + (size_t)n * 16;
#pragma unroll
    for (int k = 0; k < 16; k++) zr[k] = zp[k];
    float* o0 = y0 + (size_t)n * 16;
    float* o1 = y1 + (size_t)n * 16;
    for (int j = 0; j < 16; j++) {
        float a0 = B0[j], a1 = B1[j];
#pragma unroll
        for (int k = 0; k < 16; k++) {
            a0 = fmaf(zr[k], W0l[k * 16 + j], a0);
            a1 = fmaf(zr[k], W1l[k * 16 + j], a1);
        }
        o0[j] = a0;
        o1[j] = a1;
    }
}

// ---------------------------------------------------------------------------
// Decode: out[i] = dot( y_{et}[src], z[dst] )  — fp32 output
__global__ void decode_kernel(const float* __restrict__ y0, const float* __restrict__ y1,
                              const float* __restrict__ z,
                              const int* __restrict__ pei, const int* __restrict__ pet,
                              const int* __restrict__ nei, const int* __restrict__ net_,
                              float* __restrict__ out,
                              const int* __restrict__ dflag) {
    int i = blockIdx.x * blockDim.x + threadIdx.x;
    if (i >= 2 * ED) return;
    int sft = dflag[0];
    const int* ei;
    const int* et;
    int e;
    if (i < ED) { ei = pei; et = pet; e = i; }
    else        { ei = nei; et = net_; e = i - ED; }
    int s = ei[(size_t)e << sft];
    int d = ei[(size_t)(ED + e) << sft];
    int r = et[(size_t)e << sft];
    const float4* yv = (const float4*)((r ? y1 : y0) + ((size_t)s << 4));
    const float4* zv = (const float4*)(z + ((size_t)d << 4));
    float acc = 0.0f;
#pragma unroll
    for (int q = 0; q < 4; q++) {
        float4 a = yv[q];
        float4 b = zv[q];
        acc += a.x * b.x + a.y * b.y + a.z * b.z + a.w * b.w;
    }
    out[i] = acc;
}

// ---------------------------------------------------------------------------
extern "C" void kernel_launch(void* const* d_in, const int* in_sizes, int n_in,
                              void* d_out, int out_size, void* d_ws, size_t ws_size,
                              hipStream_t stream) {
    const float* x_paper = (const float*)d_in[0];
    const float* x_mesh  = (const float*)d_in[1];
    const int* tei  = (const int*)d_in[2];
    const int* tet  = (const int*)d_in[3];
    const int* pei  = (const int*)d_in[4];
    const int* pet  = (const int*)d_in[5];
    const int* nei  = (const int*)d_in[6];
    const int* net_ = (const int*)d_in[7];
    const float* Wp  = (const float*)d_in[8];
    const float* bp  = (const float*)d_in[9];
    const float* Wm  = (const float*)d_in[10];
    const float* bm  = (const float*)d_in[11];
    const float* Wd0 = (const float*)d_in[12];
    const float* bd0 = (const float*)d_in[13];
    const float* Wd1 = (const float*)d_in[14];
    const float* bd1 = (const float*)d_in[15];
    const float* basesL[4] = {(const float*)d_in[16], (const float*)d_in[20],
                              (const float*)d_in[24], (const float*)d_in[28]};
    const float* compL[4]  = {(const float*)d_in[17], (const float*)d_in[21],
                              (const float*)d_in[25], (const float*)d_in[29]};
    const float* rootL[4]  = {(const float*)d_in[18], (const float*)d_in[22],
                              (const float*)d_in[26], (const float*)d_in[30]};
    const float* biasL[4]  = {(const float*)d_in[19], (const float*)d_in[23],
                              (const float*)d_in[27], (const float*)d_in[31]};

    // Workspace carve-up (fp32/int32 elements) — ~58 MB total
    float* ws = (float*)d_ws;
    size_t o = 0;
    float* bufA = ws + o; o += (size_t)NN * 32;
    float* bufB = ws + o; o += (size_t)NN * 32;
    float* h0   = ws + o; o += (size_t)NN * 32;
    float* h1   = ws + o; o += (size_t)NN * 32;
    float* inv  = ws + o; o += (size_t)TWO_NN;
    int*   cnt    = (int*)(ws + o); o += (size_t)TWO_NN;
    int*   off    = (int*)(ws + o); o += (size_t)TWO_NN + 4;
    int*   cursor = (int*)(ws + o); o += (size_t)TWO_NN;
    int*   bsum   = (int*)(ws + o); o += 256;
    int*   csr    = (int*)(ws + o); o += (size_t)ET;
    float* Wbuf = ws + o; o += 4096;
    int*   dflag = (int*)(ws + o); o += 16;

    // 0. Dtype detect (verified int32; zero-cost insurance)
    detect_kernel<<<1, 64, 0, stream>>>(tei, dflag);

    // 1. Degree histogram + inverse (edge structure is layer-invariant)
    hipMemsetAsync(cnt, 0, (size_t)TWO_NN * sizeof(int), stream);
    count_deg_kernel<<<(ET + 255) / 256, 256, 0, stream>>>(tei, tet, cnt, dflag);
    inv_kernel<<<(TWO_NN + 255) / 256, 256, 0, stream>>>(cnt, inv);

    // 2. CSR build (once): scan cnt -> off/cursor, then fill src lists
    scan_block_kernel<<<SCAN_BLKS, 256, 0, stream>>>(cnt, bsum);
    scan_bsum_kernel<<<1, 256, 0, stream>>>(bsum, SCAN_BLKS);
    scan_final_kernel<<<SCAN_BLKS, 256, 0, stream>>>(cnt, bsum, off, cursor);
    csr_fill_kernel<<<(ET + 255) / 256, 256, 0, stream>>>(tei, tet, cursor, csr, dflag);

    // 3. Input embed -> bufA [NN,16]
    embed_kernel<<<(NP + 255) / 256, 256, 0, stream>>>(x_paper, NP, Wp, bp, bufA);
    embed_kernel<<<(NM + 255) / 256, 256, 0, stream>>>(x_mesh, NM, Wm, bm,
                                                       bufA + (size_t)NP * 16);

    // 4. Four RGCN layers (ping-pong bufA/bufB), pull-mode aggregation
    int dims[5] = {16, 32, 32, 32, 16};
    float* xin = bufA;
    float* xout = bufB;
    for (int l = 0; l < 4; l++) {
        int din = dims[l], dout = dims[l + 1];
        int sz = din * dout;
        prep_weights_kernel<<<(sz + 255) / 256, 256, 0, stream>>>(
            basesL[l], compL[l], rootL[l], biasL[l], Wbuf, din, dout);
        transform_kernel<<<(NN + 255) / 256, 256, 0, stream>>>(
            xin, xout, h0, h1, Wbuf, din, dout, l > 0 ? 1 : 0);
        int shift = (dout == 32) ? 5 : 4;
        long total = (long)NN << (shift + 1); // dst x relation x feature
        aggregate_kernel<<<(int)((total + 255) / 256), 256, 0, stream>>>(
            off, csr, h0, h1, inv, xout, shift);
        float* t = xin; xin = xout; xout = t;
    }
    // z = xin [NN,16]

    // 5. Decode
    decode_prep_kernel<<<(NN + 255) / 256, 256, 0, stream>>>(xin, Wd0, bd0, Wd1, bd1,
                                                             h0, h1);
    decode_kernel<<<(2 * ED + 255) / 256, 256, 0, stream>>>(
        h0, h1, xin, pei, pet, nei, net_, (float*)d_out, dflag);
}

// Round 7
// 1001.544 us; speedup vs baseline: 1.4699x; 1.2028x over previous
//
#include <hip/hip_runtime.h>
#include <hip/hip_bf16.h>

// Problem constants (from reference)
constexpr int NN = 90000;   // total nodes
constexpr int NP = 60000;   // paper nodes
constexpr int NM = 30000;   // mesh nodes
constexpr int ET = 2000000; // train edges
constexpr int ED = 400000;  // decode edges (each of pos/neg)
constexpr int TWO_NN = 2 * NN;
constexpr int SCAN_BLKS = (TWO_NN + 1023) / 1024; // 176

// Binned CSR build parameters
constexpr int BKT_SH  = 10;                        // 1024 keys per bucket
constexpr int NB_BKT  = (TWO_NN + 1023) >> BKT_SH; // 176 buckets
constexpr int BKT_CAP = 12288;                     // mean 11366, +8.7 sigma
constexpr int TILE    = 2048;                      // edges per binning tile
constexpr int N_TILES = (ET + TILE - 1) / TILE;    // 977

// ---------------------------------------------------------------------------
// Detect whether int arrays are int64 or int32 (verified int32; insurance).
__global__ void detect_kernel(const int* __restrict__ tei, int* __restrict__ flag) {
    if (blockIdx.x == 0 && threadIdx.x == 0) {
        int allzero = 1;
        for (int i = 0; i < 16; i++)
            if (tei[2 * i + 1] != 0) allzero = 0;
        flag[0] = allzero; // 1 => int64 => index shift 1
    }
}

__global__ void init_gcur_kernel(int* __restrict__ gcur) {
    int b = blockIdx.x * blockDim.x + threadIdx.x;
    if (b < NB_BKT) gcur[b] = b * BKT_CAP;
}

// ---------------------------------------------------------------------------
// Pass A: bin edges into per-bucket pair arrays with line-dense writes.
// Each tile of 2048 edges is counting-sorted by bucket in LDS, then flushed
// as contiguous per-bucket runs (avoids the 64B dirty-line thrash measured in
// R5/R6: 125-140 MB WRITE_SIZE for an 8 MB array with random 4B stores).
__global__ void __launch_bounds__(256) binA_kernel(
        const int* __restrict__ ei, const int* __restrict__ et,
        const int* __restrict__ dflag, int* __restrict__ gcur,
        int2* __restrict__ pairs) {
    __shared__ int hist[NB_BKT];
    __shared__ int excl[NB_BKT];
    __shared__ int cur[NB_BKT];
    __shared__ int gbase[NB_BKT];
    __shared__ int scn[256];
    __shared__ int2 tbuf[TILE];
    int t = threadIdx.x;
    int tile0 = blockIdx.x * TILE;
    int tcount = ET - tile0;
    if (tcount > TILE) tcount = TILE;
    for (int i = t; i < NB_BKT; i += 256) hist[i] = 0;
    __syncthreads();
    int sft = dflag[0];
    int myk[8], mys[8];
#pragma unroll
    for (int q = 0; q < 8; q++) {
        int li = q * 256 + t;
        myk[q] = -1;
        if (li < tcount) {
            int e = tile0 + li;
            int s = ei[(size_t)e << sft];
            int d = ei[(size_t)(ET + e) << sft];
            int r = et[(size_t)e << sft];
            int key = r * NN + d;
            myk[q] = key;
            mys[q] = s;
            atomicAdd(&hist[key >> BKT_SH], 1);
        }
    }
    __syncthreads();
    // exclusive scan of hist over 176 bins (Hillis-Steele on 256 lanes)
    int v = (t < NB_BKT) ? hist[t] : 0;
    scn[t] = v;
    __syncthreads();
    for (int st = 1; st < 256; st <<= 1) {
        int u = (t >= st) ? scn[t - st] : 0;
        __syncthreads();
        scn[t] += u;
        __syncthreads();
    }
    if (t < NB_BKT) {
        excl[t] = scn[t] - v;
        cur[t] = scn[t] - v;
    }
    __syncthreads();
    // place into LDS tile buffer (bucket-contiguous)
#pragma unroll
    for (int q = 0; q < 8; q++) {
        if (myk[q] >= 0) {
            int b = myk[q] >> BKT_SH;
            int p = atomicAdd(&cur[b], 1);
            tbuf[p] = make_int2(myk[q], mys[q]);
        }
    }
    __syncthreads();
    // reserve global runs
    if (t < NB_BKT && hist[t] > 0) gbase[t] = atomicAdd(&gcur[t], hist[t]);
    __syncthreads();
    // flush: consecutive i -> mostly consecutive global positions
    for (int i = t; i < tcount; i += 256) {
        int2 p = tbuf[i];
        int b = p.x >> BKT_SH;
        int gpos = gbase[b] + (i - excl[b]);
        int cap = (b + 1) * BKT_CAP - 1;
        pairs[gpos < cap ? gpos : cap] = p;
    }
}

// ---------------------------------------------------------------------------
// Pass B1: per-bucket key histogram (LDS) -> cnt written densely.
// Replaces count_deg's 2M scattered global atomics.
__global__ void __launch_bounds__(256) histB_kernel(
        const int* __restrict__ gcur, const int2* __restrict__ pairs,
        int* __restrict__ cnt) {
    __shared__ int kh[1024];
    int b = blockIdx.x;
    int t = threadIdx.x;
    for (int i = t; i < 1024; i += 256) kh[i] = 0;
    __syncthreads();
    int beg = b * BKT_CAP, end = gcur[b];
    for (int i = beg + t; i < end; i += 256)
        atomicAdd(&kh[pairs[i].x & 1023], 1);
    __syncthreads();
    int kbase = b << BKT_SH;
    for (int i = t; i < 1024; i += 256)
        if (kbase + i < TWO_NN) cnt[kbase + i] = kh[i];
}

__global__ void inv_kernel(const int* __restrict__ cnt, float* __restrict__ inv) {
    int i = blockIdx.x * blockDim.x + threadIdx.x;
    if (i < TWO_NN) {
        int c = cnt[i];
        inv[i] = 1.0f / (float)(c > 1 ? c : 1);
    }
}

// ---------------------------------------------------------------------------
// Hierarchical exclusive scan of cnt[0..2NN) -> off
__global__ void scan_block_kernel(const int* __restrict__ cnt, int* __restrict__ bsum) {
    __shared__ int lds[256];
    int base = blockIdx.x * 1024;
    int t = threadIdx.x;
    int s = 0;
#pragma unroll
    for (int q = 0; q < 4; q++) {
        int i = base + t * 4 + q;
        s += (i < TWO_NN) ? cnt[i] : 0;
    }
    lds[t] = s;
    __syncthreads();
    for (int st = 128; st > 0; st >>= 1) {
        if (t < st) lds[t] += lds[t + st];
        __syncthreads();
    }
    if (t == 0) bsum[blockIdx.x] = lds[0];
}

__global__ void scan_bsum_kernel(int* __restrict__ bsum, int nb) {
    __shared__ int lds[256];
    int t = threadIdx.x;
    lds[t] = (t < nb) ? bsum[t] : 0;
    __syncthreads();
    for (int st = 1; st < 256; st <<= 1) {
        int v = (t >= st) ? lds[t - st] : 0;
        __syncthreads();
        lds[t] += v;
        __syncthreads();
    }
    if (t < nb) bsum[t] = (t > 0) ? lds[t - 1] : 0;
}

__global__ void scan_final_kernel(const int* __restrict__ cnt, const int* __restrict__ bsum,
                                  int* __restrict__ off) {
    __shared__ int lds[256];
    int base = blockIdx.x * 1024;
    int t = threadIdx.x;
    int v[4];
    int s = 0;
#pragma unroll
    for (int q = 0; q < 4; q++) {
        int i = base + t * 4 + q;
        v[q] = (i < TWO_NN) ? cnt[i] : 0;
        s += v[q];
    }
    lds[t] = s;
    __syncthreads();
    for (int st = 1; st < 256; st <<= 1) {
        int u = (t >= st) ? lds[t - st] : 0;
        __syncthreads();
        lds[t] += u;
        __syncthreads();
    }
    int run = bsum[blockIdx.x] + lds[t] - s;
#pragma unroll
    for (int q = 0; q < 4; q++) {
        int i = base + t * 4 + q;
        if (i < TWO_NN) off[i] = run;
        run += v[q];
    }
    if (blockIdx.x == 0 && t == 0) off[TWO_NN] = ET;
}

// ---------------------------------------------------------------------------
// Pass B2: place pairs into final CSR. Each bucket's csr range is contiguous
// (~45 KB) -> stays hot in the executing XCD's L2, lines fill before eviction.
__global__ void __launch_bounds__(256) placeB_kernel(
        const int* __restrict__ gcur, const int2* __restrict__ pairs,
        const int* __restrict__ off, int* __restrict__ csr) {
    __shared__ int kc[1024];
    int b = blockIdx.x;
    int t = threadIdx.x;
    int kbase = b << BKT_SH;
    for (int i = t; i < 1024; i += 256)
        if (kbase + i < TWO_NN) kc[i] = off[kbase + i];
    __syncthreads();
    int beg = b * BKT_CAP, end = gcur[b];
    for (int i = beg + t; i < end; i += 256) {
        int2 p = pairs[i];
        int pos = atomicAdd(&kc[p.x & 1023], 1);
        csr[pos] = p.y;
    }
}

// ---------------------------------------------------------------------------
// Input embed: out[n] = X[n] (128, fp32) @ W (128x16, fp32) + b
__global__ void embed_kernel(const float* __restrict__ X, int rows,
                             const float* __restrict__ W,
                             const float* __restrict__ b,
                             float* __restrict__ out) {
    __shared__ float Wl[128 * 16];
    __shared__ float bl[16];
    for (int i = threadIdx.x; i < 128 * 16; i += blockDim.x) Wl[i] = W[i];
    if (threadIdx.x < 16) bl[threadIdx.x] = b[threadIdx.x];
    __syncthreads();
    int n = blockIdx.x * blockDim.x + threadIdx.x;
    if (n >= rows) return;
    float acc[16];
#pragma unroll
    for (int j = 0; j < 16; j++) acc[j] = bl[j];
    const float4* row = (const float4*)(X + (size_t)n * 128);
    for (int k4 = 0; k4 < 32; k4++) {
        float4 xv = row[k4];
        int k = k4 * 4;
#pragma unroll
        for (int j = 0; j < 16; j++) {
            float a = acc[j];
            a = fmaf(xv.x, Wl[(k + 0) * 16 + j], a);
            a = fmaf(xv.y, Wl[(k + 1) * 16 + j], a);
            a = fmaf(xv.z, Wl[(k + 2) * 16 + j], a);
            a = fmaf(xv.w, Wl[(k + 3) * 16 + j], a);
            acc[j] = a;
        }
    }
    float* o = out + (size_t)n * 16;
#pragma unroll
    for (int j = 0; j < 16; j++) o[j] = acc[j];
}

// ---------------------------------------------------------------------------
// Combine bases with comp into per-relation W, plus copies of root/bias.
__global__ void prep_weights_kernel(const float* __restrict__ bases,
                                    const float* __restrict__ comp,
                                    const float* __restrict__ root,
                                    const float* __restrict__ bias,
                                    float* __restrict__ Wbuf, int din, int dout) {
    int sz = din * dout;
    int i = blockIdx.x * blockDim.x + threadIdx.x;
    if (i < sz) {
        float b0 = bases[i];
        float b1 = bases[sz + i];
        float b2 = bases[2 * sz + i];
        float b3 = bases[3 * sz + i];
        for (int r = 0; r < 2; r++) {
            Wbuf[r * sz + i] = comp[r * 4 + 0] * b0 + comp[r * 4 + 1] * b1 +
                               comp[r * 4 + 2] * b2 + comp[r * 4 + 3] * b3;
        }
        Wbuf[2 * sz + i] = root[i];
    }
    if (i < dout) Wbuf[3 * sz + i] = bias[i];
}

// ---------------------------------------------------------------------------
// Node transform: out = relu?(x) @ root + bias ; h0 = relu?(x) @ W0 ; h1 = relu?(x) @ W1
__global__ void transform_kernel(const float* __restrict__ x, float* __restrict__ out,
                                 float* __restrict__ h0, float* __restrict__ h1,
                                 const float* __restrict__ Wbuf, int din, int dout,
                                 int relu) {
    __shared__ float Wl[3 * 1024 + 32];
    int sz = din * dout;
    int tot = 3 * sz + dout;
    for (int i = threadIdx.x; i < tot; i += blockDim.x) Wl[i] = Wbuf[i];
    __syncthreads();
    int n = blockIdx.x * blockDim.x + threadIdx.x;
    if (n >= NN) return;
    float xr[32];
    const float* xp = x + (size_t)n * din;
    for (int k = 0; k < din; k++) {
        float v = xp[k];
        xr[k] = relu ? fmaxf(v, 0.0f) : v;
    }
    const float* W0 = Wl;
    const float* W1 = Wl + sz;
    const float* R  = Wl + 2 * sz;
    const float* B  = Wl + 3 * sz;
    float* o  = out + (size_t)n * dout;
    float* p0 = h0 + (size_t)n * dout;
    float* p1 = h1 + (size_t)n * dout;
    for (int j = 0; j < dout; j++) {
        float a0 = 0.0f, a1 = 0.0f, ar = B[j];
        for (int k = 0; k < din; k++) {
            float xv = xr[k];
            a0 = fmaf(xv, W0[k * dout + j], a0);
            a1 = fmaf(xv, W1[k * dout + j], a1);
            ar = fmaf(xv, R[k * dout + j], ar);
        }
        p0[j] = a0;
        p1[j] = a1;
        o[j]  = ar;
    }
}

// ---------------------------------------------------------------------------
// Pull-mode aggregation, both relations in parallel within one wave.
__global__ void aggregate_kernel(const int* __restrict__ off, const int* __restrict__ csr,
                                 const float* __restrict__ h0, const float* __restrict__ h1,
                                 const float* __restrict__ inv, float* __restrict__ out,
                                 int shift) {
    int gid = blockIdx.x * blockDim.x + threadIdx.x;
    int d = gid >> (shift + 1);
    if (d >= NN) return;
    int F = 1 << shift;
    int rj = gid & (2 * F - 1);
    int r = rj >> shift;
    int j = rj & (F - 1);
    const float* h = r ? h1 : h0;
    int b = off[r * NN + d];
    int e = off[r * NN + d + 1];
    float acc_a = 0.0f, acc_b = 0.0f;
    int k = b;
    for (; k + 1 < e; k += 2) {
        int s0 = csr[k];
        int s1 = csr[k + 1];
        acc_a += h[((size_t)s0 << shift) + j];
        acc_b += h[((size_t)s1 << shift) + j];
    }
    if (k < e) acc_a += h[((size_t)csr[k] << shift) + j];
    float scaled = (acc_a + acc_b) * inv[r * NN + d];
    float partner = __shfl_down(scaled, F, 64);
    if (r == 0) out[((size_t)d << shift) + j] += scaled + partner;
}

// ---------------------------------------------------------------------------
// Decode prep: y0 = z @ Wd0 + bd0 ; y1 = z @ Wd1 + bd1   (all 16-dim)
__global__ void decode_prep_kernel(const float* __restrict__ z,
                                   const float* __restrict__ Wd0,
                                   const float* __restrict__ bd0,
                                   const float* __restrict__ Wd1,
                                   const float* __restrict__ bd1,
                                   float* __restrict__ y0, float* __restrict__ y1) {
    __shared__ float W0l[256], W1l[256], B0[16], B1[16];
    for (int i = threadIdx.x; i < 256; i += blockDim.x) {
        W0l[i] = Wd0[i];
        W1l[i] = Wd1[i];
    }
    if (threadIdx.x < 16) {
        B0[threadIdx.x] = bd0[threadIdx.x];
        B1[threadIdx.x] = bd1[threadIdx.x];
    }
    __syncthreads();
    int n = blockIdx.x * blockDim.x + threadIdx.x;
    if (n >= NN) return;
    float zr[16];
    const float* zp = z + (size_t)n * 16;
#pragma unroll
    for (int k = 0; k < 16; k++) zr[k] = zp[k];
    float* o0 = y0 + (size_t)n * 16;
    float* o1 = y1 + (size_t)n * 16;
    for (int j = 0; j < 16; j++) {
        float a0 = B0[j], a1 = B1[j];
#pragma unroll
        for (int k = 0; k < 16; k++) {
            a0 = fmaf(zr[k], W0l[k * 16 + j], a0);
            a1 = fmaf(zr[k], W1l[k * 16 + j], a1);
        }
        o0[j] = a0;
        o1[j] = a1;
    }
}

// ---------------------------------------------------------------------------
// Decode: out[i] = dot( y_{et}[src], z[dst] )  — fp32 output
__global__ void decode_kernel(const float* __restrict__ y0, const float* __restrict__ y1,
                              const float* __restrict__ z,
                              const int* __restrict__ pei, const int* __restrict__ pet,
                              const int* __restrict__ nei, const int* __restrict__ net_,
                              float* __restrict__ out,
                              const int* __restrict__ dflag) {
    int i = blockIdx.x * blockDim.x + threadIdx.x;
    if (i >= 2 * ED) return;
    int sft = dflag[0];
    const int* ei;
    const int* et;
    int e;
    if (i < ED) { ei = pei; et = pet; e = i; }
    else        { ei = nei; et = net_; e = i - ED; }
    int s = ei[(size_t)e << sft];
    int d = ei[(size_t)(ED + e) << sft];
    int r = et[(size_t)e << sft];
    const float4* yv = (const float4*)((r ? y1 : y0) + ((size_t)s << 4));
    const float4* zv = (const float4*)(z + ((size_t)d << 4));
    float acc = 0.0f;
#pragma unroll
    for (int q = 0; q < 4; q++) {
        float4 a = yv[q];
        float4 b = zv[q];
        acc += a.x * b.x + a.y * b.y + a.z * b.z + a.w * b.w;
    }
    out[i] = acc;
}

// ---------------------------------------------------------------------------
extern "C" void kernel_launch(void* const* d_in, const int* in_sizes, int n_in,
                              void* d_out, int out_size, void* d_ws, size_t ws_size,
                              hipStream_t stream) {
    const float* x_paper = (const float*)d_in[0];
    const float* x_mesh  = (const float*)d_in[1];
    const int* tei  = (const int*)d_in[2];
    const int* tet  = (const int*)d_in[3];
    const int* pei  = (const int*)d_in[4];
    const int* pet  = (const int*)d_in[5];
    const int* nei  = (const int*)d_in[6];
    const int* net_ = (const int*)d_in[7];
    const float* Wp  = (const float*)d_in[8];
    const float* bp  = (const float*)d_in[9];
    const float* Wm  = (const float*)d_in[10];
    const float* bm  = (const float*)d_in[11];
    const float* Wd0 = (const float*)d_in[12];
    const float* bd0 = (const float*)d_in[13];
    const float* Wd1 = (const float*)d_in[14];
    const float* bd1 = (const float*)d_in[15];
    const float* basesL[4] = {(const float*)d_in[16], (const float*)d_in[20],
                              (const float*)d_in[24], (const float*)d_in[28]};
    const float* compL[4]  = {(const float*)d_in[17], (const float*)d_in[21],
                              (const float*)d_in[25], (const float*)d_in[29]};
    const float* rootL[4]  = {(const float*)d_in[18], (const float*)d_in[22],
                              (const float*)d_in[26], (const float*)d_in[30]};
    const float* biasL[4]  = {(const float*)d_in[19], (const float*)d_in[23],
                              (const float*)d_in[27], (const float*)d_in[31]};

    // Workspace carve-up (fp32/int32 elements) — ~57 MB total
    float* ws = (float*)d_ws;
    size_t o = 0;
    float* bufA = ws + o; o += (size_t)NN * 32;
    float* bufB = ws + o; o += (size_t)NN * 32;
    float* h0   = ws + o; o += (size_t)NN * 32;
    float* h1   = ws + o; o += (size_t)NN * 32;
    float* inv  = ws + o; o += (size_t)TWO_NN;
    int*   cnt  = (int*)(ws + o); o += (size_t)TWO_NN;
    int*   off  = (int*)(ws + o); o += (size_t)TWO_NN + 4;
    int*   bsum = (int*)(ws + o); o += 256;
    int*   csr  = (int*)(ws + o); o += (size_t)ET;
    int*   gcur = (int*)(ws + o); o += 256;
    float* Wbuf = ws + o; o += 4096;
    int*   dflag = (int*)(ws + o); o += 16;
    // pairs alias h0/h1 (dead until first transform): 176*12288*8B = 17.3 MB < 23 MB
    int2* pairs = (int2*)h0;

    // 0. Dtype detect
    detect_kernel<<<1, 64, 0, stream>>>(tei, dflag);

    // 1. Binned CSR build (once; edge structure is layer-invariant)
    init_gcur_kernel<<<1, 256, 0, stream>>>(gcur);
    binA_kernel<<<N_TILES, 256, 0, stream>>>(tei, tet, dflag, gcur, pairs);
    histB_kernel<<<NB_BKT, 256, 0, stream>>>(gcur, pairs, cnt);
    inv_kernel<<<(TWO_NN + 255) / 256, 256, 0, stream>>>(cnt, inv);
    scan_block_kernel<<<SCAN_BLKS, 256, 0, stream>>>(cnt, bsum);
    scan_bsum_kernel<<<1, 256, 0, stream>>>(bsum, SCAN_BLKS);
    scan_final_kernel<<<SCAN_BLKS, 256, 0, stream>>>(cnt, bsum, off);
    placeB_kernel<<<NB_BKT, 256, 0, stream>>>(gcur, pairs, off, csr);

    // 2. Input embed -> bufA [NN,16]
    embed_kernel<<<(NP + 255) / 256, 256, 0, stream>>>(x_paper, NP, Wp, bp, bufA);
    embed_kernel<<<(NM + 255) / 256, 256, 0, stream>>>(x_mesh, NM, Wm, bm,
                                                       bufA + (size_t)NP * 16);

    // 3. Four RGCN layers (ping-pong bufA/bufB), pull-mode aggregation
    int dims[5] = {16, 32, 32, 32, 16};
    float* xin = bufA;
    float* xout = bufB;
    for (int l = 0; l < 4; l++) {
        int din = dims[l], dout = dims[l + 1];
        int sz = din * dout;
        prep_weights_kernel<<<(sz + 255) / 256, 256, 0, stream>>>(
            basesL[l], compL[l], rootL[l], biasL[l], Wbuf, din, dout);
        transform_kernel<<<(NN + 255) / 256, 256, 0, stream>>>(
            xin, xout, h0, h1, Wbuf, din, dout, l > 0 ? 1 : 0);
        int shift = (dout == 32) ? 5 : 4;
        long total = (long)NN << (shift + 1); // dst x relation x feature
        aggregate_kernel<<<(int)((total + 255) / 256), 256, 0, stream>>>(
            off, csr, h0, h1, inv, xout, shift);
        float* t = xin; xin = xout; xout = t;
    }
    // z = xin [NN,16]

    // 4. Decode
    decode_prep_kernel<<<(NN + 255) / 256, 256, 0, stream>>>(xin, Wd0, bd0, Wd1, bd1,
                                                             h0, h1);
    decode_kernel<<<(2 * ED + 255) / 256, 256, 0, stream>>>(
        h0, h1, xin, pei, pet, nei, net_, (float*)d_out, dflag);
}

// Round 8
// 625.873 us; speedup vs baseline: 2.3521x; 1.6002x over previous
//
#include <hip/hip_runtime.h>
#include <hip/hip_bf16.h>

// Problem constants (from reference)
constexpr int NN = 90000;   // total nodes
constexpr int NP = 60000;   // paper nodes
constexpr int NM = 30000;   // mesh nodes
constexpr int ET = 2000000; // train edges
constexpr int ED = 400000;  // decode edges (each of pos/neg)
constexpr int TWO_NN = 2 * NN;
constexpr int SCAN_BLKS = (TWO_NN + 1023) / 1024; // 176

// Binned CSR build parameters
constexpr int BKT_SH  = 10;                        // 1024 keys per bucket
constexpr int NB_BKT  = (TWO_NN + 1023) >> BKT_SH; // 176 buckets
constexpr int BKT_CAP = 12288;                     // mean 11366, +8.7 sigma
constexpr int TILE    = 2048;                      // edges per binning tile
constexpr int N_TILES = (ET + TILE - 1) / TILE;    // 977

// ---------------------------------------------------------------------------
__global__ void detect_kernel(const int* __restrict__ tei, int* __restrict__ flag) {
    if (blockIdx.x == 0 && threadIdx.x == 0) {
        int allzero = 1;
        for (int i = 0; i < 16; i++)
            if (tei[2 * i + 1] != 0) allzero = 0;
        flag[0] = allzero; // 1 => int64 => index shift 1
    }
}

__global__ void init_gcur_kernel(int* __restrict__ gcur) {
    int b = blockIdx.x * blockDim.x + threadIdx.x;
    if (b < NB_BKT) gcur[b] = b * BKT_CAP;
}

// ---------------------------------------------------------------------------
// Pass A: bin edges into per-bucket pair arrays with line-dense writes.
__global__ void __launch_bounds__(256) binA_kernel(
        const int* __restrict__ ei, const int* __restrict__ et,
        const int* __restrict__ dflag, int* __restrict__ gcur,
        int2* __restrict__ pairs) {
    __shared__ int hist[NB_BKT];
    __shared__ int excl[NB_BKT];
    __shared__ int cur[NB_BKT];
    __shared__ int gbase[NB_BKT];
    __shared__ int scn[256];
    __shared__ int2 tbuf[TILE];
    int t = threadIdx.x;
    int tile0 = blockIdx.x * TILE;
    int tcount = ET - tile0;
    if (tcount > TILE) tcount = TILE;
    for (int i = t; i < NB_BKT; i += 256) hist[i] = 0;
    __syncthreads();
    int sft = dflag[0];
    int myk[8], mys[8];
#pragma unroll
    for (int q = 0; q < 8; q++) {
        int li = q * 256 + t;
        myk[q] = -1;
        if (li < tcount) {
            int e = tile0 + li;
            int s = ei[(size_t)e << sft];
            int d = ei[(size_t)(ET + e) << sft];
            int r = et[(size_t)e << sft];
            int key = r * NN + d;
            myk[q] = key;
            mys[q] = s;
            atomicAdd(&hist[key >> BKT_SH], 1);
        }
    }
    __syncthreads();
    int v = (t < NB_BKT) ? hist[t] : 0;
    scn[t] = v;
    __syncthreads();
    for (int st = 1; st < 256; st <<= 1) {
        int u = (t >= st) ? scn[t - st] : 0;
        __syncthreads();
        scn[t] += u;
        __syncthreads();
    }
    if (t < NB_BKT) {
        excl[t] = scn[t] - v;
        cur[t] = scn[t] - v;
    }
    __syncthreads();
#pragma unroll
    for (int q = 0; q < 8; q++) {
        if (myk[q] >= 0) {
            int b = myk[q] >> BKT_SH;
            int p = atomicAdd(&cur[b], 1);
            tbuf[p] = make_int2(myk[q], mys[q]);
        }
    }
    __syncthreads();
    if (t < NB_BKT && hist[t] > 0) gbase[t] = atomicAdd(&gcur[t], hist[t]);
    __syncthreads();
    for (int i = t; i < tcount; i += 256) {
        int2 p = tbuf[i];
        int b = p.x >> BKT_SH;
        int gpos = gbase[b] + (i - excl[b]);
        int cap = (b + 1) * BKT_CAP - 1;
        pairs[gpos < cap ? gpos : cap] = p;
    }
}

// ---------------------------------------------------------------------------
// Pass B1: per-bucket key histogram (LDS) -> cnt written densely.
__global__ void __launch_bounds__(256) histB_kernel(
        const int* __restrict__ gcur, const int2* __restrict__ pairs,
        int* __restrict__ cnt) {
    __shared__ int kh[1024];
    int b = blockIdx.x;
    int t = threadIdx.x;
    for (int i = t; i < 1024; i += 256) kh[i] = 0;
    __syncthreads();
    int beg = b * BKT_CAP, end = gcur[b];
    for (int i = beg + t; i < end; i += 256)
        atomicAdd(&kh[pairs[i].x & 1023], 1);
    __syncthreads();
    int kbase = b << BKT_SH;
    for (int i = t; i < 1024; i += 256)
        if (kbase + i < TWO_NN) cnt[kbase + i] = kh[i];
}

__global__ void inv_kernel(const int* __restrict__ cnt, float* __restrict__ inv) {
    int i = blockIdx.x * blockDim.x + threadIdx.x;
    if (i < TWO_NN) {
        int c = cnt[i];
        inv[i] = 1.0f / (float)(c > 1 ? c : 1);
    }
}

// ---------------------------------------------------------------------------
// Hierarchical exclusive scan of cnt[0..2NN) -> off
__global__ void scan_block_kernel(const int* __restrict__ cnt, int* __restrict__ bsum) {
    __shared__ int lds[256];
    int base = blockIdx.x * 1024;
    int t = threadIdx.x;
    int s = 0;
#pragma unroll
    for (int q = 0; q < 4; q++) {
        int i = base + t * 4 + q;
        s += (i < TWO_NN) ? cnt[i] : 0;
    }
    lds[t] = s;
    __syncthreads();
    for (int st = 128; st > 0; st >>= 1) {
        if (t < st) lds[t] += lds[t + st];
        __syncthreads();
    }
    if (t == 0) bsum[blockIdx.x] = lds[0];
}

__global__ void scan_bsum_kernel(int* __restrict__ bsum, int nb) {
    __shared__ int lds[256];
    int t = threadIdx.x;
    lds[t] = (t < nb) ? bsum[t] : 0;
    __syncthreads();
    for (int st = 1; st < 256; st <<= 1) {
        int v = (t >= st) ? lds[t - st] : 0;
        __syncthreads();
        lds[t] += v;
        __syncthreads();
    }
    if (t < nb) bsum[t] = (t > 0) ? lds[t - 1] : 0;
}

__global__ void scan_final_kernel(const int* __restrict__ cnt, const int* __restrict__ bsum,
                                  int* __restrict__ off) {
    __shared__ int lds[256];
    int base = blockIdx.x * 1024;
    int t = threadIdx.x;
    int v[4];
    int s = 0;
#pragma unroll
    for (int q = 0; q < 4; q++) {
        int i = base + t * 4 + q;
        v[q] = (i < TWO_NN) ? cnt[i] : 0;
        s += v[q];
    }
    lds[t] = s;
    __syncthreads();
    for (int st = 1; st < 256; st <<= 1) {
        int u = (t >= st) ? lds[t - st] : 0;
        __syncthreads();
        lds[t] += u;
        __syncthreads();
    }
    int run = bsum[blockIdx.x] + lds[t] - s;
#pragma unroll
    for (int q = 0; q < 4; q++) {
        int i = base + t * 4 + q;
        if (i < TWO_NN) off[i] = run;
        run += v[q];
    }
    if (blockIdx.x == 0 && t == 0) off[TWO_NN] = ET;
}

// ---------------------------------------------------------------------------
// Pass B2: place pairs into final CSR (bucket range contiguous -> L2-hot).
__global__ void __launch_bounds__(256) placeB_kernel(
        const int* __restrict__ gcur, const int2* __restrict__ pairs,
        const int* __restrict__ off, int* __restrict__ csr) {
    __shared__ int kc[1024];
    int b = blockIdx.x;
    int t = threadIdx.x;
    int kbase = b << BKT_SH;
    for (int i = t; i < 1024; i += 256)
        if (kbase + i < TWO_NN) kc[i] = off[kbase + i];
    __syncthreads();
    int beg = b * BKT_CAP, end = gcur[b];
    for (int i = beg + t; i < end; i += 256) {
        int2 p = pairs[i];
        int pos = atomicAdd(&kc[p.x & 1023], 1);
        csr[pos] = p.y;
    }
}

// ---------------------------------------------------------------------------
// Input embed: out[n] = X[n] (128, fp32) @ W (128x16, fp32) + b
__global__ void embed_kernel(const float* __restrict__ X, int rows,
                             const float* __restrict__ W,
                             const float* __restrict__ b,
                             float* __restrict__ out) {
    __shared__ float Wl[128 * 16];
    __shared__ float bl[16];
    for (int i = threadIdx.x; i < 128 * 16; i += blockDim.x) Wl[i] = W[i];
    if (threadIdx.x < 16) bl[threadIdx.x] = b[threadIdx.x];
    __syncthreads();
    int n = blockIdx.x * blockDim.x + threadIdx.x;
    if (n >= rows) return;
    float acc[16];
#pragma unroll
    for (int j = 0; j < 16; j++) acc[j] = bl[j];
    const float4* row = (const float4*)(X + (size_t)n * 128);
    for (int k4 = 0; k4 < 32; k4++) {
        float4 xv = row[k4];
        int k = k4 * 4;
#pragma unroll
        for (int j = 0; j < 16; j++) {
            float a = acc[j];
            a = fmaf(xv.x, Wl[(k + 0) * 16 + j], a);
            a = fmaf(xv.y, Wl[(k + 1) * 16 + j], a);
            a = fmaf(xv.z, Wl[(k + 2) * 16 + j], a);
            a = fmaf(xv.w, Wl[(k + 3) * 16 + j], a);
            acc[j] = a;
        }
    }
    float4* o = (float4*)(out + (size_t)n * 16);
#pragma unroll
    for (int q = 0; q < 4; q++)
        o[q] = make_float4(acc[4 * q], acc[4 * q + 1], acc[4 * q + 2], acc[4 * q + 3]);
}

// ---------------------------------------------------------------------------
// Combine bases with comp into per-relation W, plus copies of root/bias.
__global__ void prep_weights_kernel(const float* __restrict__ bases,
                                    const float* __restrict__ comp,
                                    const float* __restrict__ root,
                                    const float* __restrict__ bias,
                                    float* __restrict__ Wbuf, int din, int dout) {
    int sz = din * dout;
    int i = blockIdx.x * blockDim.x + threadIdx.x;
    if (i < sz) {
        float b0 = bases[i];
        float b1 = bases[sz + i];
        float b2 = bases[2 * sz + i];
        float b3 = bases[3 * sz + i];
        for (int r = 0; r < 2; r++) {
            Wbuf[r * sz + i] = comp[r * 4 + 0] * b0 + comp[r * 4 + 1] * b1 +
                               comp[r * 4 + 2] * b2 + comp[r * 4 + 3] * b3;
        }
        Wbuf[2 * sz + i] = root[i];
    }
    if (i < dout) Wbuf[3 * sz + i] = bias[i];
}

// ---------------------------------------------------------------------------
// Node transform, templated (compile-time dims => full unroll + float4 stores).
// DOUT/4 lanes per node; each lane computes 4 output cols for all 3 matrices
// and writes exactly one float4 per array -> wave stores are contiguous full
// lines (fixes R7's 12x write amplification: 427 MB for 34.5 MB of data).
template <int DIN, int DOUT, int RELU>
__global__ void __launch_bounds__(256) transform_t_kernel(
        const float* __restrict__ x, float* __restrict__ out,
        float* __restrict__ h0, float* __restrict__ h1,
        const float* __restrict__ Wbuf) {
    constexpr int SZ = DIN * DOUT;
    constexpr int LPN = DOUT / 4; // lanes per node
    __shared__ float Wl[3 * SZ + DOUT];
    for (int i = threadIdx.x; i < 3 * SZ + DOUT; i += 256) Wl[i] = Wbuf[i];
    __syncthreads();
    int gid = blockIdx.x * 256 + threadIdx.x;
    int n = gid / LPN;
    if (n >= NN) return;
    int j0 = (gid % LPN) * 4;
    // load x row (broadcast across the LPN lanes of this node)
    float xr[DIN];
    const float4* xp = (const float4*)(x + (size_t)n * DIN);
#pragma unroll
    for (int k4 = 0; k4 < DIN / 4; k4++) {
        float4 v = xp[k4];
        if (RELU) {
            v.x = fmaxf(v.x, 0.0f); v.y = fmaxf(v.y, 0.0f);
            v.z = fmaxf(v.z, 0.0f); v.w = fmaxf(v.w, 0.0f);
        }
        xr[4 * k4 + 0] = v.x; xr[4 * k4 + 1] = v.y;
        xr[4 * k4 + 2] = v.z; xr[4 * k4 + 3] = v.w;
    }
    float a0[4] = {0, 0, 0, 0}, a1[4] = {0, 0, 0, 0}, ar[4];
#pragma unroll
    for (int jj = 0; jj < 4; jj++) ar[jj] = Wl[3 * SZ + j0 + jj];
#pragma unroll
    for (int k = 0; k < DIN; k++) {
        float xv = xr[k];
        const float* w0 = &Wl[k * DOUT + j0];
        const float* w1 = &Wl[SZ + k * DOUT + j0];
        const float* wr = &Wl[2 * SZ + k * DOUT + j0];
#pragma unroll
        for (int jj = 0; jj < 4; jj++) {
            a0[jj] = fmaf(xv, w0[jj], a0[jj]);
            a1[jj] = fmaf(xv, w1[jj], a1[jj]);
            ar[jj] = fmaf(xv, wr[jj], ar[jj]);
        }
    }
    size_t base = (size_t)n * DOUT + j0;
    *(float4*)(h0 + base)  = make_float4(a0[0], a0[1], a0[2], a0[3]);
    *(float4*)(h1 + base)  = make_float4(a1[0], a1[1], a1[2], a1[3]);
    *(float4*)(out + base) = make_float4(ar[0], ar[1], ar[2], ar[3]);
}

// ---------------------------------------------------------------------------
// Pull-mode aggregation, both relations in parallel within one wave.
__global__ void aggregate_kernel(const int* __restrict__ off, const int* __restrict__ csr,
                                 const float* __restrict__ h0, const float* __restrict__ h1,
                                 const float* __restrict__ inv, float* __restrict__ out,
                                 int shift) {
    int gid = blockIdx.x * blockDim.x + threadIdx.x;
    int d = gid >> (shift + 1);
    if (d >= NN) return;
    int F = 1 << shift;
    int rj = gid & (2 * F - 1);
    int r = rj >> shift;
    int j = rj & (F - 1);
    const float* h = r ? h1 : h0;
    int b = off[r * NN + d];
    int e = off[r * NN + d + 1];
    float acc_a = 0.0f, acc_b = 0.0f;
    int k = b;
    for (; k + 1 < e; k += 2) {
        int s0 = csr[k];
        int s1 = csr[k + 1];
        acc_a += h[((size_t)s0 << shift) + j];
        acc_b += h[((size_t)s1 << shift) + j];
    }
    if (k < e) acc_a += h[((size_t)csr[k] << shift) + j];
    float scaled = (acc_a + acc_b) * inv[r * NN + d];
    float partner = __shfl_down(scaled, F, 64);
    if (r == 0) out[((size_t)d << shift) + j] += scaled + partner;
}

// ---------------------------------------------------------------------------
// Decode prep: y0 = z @ Wd0 + bd0 ; y1 = z @ Wd1 + bd1   (all 16-dim)
__global__ void decode_prep_kernel(const float* __restrict__ z,
                                   const float* __restrict__ Wd0,
                                   const float* __restrict__ bd0,
                                   const float* __restrict__ Wd1,
                                   const float* __restrict__ bd1,
                                   float* __restrict__ y0, float* __restrict__ y1) {
    __shared__ float W0l[256], W1l[256], B0[16], B1[16];
    for (int i = threadIdx.x; i < 256; i += blockDim.x) {
        W0l[i] = Wd0[i];
        W1l[i] = Wd1[i];
    }
    if (threadIdx.x < 16) {
        B0[threadIdx.x] = bd0[threadIdx.x];
        B1[threadIdx.x] = bd1[threadIdx.x];
    }
    __syncthreads();
    int n = blockIdx.x * blockDim.x + threadIdx.x;
    if (n >= NN) return;
    float zr[16];
    const float* zp = z + (size_t)n * 16;
#pragma unroll
    for (int k = 0; k < 16; k++) zr[k] = zp[k];
    float* o0 = y0 + (size_t)n * 16;
    float* o1 = y1 + (size_t)n * 16;
#pragma unroll
    for (int j = 0; j < 16; j++) {
        float a0 = B0[j], a1 = B1[j];
#pragma unroll
        for (int k = 0; k < 16; k++) {
            a0 = fmaf(zr[k], W0l[k * 16 + j], a0);
            a1 = fmaf(zr[k], W1l[k * 16 + j], a1);
        }
        o0[j] = a0;
        o1[j] = a1;
    }
}

// ---------------------------------------------------------------------------
// Decode: out[i] = dot( y_{et}[src], z[dst] )  — fp32 output
__global__ void decode_kernel(const float* __restrict__ y0, const float* __restrict__ y1,
                              const float* __restrict__ z,
                              const int* __restrict__ pei, const int* __restrict__ pet,
                              const int* __restrict__ nei, const int* __restrict__ net_,
                              float* __restrict__ out,
                              const int* __restrict__ dflag) {
    int i = blockIdx.x * blockDim.x + threadIdx.x;
    if (i >= 2 * ED) return;
    int sft = dflag[0];
    const int* ei;
    const int* et;
    int e;
    if (i < ED) { ei = pei; et = pet; e = i; }
    else        { ei = nei; et = net_; e = i - ED; }
    int s = ei[(size_t)e << sft];
    int d = ei[(size_t)(ED + e) << sft];
    int r = et[(size_t)e << sft];
    const float4* yv = (const float4*)((r ? y1 : y0) + ((size_t)s << 4));
    const float4* zv = (const float4*)(z + ((size_t)d << 4));
    float acc = 0.0f;
#pragma unroll
    for (int q = 0; q < 4; q++) {
        float4 a = yv[q];
        float4 b = zv[q];
        acc += a.x * b.x + a.y * b.y + a.z * b.z + a.w * b.w;
    }
    out[i] = acc;
}

// ---------------------------------------------------------------------------
extern "C" void kernel_launch(void* const* d_in, const int* in_sizes, int n_in,
                              void* d_out, int out_size, void* d_ws, size_t ws_size,
                              hipStream_t stream) {
    const float* x_paper = (const float*)d_in[0];
    const float* x_mesh  = (const float*)d_in[1];
    const int* tei  = (const int*)d_in[2];
    const int* tet  = (const int*)d_in[3];
    const int* pei  = (const int*)d_in[4];
    const int* pet  = (const int*)d_in[5];
    const int* nei  = (const int*)d_in[6];
    const int* net_ = (const int*)d_in[7];
    const float* Wp  = (const float*)d_in[8];
    const float* bp  = (const float*)d_in[9];
    const float* Wm  = (const float*)d_in[10];
    const float* bm  = (const float*)d_in[11];
    const float* Wd0 = (const float*)d_in[12];
    const float* bd0 = (const float*)d_in[13];
    const float* Wd1 = (const float*)d_in[14];
    const float* bd1 = (const float*)d_in[15];
    const float* basesL[4] = {(const float*)d_in[16], (const float*)d_in[20],
                              (const float*)d_in[24], (const float*)d_in[28]};
    const float* compL[4]  = {(const float*)d_in[17], (const float*)d_in[21],
                              (const float*)d_in[25], (const float*)d_in[29]};
    const float* rootL[4]  = {(const float*)d_in[18], (const float*)d_in[22],
                              (const float*)d_in[26], (const float*)d_in[30]};
    const float* biasL[4]  = {(const float*)d_in[19], (const float*)d_in[23],
                              (const float*)d_in[27], (const float*)d_in[31]};

    // Workspace carve-up (fp32/int32 elements) — ~57 MB total
    float* ws = (float*)d_ws;
    size_t o = 0;
    float* bufA = ws + o; o += (size_t)NN * 32;
    float* bufB = ws + o; o += (size_t)NN * 32;
    float* h0   = ws + o; o += (size_t)NN * 32;
    float* h1   = ws + o; o += (size_t)NN * 32;
    float* inv  = ws + o; o += (size_t)TWO_NN;
    int*   cnt  = (int*)(ws + o); o += (size_t)TWO_NN;
    int*   off  = (int*)(ws + o); o += (size_t)TWO_NN + 4;
    int*   bsum = (int*)(ws + o); o += 256;
    int*   csr  = (int*)(ws + o); o += (size_t)ET;
    int*   gcur = (int*)(ws + o); o += 256;
    float* Wbuf = ws + o; o += 4096;
    int*   dflag = (int*)(ws + o); o += 16;
    // pairs alias h0/h1 (dead until first transform): 17.3 MB < 23 MB
    int2* pairs = (int2*)h0;

    // 0. Dtype detect
    detect_kernel<<<1, 64, 0, stream>>>(tei, dflag);

    // 1. Binned CSR build (once; edge structure is layer-invariant)
    init_gcur_kernel<<<1, 256, 0, stream>>>(gcur);
    binA_kernel<<<N_TILES, 256, 0, stream>>>(tei, tet, dflag, gcur, pairs);
    histB_kernel<<<NB_BKT, 256, 0, stream>>>(gcur, pairs, cnt);
    inv_kernel<<<(TWO_NN + 255) / 256, 256, 0, stream>>>(cnt, inv);
    scan_block_kernel<<<SCAN_BLKS, 256, 0, stream>>>(cnt, bsum);
    scan_bsum_kernel<<<1, 256, 0, stream>>>(bsum, SCAN_BLKS);
    scan_final_kernel<<<SCAN_BLKS, 256, 0, stream>>>(cnt, bsum, off);
    placeB_kernel<<<NB_BKT, 256, 0, stream>>>(gcur, pairs, off, csr);

    // 2. Input embed -> bufA [NN,16]
    embed_kernel<<<(NP + 255) / 256, 256, 0, stream>>>(x_paper, NP, Wp, bp, bufA);
    embed_kernel<<<(NM + 255) / 256, 256, 0, stream>>>(x_mesh, NM, Wm, bm,
                                                       bufA + (size_t)NP * 16);

    // 3. Four RGCN layers (ping-pong bufA/bufB), pull-mode aggregation
    float* xin = bufA;
    float* xout = bufB;
    for (int l = 0; l < 4; l++) {
        int din = (l == 0) ? 16 : 32;
        int dout = (l == 3) ? 16 : 32;
        int sz = din * dout;
        prep_weights_kernel<<<(sz + 255) / 256, 256, 0, stream>>>(
            basesL[l], compL[l], rootL[l], biasL[l], Wbuf, din, dout);
        int lpn = dout / 4;
        int nthreads = NN * lpn;
        int nblk = (nthreads + 255) / 256;
        if (l == 0)
            transform_t_kernel<16, 32, 0><<<nblk, 256, 0, stream>>>(xin, xout, h0, h1, Wbuf);
        else if (l == 3)
            transform_t_kernel<32, 16, 1><<<nblk, 256, 0, stream>>>(xin, xout, h0, h1, Wbuf);
        else
            transform_t_kernel<32, 32, 1><<<nblk, 256, 0, stream>>>(xin, xout, h0, h1, Wbuf);
        int shift = (dout == 32) ? 5 : 4;
        long total = (long)NN << (shift + 1); // dst x relation x feature
        aggregate_kernel<<<(int)((total + 255) / 256), 256, 0, stream>>>(
            off, csr, h0, h1, inv, xout, shift);
        float* t = xin; xin = xout; xout = t;
    }
    // z = xin [NN,16]

    // 4. Decode
    decode_prep_kernel<<<(NN + 255) / 256, 256, 0, stream>>>(xin, Wd0, bd0, Wd1, bd1,
                                                             h0, h1);
    decode_kernel<<<(2 * ED + 255) / 256, 256, 0, stream>>>(
        h0, h1, xin, pei, pet, nei, net_, (float*)d_out, dflag);
}

// Round 9
// 507.949 us; speedup vs baseline: 2.8982x; 1.2322x over previous
//
#include <hip/hip_runtime.h>
#include <hip/hip_bf16.h>

// Problem constants (from reference)
constexpr int NN = 90000;   // total nodes
constexpr int NP = 60000;   // paper nodes
constexpr int NM = 30000;   // mesh nodes
constexpr int ET = 2000000; // train edges
constexpr int ED = 400000;  // decode edges (each of pos/neg)
constexpr int TWO_NN = 2 * NN;
constexpr int SCAN_BLKS = (TWO_NN + 1023) / 1024; // 176

// Binned CSR build parameters
constexpr int BKT_SH  = 10;                        // 1024 keys per bucket
constexpr int NB_BKT  = (TWO_NN + 1023) >> BKT_SH; // 176 buckets
constexpr int BKT_CAP = 12288;                     // mean 11366, +8.7 sigma
constexpr int TILE    = 2048;                      // edges per binning tile
constexpr int N_TILES = (ET + TILE - 1) / TILE;    // 977

// ---------------------------------------------------------------------------
__global__ void detect_kernel(const int* __restrict__ tei, int* __restrict__ flag) {
    if (blockIdx.x == 0 && threadIdx.x == 0) {
        int allzero = 1;
        for (int i = 0; i < 16; i++)
            if (tei[2 * i + 1] != 0) allzero = 0;
        flag[0] = allzero; // 1 => int64 => index shift 1
    }
}

__global__ void init_gcur_kernel(int* __restrict__ gcur) {
    int b = blockIdx.x * blockDim.x + threadIdx.x;
    if (b < NB_BKT) gcur[b] = b * BKT_CAP;
}

// ---------------------------------------------------------------------------
// Pass A: bin edges into per-bucket pair arrays with line-dense writes.
__global__ void __launch_bounds__(256) binA_kernel(
        const int* __restrict__ ei, const int* __restrict__ et,
        const int* __restrict__ dflag, int* __restrict__ gcur,
        int2* __restrict__ pairs) {
    __shared__ int hist[NB_BKT];
    __shared__ int excl[NB_BKT];
    __shared__ int cur[NB_BKT];
    __shared__ int gbase[NB_BKT];
    __shared__ int scn[256];
    __shared__ int2 tbuf[TILE];
    int t = threadIdx.x;
    int tile0 = blockIdx.x * TILE;
    int tcount = ET - tile0;
    if (tcount > TILE) tcount = TILE;
    for (int i = t; i < NB_BKT; i += 256) hist[i] = 0;
    __syncthreads();
    int sft = dflag[0];
    int myk[8], mys[8];
#pragma unroll
    for (int q = 0; q < 8; q++) {
        int li = q * 256 + t;
        myk[q] = -1;
        if (li < tcount) {
            int e = tile0 + li;
            int s = ei[(size_t)e << sft];
            int d = ei[(size_t)(ET + e) << sft];
            int r = et[(size_t)e << sft];
            int key = r * NN + d;
            myk[q] = key;
            mys[q] = s;
            atomicAdd(&hist[key >> BKT_SH], 1);
        }
    }
    __syncthreads();
    int v = (t < NB_BKT) ? hist[t] : 0;
    scn[t] = v;
    __syncthreads();
    for (int st = 1; st < 256; st <<= 1) {
        int u = (t >= st) ? scn[t - st] : 0;
        __syncthreads();
        scn[t] += u;
        __syncthreads();
    }
    if (t < NB_BKT) {
        excl[t] = scn[t] - v;
        cur[t] = scn[t] - v;
    }
    __syncthreads();
#pragma unroll
    for (int q = 0; q < 8; q++) {
        if (myk[q] >= 0) {
            int b = myk[q] >> BKT_SH;
            int p = atomicAdd(&cur[b], 1);
            tbuf[p] = make_int2(myk[q], mys[q]);
        }
    }
    __syncthreads();
    if (t < NB_BKT && hist[t] > 0) gbase[t] = atomicAdd(&gcur[t], hist[t]);
    __syncthreads();
    for (int i = t; i < tcount; i += 256) {
        int2 p = tbuf[i];
        int b = p.x >> BKT_SH;
        int gpos = gbase[b] + (i - excl[b]);
        int cap = (b + 1) * BKT_CAP - 1;
        pairs[gpos < cap ? gpos : cap] = p;
    }
}

// ---------------------------------------------------------------------------
// Pass B1: per-bucket key histogram (LDS) -> cnt written densely.
__global__ void __launch_bounds__(256) histB_kernel(
        const int* __restrict__ gcur, const int2* __restrict__ pairs,
        int* __restrict__ cnt) {
    __shared__ int kh[1024];
    int b = blockIdx.x;
    int t = threadIdx.x;
    for (int i = t; i < 1024; i += 256) kh[i] = 0;
    __syncthreads();
    int beg = b * BKT_CAP, end = gcur[b];
    for (int i = beg + t; i < end; i += 256)
        atomicAdd(&kh[pairs[i].x & 1023], 1);
    __syncthreads();
    int kbase = b << BKT_SH;
    for (int i = t; i < 1024; i += 256)
        if (kbase + i < TWO_NN) cnt[kbase + i] = kh[i];
}

__global__ void inv_kernel(const int* __restrict__ cnt, float* __restrict__ inv) {
    int i = blockIdx.x * blockDim.x + threadIdx.x;
    if (i < TWO_NN) {
        int c = cnt[i];
        inv[i] = 1.0f / (float)(c > 1 ? c : 1);
    }
}

// ---------------------------------------------------------------------------
// Hierarchical exclusive scan of cnt[0..2NN) -> off
__global__ void scan_block_kernel(const int* __restrict__ cnt, int* __restrict__ bsum) {
    __shared__ int lds[256];
    int base = blockIdx.x * 1024;
    int t = threadIdx.x;
    int s = 0;
#pragma unroll
    for (int q = 0; q < 4; q++) {
        int i = base + t * 4 + q;
        s += (i < TWO_NN) ? cnt[i] : 0;
    }
    lds[t] = s;
    __syncthreads();
    for (int st = 128; st > 0; st >>= 1) {
        if (t < st) lds[t] += lds[t + st];
        __syncthreads();
    }
    if (t == 0) bsum[blockIdx.x] = lds[0];
}

__global__ void scan_bsum_kernel(int* __restrict__ bsum, int nb) {
    __shared__ int lds[256];
    int t = threadIdx.x;
    lds[t] = (t < nb) ? bsum[t] : 0;
    __syncthreads();
    for (int st = 1; st < 256; st <<= 1) {
        int v = (t >= st) ? lds[t - st] : 0;
        __syncthreads();
        lds[t] += v;
        __syncthreads();
    }
    if (t < nb) bsum[t] = (t > 0) ? lds[t - 1] : 0;
}

__global__ void scan_final_kernel(const int* __restrict__ cnt, const int* __restrict__ bsum,
                                  int* __restrict__ off) {
    __shared__ int lds[256];
    int base = blockIdx.x * 1024;
    int t = threadIdx.x;
    int v[4];
    int s = 0;
#pragma unroll
    for (int q = 0; q < 4; q++) {
        int i = base + t * 4 + q;
        v[q] = (i < TWO_NN) ? cnt[i] : 0;
        s += v[q];
    }
    lds[t] = s;
    __syncthreads();
    for (int st = 1; st < 256; st <<= 1) {
        int u = (t >= st) ? lds[t - st] : 0;
        __syncthreads();
        lds[t] += u;
        __syncthreads();
    }
    int run = bsum[blockIdx.x] + lds[t] - s;
#pragma unroll
    for (int q = 0; q < 4; q++) {
        int i = base + t * 4 + q;
        if (i < TWO_NN) off[i] = run;
        run += v[q];
    }
    if (blockIdx.x == 0 && t == 0) off[TWO_NN] = ET;
}

// ---------------------------------------------------------------------------
// Pass B2: place pairs into final CSR (bucket range contiguous -> L2-hot).
__global__ void __launch_bounds__(256) placeB_kernel(
        const int* __restrict__ gcur, const int2* __restrict__ pairs,
        const int* __restrict__ off, int* __restrict__ csr) {
    __shared__ int kc[1024];
    int b = blockIdx.x;
    int t = threadIdx.x;
    int kbase = b << BKT_SH;
    for (int i = t; i < 1024; i += 256)
        if (kbase + i < TWO_NN) kc[i] = off[kbase + i];
    __syncthreads();
    int beg = b * BKT_CAP, end = gcur[b];
    for (int i = beg + t; i < end; i += 256) {
        int2 p = pairs[i];
        int pos = atomicAdd(&kc[p.x & 1023], 1);
        csr[pos] = p.y;
    }
}

// ---------------------------------------------------------------------------
// Input embed: out[n] = X[n] (128, fp32) @ W (128x16, fp32) + b
__global__ void embed_kernel(const float* __restrict__ X, int rows,
                             const float* __restrict__ W,
                             const float* __restrict__ b,
                             float* __restrict__ out) {
    __shared__ float Wl[128 * 16];
    __shared__ float bl[16];
    for (int i = threadIdx.x; i < 128 * 16; i += blockDim.x) Wl[i] = W[i];
    if (threadIdx.x < 16) bl[threadIdx.x] = b[threadIdx.x];
    __syncthreads();
    int n = blockIdx.x * blockDim.x + threadIdx.x;
    if (n >= rows) return;
    float acc[16];
#pragma unroll
    for (int j = 0; j < 16; j++) acc[j] = bl[j];
    const float4* row = (const float4*)(X + (size_t)n * 128);
    for (int k4 = 0; k4 < 32; k4++) {
        float4 xv = row[k4];
        int k = k4 * 4;
#pragma unroll
        for (int j = 0; j < 16; j++) {
            float a = acc[j];
            a = fmaf(xv.x, Wl[(k + 0) * 16 + j], a);
            a = fmaf(xv.y, Wl[(k + 1) * 16 + j], a);
            a = fmaf(xv.z, Wl[(k + 2) * 16 + j], a);
            a = fmaf(xv.w, Wl[(k + 3) * 16 + j], a);
            acc[j] = a;
        }
    }
    float4* o = (float4*)(out + (size_t)n * 16);
#pragma unroll
    for (int q = 0; q < 4; q++)
        o[q] = make_float4(acc[4 * q], acc[4 * q + 1], acc[4 * q + 2], acc[4 * q + 3]);
}

// ---------------------------------------------------------------------------
// Combine bases with comp into per-relation W, plus copies of root/bias.
__global__ void prep_weights_kernel(const float* __restrict__ bases,
                                    const float* __restrict__ comp,
                                    const float* __restrict__ root,
                                    const float* __restrict__ bias,
                                    float* __restrict__ Wbuf, int din, int dout) {
    int sz = din * dout;
    int i = blockIdx.x * blockDim.x + threadIdx.x;
    if (i < sz) {
        float b0 = bases[i];
        float b1 = bases[sz + i];
        float b2 = bases[2 * sz + i];
        float b3 = bases[3 * sz + i];
        for (int r = 0; r < 2; r++) {
            Wbuf[r * sz + i] = comp[r * 4 + 0] * b0 + comp[r * 4 + 1] * b1 +
                               comp[r * 4 + 2] * b2 + comp[r * 4 + 3] * b3;
        }
        Wbuf[2 * sz + i] = root[i];
    }
    if (i < dout) Wbuf[3 * sz + i] = bias[i];
}

// ---------------------------------------------------------------------------
// Node transform, templated: DOUT/4 lanes per node, float4 stores.
template <int DIN, int DOUT, int RELU>
__global__ void __launch_bounds__(256) transform_t_kernel(
        const float* __restrict__ x, float* __restrict__ out,
        float* __restrict__ h0, float* __restrict__ h1,
        const float* __restrict__ Wbuf) {
    constexpr int SZ = DIN * DOUT;
    constexpr int LPN = DOUT / 4; // lanes per node
    __shared__ float Wl[3 * SZ + DOUT];
    for (int i = threadIdx.x; i < 3 * SZ + DOUT; i += 256) Wl[i] = Wbuf[i];
    __syncthreads();
    int gid = blockIdx.x * 256 + threadIdx.x;
    int n = gid / LPN;
    if (n >= NN) return;
    int j0 = (gid % LPN) * 4;
    float xr[DIN];
    const float4* xp = (const float4*)(x + (size_t)n * DIN);
#pragma unroll
    for (int k4 = 0; k4 < DIN / 4; k4++) {
        float4 v = xp[k4];
        if (RELU) {
            v.x = fmaxf(v.x, 0.0f); v.y = fmaxf(v.y, 0.0f);
            v.z = fmaxf(v.z, 0.0f); v.w = fmaxf(v.w, 0.0f);
        }
        xr[4 * k4 + 0] = v.x; xr[4 * k4 + 1] = v.y;
        xr[4 * k4 + 2] = v.z; xr[4 * k4 + 3] = v.w;
    }
    float a0[4] = {0, 0, 0, 0}, a1[4] = {0, 0, 0, 0}, ar[4];
#pragma unroll
    for (int jj = 0; jj < 4; jj++) ar[jj] = Wl[3 * SZ + j0 + jj];
#pragma unroll
    for (int k = 0; k < DIN; k++) {
        float xv = xr[k];
        const float* w0 = &Wl[k * DOUT + j0];
        const float* w1 = &Wl[SZ + k * DOUT + j0];
        const float* wr = &Wl[2 * SZ + k * DOUT + j0];
#pragma unroll
        for (int jj = 0; jj < 4; jj++) {
            a0[jj] = fmaf(xv, w0[jj], a0[jj]);
            a1[jj] = fmaf(xv, w1[jj], a1[jj]);
            ar[jj] = fmaf(xv, wr[jj], ar[jj]);
        }
    }
    size_t base = (size_t)n * DOUT + j0;
    *(float4*)(h0 + base)  = make_float4(a0[0], a0[1], a0[2], a0[3]);
    *(float4*)(h1 + base)  = make_float4(a1[0], a1[1], a1[2], a1[3]);
    *(float4*)(out + base) = make_float4(ar[0], ar[1], ar[2], ar[3]);
}

// ---------------------------------------------------------------------------
// Pull-mode aggregation, float4 per lane: F/4 lanes per (dst, relation) group.
// One wave-wide gather instruction touches 8 distinct h-rows (dout=32) vs 1-2
// in the scalar version -> 4-8x more cache lines in flight (R8: latency-bound
// at 1.78 TB/s, VALUBusy only 26%). r0/r1 combined in-wave via shfl_down.
template <int SHIFT>
__global__ void __launch_bounds__(256) aggregate_v_kernel(
        const int* __restrict__ off, const int* __restrict__ csr,
        const float* __restrict__ h0, const float* __restrict__ h1,
        const float* __restrict__ inv, float* __restrict__ out) {
    constexpr int GL = (1 << SHIFT) / 4; // lanes per (dst, relation) group
    int gid = blockIdx.x * 256 + threadIdx.x;
    int gg = gid / GL;   // group index: d = gg>>1, r = gg&1
    int d = gg >> 1;
    if (d >= NN) return;
    int r = gg & 1;
    int lane = gid % GL; // feature-quad index
    const float* h = (r ? h1 : h0) + lane * 4;
    int b = off[r * NN + d];
    int e = off[r * NN + d + 1];
    float4 aa = make_float4(0, 0, 0, 0), ab = make_float4(0, 0, 0, 0);
    int k = b;
    for (; k + 1 < e; k += 2) {
        int s0 = csr[k];
        int s1 = csr[k + 1];
        float4 va = *(const float4*)(h + ((size_t)s0 << SHIFT));
        float4 vb = *(const float4*)(h + ((size_t)s1 << SHIFT));
        aa.x += va.x; aa.y += va.y; aa.z += va.z; aa.w += va.w;
        ab.x += vb.x; ab.y += vb.y; ab.z += vb.z; ab.w += vb.w;
    }
    if (k < e) {
        float4 va = *(const float4*)(h + ((size_t)csr[k] << SHIFT));
        aa.x += va.x; aa.y += va.y; aa.z += va.z; aa.w += va.w;
    }
    float iv = inv[r * NN + d];
    float sx = (aa.x + ab.x) * iv, sy = (aa.y + ab.y) * iv;
    float sz = (aa.z + ab.z) * iv, sw = (aa.w + ab.w) * iv;
    float px = __shfl_down(sx, GL, 64);
    float py = __shfl_down(sy, GL, 64);
    float pz = __shfl_down(sz, GL, 64);
    float pw = __shfl_down(sw, GL, 64);
    if (r == 0) {
        float4* op = (float4*)(out + ((size_t)d << SHIFT)) + lane;
        float4 c = *op;
        *op = make_float4(c.x + sx + px, c.y + sy + py, c.z + sz + pz, c.w + sw + pw);
    }
}

// ---------------------------------------------------------------------------
// Decode prep: y0 = z @ Wd0 + bd0 ; y1 = z @ Wd1 + bd1   (all 16-dim)
__global__ void decode_prep_kernel(const float* __restrict__ z,
                                   const float* __restrict__ Wd0,
                                   const float* __restrict__ bd0,
                                   const float* __restrict__ Wd1,
                                   const float* __restrict__ bd1,
                                   float* __restrict__ y0, float* __restrict__ y1) {
    __shared__ float W0l[256], W1l[256], B0[16], B1[16];
    for (int i = threadIdx.x; i < 256; i += blockDim.x) {
        W0l[i] = Wd0[i];
        W1l[i] = Wd1[i];
    }
    if (threadIdx.x < 16) {
        B0[threadIdx.x] = bd0[threadIdx.x];
        B1[threadIdx.x] = bd1[threadIdx.x];
    }
    __syncthreads();
    int n = blockIdx.x * blockDim.x + threadIdx.x;
    if (n >= NN) return;
    float zr[16];
    const float* zp = z + (size_t)n * 16;
#pragma unroll
    for (int k = 0; k < 16; k++) zr[k] = zp[k];
    float o0[16], o1[16];
#pragma unroll
    for (int j = 0; j < 16; j++) {
        float a0 = B0[j], a1 = B1[j];
#pragma unroll
        for (int k = 0; k < 16; k++) {
            a0 = fmaf(zr[k], W0l[k * 16 + j], a0);
            a1 = fmaf(zr[k], W1l[k * 16 + j], a1);
        }
        o0[j] = a0;
        o1[j] = a1;
    }
    float4* p0 = (float4*)(y0 + (size_t)n * 16);
    float4* p1 = (float4*)(y1 + (size_t)n * 16);
#pragma unroll
    for (int q = 0; q < 4; q++) {
        p0[q] = make_float4(o0[4 * q], o0[4 * q + 1], o0[4 * q + 2], o0[4 * q + 3]);
        p1[q] = make_float4(o1[4 * q], o1[4 * q + 1], o1[4 * q + 2], o1[4 * q + 3]);
    }
}

// ---------------------------------------------------------------------------
// Decode: out[i] = dot( y_{et}[src], z[dst] )  — fp32 output
__global__ void decode_kernel(const float* __restrict__ y0, const float* __restrict__ y1,
                              const float* __restrict__ z,
                              const int* __restrict__ pei, const int* __restrict__ pet,
                              const int* __restrict__ nei, const int* __restrict__ net_,
                              float* __restrict__ out,
                              const int* __restrict__ dflag) {
    int i = blockIdx.x * blockDim.x + threadIdx.x;
    if (i >= 2 * ED) return;
    int sft = dflag[0];
    const int* ei;
    const int* et;
    int e;
    if (i < ED) { ei = pei; et = pet; e = i; }
    else        { ei = nei; et = net_; e = i - ED; }
    int s = ei[(size_t)e << sft];
    int d = ei[(size_t)(ED + e) << sft];
    int r = et[(size_t)e << sft];
    const float4* yv = (const float4*)((r ? y1 : y0) + ((size_t)s << 4));
    const float4* zv = (const float4*)(z + ((size_t)d << 4));
    float acc = 0.0f;
#pragma unroll
    for (int q = 0; q < 4; q++) {
        float4 a = yv[q];
        float4 b = zv[q];
        acc += a.x * b.x + a.y * b.y + a.z * b.z + a.w * b.w;
    }
    out[i] = acc;
}

// ---------------------------------------------------------------------------
extern "C" void kernel_launch(void* const* d_in, const int* in_sizes, int n_in,
                              void* d_out, int out_size, void* d_ws, size_t ws_size,
                              hipStream_t stream) {
    const float* x_paper = (const float*)d_in[0];
    const float* x_mesh  = (const float*)d_in[1];
    const int* tei  = (const int*)d_in[2];
    const int* tet  = (const int*)d_in[3];
    const int* pei  = (const int*)d_in[4];
    const int* pet  = (const int*)d_in[5];
    const int* nei  = (const int*)d_in[6];
    const int* net_ = (const int*)d_in[7];
    const float* Wp  = (const float*)d_in[8];
    const float* bp  = (const float*)d_in[9];
    const float* Wm  = (const float*)d_in[10];
    const float* bm  = (const float*)d_in[11];
    const float* Wd0 = (const float*)d_in[12];
    const float* bd0 = (const float*)d_in[13];
    const float* Wd1 = (const float*)d_in[14];
    const float* bd1 = (const float*)d_in[15];
    const float* basesL[4] = {(const float*)d_in[16], (const float*)d_in[20],
                              (const float*)d_in[24], (const float*)d_in[28]};
    const float* compL[4]  = {(const float*)d_in[17], (const float*)d_in[21],
                              (const float*)d_in[25], (const float*)d_in[29]};
    const float* rootL[4]  = {(const float*)d_in[18], (const float*)d_in[22],
                              (const float*)d_in[26], (const float*)d_in[30]};
    const float* biasL[4]  = {(const float*)d_in[19], (const float*)d_in[23],
                              (const float*)d_in[27], (const float*)d_in[31]};

    // Workspace carve-up (fp32/int32 elements) — ~57 MB total
    float* ws = (float*)d_ws;
    size_t o = 0;
    float* bufA = ws + o; o += (size_t)NN * 32;
    float* bufB = ws + o; o += (size_t)NN * 32;
    float* h0   = ws + o; o += (size_t)NN * 32;
    float* h1   = ws + o; o += (size_t)NN * 32;
    float* inv  = ws + o; o += (size_t)TWO_NN;
    int*   cnt  = (int*)(ws + o); o += (size_t)TWO_NN;
    int*   off  = (int*)(ws + o); o += (size_t)TWO_NN + 4;
    int*   bsum = (int*)(ws + o); o += 256;
    int*   csr  = (int*)(ws + o); o += (size_t)ET;
    int*   gcur = (int*)(ws + o); o += 256;
    float* Wbuf = ws + o; o += 4096;
    int*   dflag = (int*)(ws + o); o += 16;
    // pairs alias h0/h1 (dead until first transform): 17.3 MB < 23 MB
    int2* pairs = (int2*)h0;

    // 0. Dtype detect
    detect_kernel<<<1, 64, 0, stream>>>(tei, dflag);

    // 1. Binned CSR build (once; edge structure is layer-invariant)
    init_gcur_kernel<<<1, 256, 0, stream>>>(gcur);
    binA_kernel<<<N_TILES, 256, 0, stream>>>(tei, tet, dflag, gcur, pairs);
    histB_kernel<<<NB_BKT, 256, 0, stream>>>(gcur, pairs, cnt);
    inv_kernel<<<(TWO_NN + 255) / 256, 256, 0, stream>>>(cnt, inv);
    scan_block_kernel<<<SCAN_BLKS, 256, 0, stream>>>(cnt, bsum);
    scan_bsum_kernel<<<1, 256, 0, stream>>>(bsum, SCAN_BLKS);
    scan_final_kernel<<<SCAN_BLKS, 256, 0, stream>>>(cnt, bsum, off);
    placeB_kernel<<<NB_BKT, 256, 0, stream>>>(gcur, pairs, off, csr);

    // 2. Input embed -> bufA [NN,16]
    embed_kernel<<<(NP + 255) / 256, 256, 0, stream>>>(x_paper, NP, Wp, bp, bufA);
    embed_kernel<<<(NM + 255) / 256, 256, 0, stream>>>(x_mesh, NM, Wm, bm,
                                                       bufA + (size_t)NP * 16);

    // 3. Four RGCN layers (ping-pong bufA/bufB), pull-mode aggregation
    float* xin = bufA;
    float* xout = bufB;
    for (int l = 0; l < 4; l++) {
        int din = (l == 0) ? 16 : 32;
        int dout = (l == 3) ? 16 : 32;
        int sz = din * dout;
        prep_weights_kernel<<<(sz + 255) / 256, 256, 0, stream>>>(
            basesL[l], compL[l], rootL[l], biasL[l], Wbuf, din, dout);
        int lpn = dout / 4;
        int nblk = (NN * lpn + 255) / 256;
        if (l == 0)
            transform_t_kernel<16, 32, 0><<<nblk, 256, 0, stream>>>(xin, xout, h0, h1, Wbuf);
        else if (l == 3)
            transform_t_kernel<32, 16, 1><<<nblk, 256, 0, stream>>>(xin, xout, h0, h1, Wbuf);
        else
            transform_t_kernel<32, 32, 1><<<nblk, 256, 0, stream>>>(xin, xout, h0, h1, Wbuf);
        // aggregation: NN * 2 relations * (dout/4) lanes
        int gl = dout / 4;
        long tot = (long)NN * 2 * gl;
        int ablk = (int)((tot + 255) / 256);
        if (dout == 32)
            aggregate_v_kernel<5><<<ablk, 256, 0, stream>>>(off, csr, h0, h1, inv, xout);
        else
            aggregate_v_kernel<4><<<ablk, 256, 0, stream>>>(off, csr, h0, h1, inv, xout);
        float* t = xin; xin = xout; xout = t;
    }
    // z = xin [NN,16]

    // 4. Decode
    decode_prep_kernel<<<(NN + 255) / 256, 256, 0, stream>>>(xin, Wd0, bd0, Wd1, bd1,
                                                             h0, h1);
    decode_kernel<<<(2 * ED + 255) / 256, 256, 0, stream>>>(
        h0, h1, xin, pei, pet, nei, net_, (float*)d_out, dflag);
}

// Round 10
// 488.386 us; speedup vs baseline: 3.0143x; 1.0401x over previous
//
#include <hip/hip_runtime.h>
#include <hip/hip_bf16.h>

// Problem constants (from reference)
constexpr int NN = 90000;   // total nodes
constexpr int NP = 60000;   // paper nodes
constexpr int NM = 30000;   // mesh nodes
constexpr int ET = 2000000; // train edges
constexpr int ED = 400000;  // decode edges (each of pos/neg)
constexpr int TWO_NN = 2 * NN;
constexpr int SCAN_BLKS = (TWO_NN + 1023) / 1024; // 176

// Binned CSR build parameters
constexpr int BKT_SH  = 10;                        // 1024 keys per bucket
constexpr int NB_BKT  = (TWO_NN + 1023) >> BKT_SH; // 176 buckets
constexpr int BKT_CAP = 12288;                     // mean 11366, +8.7 sigma
constexpr int TILE    = 2048;                      // edges per binning tile
constexpr int N_TILES = (ET + TILE - 1) / TILE;    // 977

// ---------------------------------------------------------------------------
__global__ void detect_kernel(const int* __restrict__ tei, int* __restrict__ flag) {
    if (blockIdx.x == 0 && threadIdx.x == 0) {
        int allzero = 1;
        for (int i = 0; i < 16; i++)
            if (tei[2 * i + 1] != 0) allzero = 0;
        flag[0] = allzero; // 1 => int64 => index shift 1
    }
}

__global__ void init_gcur_kernel(int* __restrict__ gcur) {
    int b = blockIdx.x * blockDim.x + threadIdx.x;
    if (b < NB_BKT) gcur[b] = b * BKT_CAP;
}

// ---------------------------------------------------------------------------
// Pass A: bin edges into per-bucket pair arrays with line-dense writes.
__global__ void __launch_bounds__(256) binA_kernel(
        const int* __restrict__ ei, const int* __restrict__ et,
        const int* __restrict__ dflag, int* __restrict__ gcur,
        int2* __restrict__ pairs) {
    __shared__ int hist[NB_BKT];
    __shared__ int excl[NB_BKT];
    __shared__ int cur[NB_BKT];
    __shared__ int gbase[NB_BKT];
    __shared__ int scn[256];
    __shared__ int2 tbuf[TILE];
    int t = threadIdx.x;
    int tile0 = blockIdx.x * TILE;
    int tcount = ET - tile0;
    if (tcount > TILE) tcount = TILE;
    for (int i = t; i < NB_BKT; i += 256) hist[i] = 0;
    __syncthreads();
    int sft = dflag[0];
    int myk[8], mys[8];
#pragma unroll
    for (int q = 0; q < 8; q++) {
        int li = q * 256 + t;
        myk[q] = -1;
        if (li < tcount) {
            int e = tile0 + li;
            int s = ei[(size_t)e << sft];
            int d = ei[(size_t)(ET + e) << sft];
            int r = et[(size_t)e << sft];
            int key = r * NN + d;
            myk[q] = key;
            mys[q] = s;
            atomicAdd(&hist[key >> BKT_SH], 1);
        }
    }
    __syncthreads();
    int v = (t < NB_BKT) ? hist[t] : 0;
    scn[t] = v;
    __syncthreads();
    for (int st = 1; st < 256; st <<= 1) {
        int u = (t >= st) ? scn[t - st] : 0;
        __syncthreads();
        scn[t] += u;
        __syncthreads();
    }
    if (t < NB_BKT) {
        excl[t] = scn[t] - v;
        cur[t] = scn[t] - v;
    }
    __syncthreads();
#pragma unroll
    for (int q = 0; q < 8; q++) {
        if (myk[q] >= 0) {
            int b = myk[q] >> BKT_SH;
            int p = atomicAdd(&cur[b], 1);
            tbuf[p] = make_int2(myk[q], mys[q]);
        }
    }
    __syncthreads();
    if (t < NB_BKT && hist[t] > 0) gbase[t] = atomicAdd(&gcur[t], hist[t]);
    __syncthreads();
    for (int i = t; i < tcount; i += 256) {
        int2 p = tbuf[i];
        int b = p.x >> BKT_SH;
        int gpos = gbase[b] + (i - excl[b]);
        int cap = (b + 1) * BKT_CAP - 1;
        pairs[gpos < cap ? gpos : cap] = p;
    }
}

// ---------------------------------------------------------------------------
// Pass B1: per-bucket key histogram (LDS) -> cnt written densely.
__global__ void __launch_bounds__(256) histB_kernel(
        const int* __restrict__ gcur, const int2* __restrict__ pairs,
        int* __restrict__ cnt) {
    __shared__ int kh[1024];
    int b = blockIdx.x;
    int t = threadIdx.x;
    for (int i = t; i < 1024; i += 256) kh[i] = 0;
    __syncthreads();
    int beg = b * BKT_CAP, end = gcur[b];
    for (int i = beg + t; i < end; i += 256)
        atomicAdd(&kh[pairs[i].x & 1023], 1);
    __syncthreads();
    int kbase = b << BKT_SH;
    for (int i = t; i < 1024; i += 256)
        if (kbase + i < TWO_NN) cnt[kbase + i] = kh[i];
}

__global__ void inv_kernel(const int* __restrict__ cnt, float* __restrict__ inv) {
    int i = blockIdx.x * blockDim.x + threadIdx.x;
    if (i < TWO_NN) {
        int c = cnt[i];
        inv[i] = 1.0f / (float)(c > 1 ? c : 1);
    }
}

// ---------------------------------------------------------------------------
// Hierarchical exclusive scan of cnt[0..2NN) -> off
__global__ void scan_block_kernel(const int* __restrict__ cnt, int* __restrict__ bsum) {
    __shared__ int lds[256];
    int base = blockIdx.x * 1024;
    int t = threadIdx.x;
    int s = 0;
#pragma unroll
    for (int q = 0; q < 4; q++) {
        int i = base + t * 4 + q;
        s += (i < TWO_NN) ? cnt[i] : 0;
    }
    lds[t] = s;
    __syncthreads();
    for (int st = 128; st > 0; st >>= 1) {
        if (t < st) lds[t] += lds[t + st];
        __syncthreads();
    }
    if (t == 0) bsum[blockIdx.x] = lds[0];
}

__global__ void scan_bsum_kernel(int* __restrict__ bsum, int nb) {
    __shared__ int lds[256];
    int t = threadIdx.x;
    lds[t] = (t < nb) ? bsum[t] : 0;
    __syncthreads();
    for (int st = 1; st < 256; st <<= 1) {
        int v = (t >= st) ? lds[t - st] : 0;
        __syncthreads();
        lds[t] += v;
        __syncthreads();
    }
    if (t < nb) bsum[t] = (t > 0) ? lds[t - 1] : 0;
}

__global__ void scan_final_kernel(const int* __restrict__ cnt, const int* __restrict__ bsum,
                                  int* __restrict__ off) {
    __shared__ int lds[256];
    int base = blockIdx.x * 1024;
    int t = threadIdx.x;
    int v[4];
    int s = 0;
#pragma unroll
    for (int q = 0; q < 4; q++) {
        int i = base + t * 4 + q;
        v[q] = (i < TWO_NN) ? cnt[i] : 0;
        s += v[q];
    }
    lds[t] = s;
    __syncthreads();
    for (int st = 1; st < 256; st <<= 1) {
        int u = (t >= st) ? lds[t - st] : 0;
        __syncthreads();
        lds[t] += u;
        __syncthreads();
    }
    int run = bsum[blockIdx.x] + lds[t] - s;
#pragma unroll
    for (int q = 0; q < 4; q++) {
        int i = base + t * 4 + q;
        if (i < TWO_NN) off[i] = run;
        run += v[q];
    }
    if (blockIdx.x == 0 && t == 0) off[TWO_NN] = ET;
}

// ---------------------------------------------------------------------------
// Pass B2: place pairs into final CSR (bucket range contiguous -> L2-hot).
__global__ void __launch_bounds__(256) placeB_kernel(
        const int* __restrict__ gcur, const int2* __restrict__ pairs,
        const int* __restrict__ off, int* __restrict__ csr) {
    __shared__ int kc[1024];
    int b = blockIdx.x;
    int t = threadIdx.x;
    int kbase = b << BKT_SH;
    for (int i = t; i < 1024; i += 256)
        if (kbase + i < TWO_NN) kc[i] = off[kbase + i];
    __syncthreads();
    int beg = b * BKT_CAP, end = gcur[b];
    for (int i = beg + t; i < end; i += 256) {
        int2 p = pairs[i];
        int pos = atomicAdd(&kc[p.x & 1023], 1);
        csr[pos] = p.y;
    }
}

// ---------------------------------------------------------------------------
// Input embed: out[n] = X[n] (128, fp32) @ W (128x16, fp32) + b
__global__ void embed_kernel(const float* __restrict__ X, int rows,
                             const float* __restrict__ W,
                             const float* __restrict__ b,
                             float* __restrict__ out) {
    __shared__ float Wl[128 * 16];
    __shared__ float bl[16];
    for (int i = threadIdx.x; i < 128 * 16; i += blockDim.x) Wl[i] = W[i];
    if (threadIdx.x < 16) bl[threadIdx.x] = b[threadIdx.x];
    __syncthreads();
    int n = blockIdx.x * blockDim.x + threadIdx.x;
    if (n >= rows) return;
    float acc[16];
#pragma unroll
    for (int j = 0; j < 16; j++) acc[j] = bl[j];
    const float4* row = (const float4*)(X + (size_t)n * 128);
    for (int k4 = 0; k4 < 32; k4++) {
        float4 xv = row[k4];
        int k = k4 * 4;
#pragma unroll
        for (int j = 0; j < 16; j++) {
            float a = acc[j];
            a = fmaf(xv.x, Wl[(k + 0) * 16 + j], a);
            a = fmaf(xv.y, Wl[(k + 1) * 16 + j], a);
            a = fmaf(xv.z, Wl[(k + 2) * 16 + j], a);
            a = fmaf(xv.w, Wl[(k + 3) * 16 + j], a);
            acc[j] = a;
        }
    }
    float4* o = (float4*)(out + (size_t)n * 16);
#pragma unroll
    for (int q = 0; q < 4; q++)
        o[q] = make_float4(acc[4 * q], acc[4 * q + 1], acc[4 * q + 2], acc[4 * q + 3]);
}

// ---------------------------------------------------------------------------
// Combine bases with comp into per-relation W, plus copies of root/bias.
// Wbuf layout: [W0 (sz) | W1 (sz) | root (sz) | bias (dout)]
__global__ void prep_weights_kernel(const float* __restrict__ bases,
                                    const float* __restrict__ comp,
                                    const float* __restrict__ root,
                                    const float* __restrict__ bias,
                                    float* __restrict__ Wbuf, int din, int dout) {
    int sz = din * dout;
    int i = blockIdx.x * blockDim.x + threadIdx.x;
    if (i < sz) {
        float b0 = bases[i];
        float b1 = bases[sz + i];
        float b2 = bases[2 * sz + i];
        float b3 = bases[3 * sz + i];
        for (int r = 0; r < 2; r++) {
            Wbuf[r * sz + i] = comp[r * 4 + 0] * b0 + comp[r * 4 + 1] * b1 +
                               comp[r * 4 + 2] * b2 + comp[r * 4 + 3] * b3;
        }
        Wbuf[2 * sz + i] = root[i];
    }
    if (i < dout) Wbuf[3 * sz + i] = bias[i];
}

// ---------------------------------------------------------------------------
// Aggregate raw x rows per (dst, relation): aggR[d] = sum_{s in N_r(d)} x[s].
// W_r is linear, so transform is applied AFTER aggregation (combine_kernel):
// halves the gather working set (one x table vs h0+h1) and both relations
// reuse the same rows in cache (R9: FETCH 119 MB vs 23 MB table).
template <int DIN>
__global__ void __launch_bounds__(256) aggregate_x_kernel(
        const int* __restrict__ off, const int* __restrict__ csr,
        const float* __restrict__ x,
        float* __restrict__ aggA, float* __restrict__ aggB) {
    constexpr int GL = DIN / 4; // lanes per (dst, relation) group
    int gid = blockIdx.x * 256 + threadIdx.x;
    int grp = gid / GL;
    int d = grp >> 1;
    if (d >= NN) return;
    int r = grp & 1;
    int lane = gid % GL;
    const float* h = x + lane * 4;
    int b = off[r * NN + d];
    int e = off[r * NN + d + 1];
    float4 aa = make_float4(0, 0, 0, 0), ab = make_float4(0, 0, 0, 0);
    int k = b;
    for (; k + 1 < e; k += 2) {
        int s0 = csr[k];
        int s1 = csr[k + 1];
        float4 va = *(const float4*)(h + (size_t)s0 * DIN);
        float4 vb = *(const float4*)(h + (size_t)s1 * DIN);
        aa.x += va.x; aa.y += va.y; aa.z += va.z; aa.w += va.w;
        ab.x += vb.x; ab.y += vb.y; ab.z += vb.z; ab.w += vb.w;
    }
    if (k < e) {
        float4 va = *(const float4*)(h + (size_t)csr[k] * DIN);
        aa.x += va.x; aa.y += va.y; aa.z += va.z; aa.w += va.w;
    }
    float* outp = (r ? aggB : aggA) + (size_t)d * DIN + lane * 4;
    *(float4*)outp = make_float4(aa.x + ab.x, aa.y + ab.y, aa.z + ab.z, aa.w + ab.w);
}

// ---------------------------------------------------------------------------
// Combine: out[n] = relu?( x[n]@root + bias + (aggA[n]*inv0)@W0 + (aggB[n]*inv1)@W1 )
// DOUT/4 lanes per node, one float4 store each (line-dense).
template <int DIN, int DOUT, int RELU>
__global__ void __launch_bounds__(256) combine_kernel(
        const float* __restrict__ x,
        const float* __restrict__ aggA, const float* __restrict__ aggB,
        const float* __restrict__ inv, const float* __restrict__ Wbuf,
        float* __restrict__ out) {
    constexpr int SZ = DIN * DOUT;
    constexpr int LPN = DOUT / 4;
    __shared__ float Wl[3 * SZ + DOUT];
    for (int i = threadIdx.x; i < 3 * SZ + DOUT; i += 256) Wl[i] = Wbuf[i];
    __syncthreads();
    int gid = blockIdx.x * 256 + threadIdx.x;
    int n = gid / LPN;
    if (n >= NN) return;
    int j0 = (gid % LPN) * 4;
    float iv0 = inv[n], iv1 = inv[NN + n];
    float xr[DIN], a0[DIN], a1[DIN];
    const float4* xp = (const float4*)(x + (size_t)n * DIN);
    const float4* ap = (const float4*)(aggA + (size_t)n * DIN);
    const float4* bp = (const float4*)(aggB + (size_t)n * DIN);
#pragma unroll
    for (int k4 = 0; k4 < DIN / 4; k4++) {
        float4 xv = xp[k4], av = ap[k4], bv = bp[k4];
        xr[4 * k4 + 0] = xv.x; xr[4 * k4 + 1] = xv.y;
        xr[4 * k4 + 2] = xv.z; xr[4 * k4 + 3] = xv.w;
        a0[4 * k4 + 0] = av.x * iv0; a0[4 * k4 + 1] = av.y * iv0;
        a0[4 * k4 + 2] = av.z * iv0; a0[4 * k4 + 3] = av.w * iv0;
        a1[4 * k4 + 0] = bv.x * iv1; a1[4 * k4 + 1] = bv.y * iv1;
        a1[4 * k4 + 2] = bv.z * iv1; a1[4 * k4 + 3] = bv.w * iv1;
    }
    float acc[4];
#pragma unroll
    for (int jj = 0; jj < 4; jj++) acc[jj] = Wl[3 * SZ + j0 + jj];
#pragma unroll
    for (int k = 0; k < DIN; k++) {
        const float* w0 = &Wl[k * DOUT + j0];
        const float* w1 = &Wl[SZ + k * DOUT + j0];
        const float* wr = &Wl[2 * SZ + k * DOUT + j0];
#pragma unroll
        for (int jj = 0; jj < 4; jj++) {
            acc[jj] = fmaf(xr[k], wr[jj], acc[jj]);
            acc[jj] = fmaf(a0[k], w0[jj], acc[jj]);
            acc[jj] = fmaf(a1[k], w1[jj], acc[jj]);
        }
    }
    if (RELU) {
#pragma unroll
        for (int jj = 0; jj < 4; jj++) acc[jj] = fmaxf(acc[jj], 0.0f);
    }
    *(float4*)(out + (size_t)n * DOUT + j0) =
        make_float4(acc[0], acc[1], acc[2], acc[3]);
}

// ---------------------------------------------------------------------------
// Decode prep: y0 = z @ Wd0 + bd0 ; y1 = z @ Wd1 + bd1   (all 16-dim)
__global__ void decode_prep_kernel(const float* __restrict__ z,
                                   const float* __restrict__ Wd0,
                                   const float* __restrict__ bd0,
                                   const float* __restrict__ Wd1,
                                   const float* __restrict__ bd1,
                                   float* __restrict__ y0, float* __restrict__ y1) {
    __shared__ float W0l[256], W1l[256], B0[16], B1[16];
    for (int i = threadIdx.x; i < 256; i += blockDim.x) {
        W0l[i] = Wd0[i];
        W1l[i] = Wd1[i];
    }
    if (threadIdx.x < 16) {
        B0[threadIdx.x] = bd0[threadIdx.x];
        B1[threadIdx.x] = bd1[threadIdx.x];
    }
    __syncthreads();
    int n = blockIdx.x * blockDim.x + threadIdx.x;
    if (n >= NN) return;
    float zr[16];
    const float* zp = z + (size_t)n * 16;
#pragma unroll
    for (int k = 0; k < 16; k++) zr[k] = zp[k];
    float o0[16], o1[16];
#pragma unroll
    for (int j = 0; j < 16; j++) {
        float a0 = B0[j], a1 = B1[j];
#pragma unroll
        for (int k = 0; k < 16; k++) {
            a0 = fmaf(zr[k], W0l[k * 16 + j], a0);
            a1 = fmaf(zr[k], W1l[k * 16 + j], a1);
        }
        o0[j] = a0;
        o1[j] = a1;
    }
    float4* p0 = (float4*)(y0 + (size_t)n * 16);
    float4* p1 = (float4*)(y1 + (size_t)n * 16);
#pragma unroll
    for (int q = 0; q < 4; q++) {
        p0[q] = make_float4(o0[4 * q], o0[4 * q + 1], o0[4 * q + 2], o0[4 * q + 3]);
        p1[q] = make_float4(o1[4 * q], o1[4 * q + 1], o1[4 * q + 2], o1[4 * q + 3]);
    }
}

// ---------------------------------------------------------------------------
// Decode: out[i] = dot( y_{et}[src], z[dst] )  — fp32 output
__global__ void decode_kernel(const float* __restrict__ y0, const float* __restrict__ y1,
                              const float* __restrict__ z,
                              const int* __restrict__ pei, const int* __restrict__ pet,
                              const int* __restrict__ nei, const int* __restrict__ net_,
                              float* __restrict__ out,
                              const int* __restrict__ dflag) {
    int i = blockIdx.x * blockDim.x + threadIdx.x;
    if (i >= 2 * ED) return;
    int sft = dflag[0];
    const int* ei;
    const int* et;
    int e;
    if (i < ED) { ei = pei; et = pet; e = i; }
    else        { ei = nei; et = net_; e = i - ED; }
    int s = ei[(size_t)e << sft];
    int d = ei[(size_t)(ED + e) << sft];
    int r = et[(size_t)e << sft];
    const float4* yv = (const float4*)((r ? y1 : y0) + ((size_t)s << 4));
    const float4* zv = (const float4*)(z + ((size_t)d << 4));
    float acc = 0.0f;
#pragma unroll
    for (int q = 0; q < 4; q++) {
        float4 a = yv[q];
        float4 b = zv[q];
        acc += a.x * b.x + a.y * b.y + a.z * b.z + a.w * b.w;
    }
    out[i] = acc;
}

// ---------------------------------------------------------------------------
extern "C" void kernel_launch(void* const* d_in, const int* in_sizes, int n_in,
                              void* d_out, int out_size, void* d_ws, size_t ws_size,
                              hipStream_t stream) {
    const float* x_paper = (const float*)d_in[0];
    const float* x_mesh  = (const float*)d_in[1];
    const int* tei  = (const int*)d_in[2];
    const int* tet  = (const int*)d_in[3];
    const int* pei  = (const int*)d_in[4];
    const int* pet  = (const int*)d_in[5];
    const int* nei  = (const int*)d_in[6];
    const int* net_ = (const int*)d_in[7];
    const float* Wp  = (const float*)d_in[8];
    const float* bp  = (const float*)d_in[9];
    const float* Wm  = (const float*)d_in[10];
    const float* bm  = (const float*)d_in[11];
    const float* Wd0 = (const float*)d_in[12];
    const float* bd0 = (const float*)d_in[13];
    const float* Wd1 = (const float*)d_in[14];
    const float* bd1 = (const float*)d_in[15];
    const float* basesL[4] = {(const float*)d_in[16], (const float*)d_in[20],
                              (const float*)d_in[24], (const float*)d_in[28]};
    const float* compL[4]  = {(const float*)d_in[17], (const float*)d_in[21],
                              (const float*)d_in[25], (const float*)d_in[29]};
    const float* rootL[4]  = {(const float*)d_in[18], (const float*)d_in[22],
                              (const float*)d_in[26], (const float*)d_in[30]};
    const float* biasL[4]  = {(const float*)d_in[19], (const float*)d_in[23],
                              (const float*)d_in[27], (const float*)d_in[31]};

    // Workspace carve-up (fp32/int32 elements) — ~57 MB total
    float* ws = (float*)d_ws;
    size_t o = 0;
    float* bufA = ws + o; o += (size_t)NN * 32;
    float* bufB = ws + o; o += (size_t)NN * 32;
    float* aggA = ws + o; o += (size_t)NN * 32;
    float* aggB = ws + o; o += (size_t)NN * 32;
    float* inv  = ws + o; o += (size_t)TWO_NN;
    int*   cnt  = (int*)(ws + o); o += (size_t)TWO_NN;
    int*   off  = (int*)(ws + o); o += (size_t)TWO_NN + 4;
    int*   bsum = (int*)(ws + o); o += 256;
    int*   csr  = (int*)(ws + o); o += (size_t)ET;
    int*   gcur = (int*)(ws + o); o += 256;
    float* Wbuf = ws + o; o += 4096;
    int*   dflag = (int*)(ws + o); o += 16;
    // pairs alias aggA/aggB (dead until first aggregate): 17.3 MB < 23 MB
    int2* pairs = (int2*)aggA;

    // 0. Dtype detect
    detect_kernel<<<1, 64, 0, stream>>>(tei, dflag);

    // 1. Binned CSR build (once; edge structure is layer-invariant)
    init_gcur_kernel<<<1, 256, 0, stream>>>(gcur);
    binA_kernel<<<N_TILES, 256, 0, stream>>>(tei, tet, dflag, gcur, pairs);
    histB_kernel<<<NB_BKT, 256, 0, stream>>>(gcur, pairs, cnt);
    inv_kernel<<<(TWO_NN + 255) / 256, 256, 0, stream>>>(cnt, inv);
    scan_block_kernel<<<SCAN_BLKS, 256, 0, stream>>>(cnt, bsum);
    scan_bsum_kernel<<<1, 256, 0, stream>>>(bsum, SCAN_BLKS);
    scan_final_kernel<<<SCAN_BLKS, 256, 0, stream>>>(cnt, bsum, off);
    placeB_kernel<<<NB_BKT, 256, 0, stream>>>(gcur, pairs, off, csr);

    // 2. Input embed -> bufA [NN,16]  (layer-1 input; reference applies no relu here)
    embed_kernel<<<(NP + 255) / 256, 256, 0, stream>>>(x_paper, NP, Wp, bp, bufA);
    embed_kernel<<<(NM + 255) / 256, 256, 0, stream>>>(x_mesh, NM, Wm, bm,
                                                       bufA + (size_t)NP * 16);

    // 3. Four RGCN layers: aggregate raw x, then combine (transform-after-agg).
    //    xin is already relu'd (combine fuses relu into its output store).
    float* xin = bufA;
    float* xout = bufB;
    for (int l = 0; l < 4; l++) {
        int din = (l == 0) ? 16 : 32;
        int dout = (l == 3) ? 16 : 32;
        int sz = din * dout;
        prep_weights_kernel<<<(sz + 255) / 256, 256, 0, stream>>>(
            basesL[l], compL[l], rootL[l], biasL[l], Wbuf, din, dout);
        // aggregate: NN * 2 relations * (din/4) lanes
        int gl = din / 4;
        long atot = (long)NN * 2 * gl;
        int ablk = (int)((atot + 255) / 256);
        if (din == 16)
            aggregate_x_kernel<16><<<ablk, 256, 0, stream>>>(off, csr, xin, aggA, aggB);
        else
            aggregate_x_kernel<32><<<ablk, 256, 0, stream>>>(off, csr, xin, aggA, aggB);
        // combine: NN * (dout/4) lanes
        int lpn = dout / 4;
        int cblk = (NN * lpn + 255) / 256;
        if (l == 0)
            combine_kernel<16, 32, 1><<<cblk, 256, 0, stream>>>(xin, aggA, aggB, inv, Wbuf, xout);
        else if (l == 3)
            combine_kernel<32, 16, 0><<<cblk, 256, 0, stream>>>(xin, aggA, aggB, inv, Wbuf, xout);
        else
            combine_kernel<32, 32, 1><<<cblk, 256, 0, stream>>>(xin, aggA, aggB, inv, Wbuf, xout);
        float* t = xin; xin = xout; xout = t;
    }
    // z = xin [NN,16]

    // 4. Decode (y0/y1 reuse aggA/aggB)
    decode_prep_kernel<<<(NN + 255) / 256, 256, 0, stream>>>(xin, Wd0, bd0, Wd1, bd1,
                                                             aggA, aggB);
    decode_kernel<<<(2 * ED + 255) / 256, 256, 0, stream>>>(
        aggA, aggB, xin, pei, pet, nei, net_, (float*)d_out, dflag);
}

// Round 11
// 447.242 us; speedup vs baseline: 3.2916x; 1.0920x over previous
//
#include <hip/hip_runtime.h>
#include <hip/hip_bf16.h>

// Problem constants (from reference)
constexpr int NN = 90000;   // total nodes
constexpr int NP = 60000;   // paper nodes
constexpr int NM = 30000;   // mesh nodes
constexpr int ET = 2000000; // train edges
constexpr int ED = 400000;  // decode edges (each of pos/neg)
constexpr int TWO_NN = 2 * NN;
constexpr int SCAN_BLKS = (TWO_NN + 1023) / 1024; // 176

// Binned CSR build parameters
constexpr int BKT_SH  = 10;                        // 1024 keys per bucket
constexpr int NB_BKT  = (TWO_NN + 1023) >> BKT_SH; // 176 buckets
constexpr int BKT_CAP = 12288;                     // mean 11366, +8.7 sigma
constexpr int TILE    = 2048;                      // edges per binning tile
constexpr int N_TILES = (ET + TILE - 1) / TILE;    // 977

__device__ __forceinline__ float bf2f(unsigned short u) {
    union { unsigned int i; float f; } c;
    c.i = ((unsigned int)u) << 16;
    return c.f;
}
__device__ __forceinline__ unsigned short f2bf(float f) {
    union { float f; unsigned int i; } c;
    c.f = f;
    unsigned int x = c.i;
    return (unsigned short)((x + 0x7FFFu + ((x >> 16) & 1u)) >> 16);
}

// ---------------------------------------------------------------------------
__global__ void detect_kernel(const int* __restrict__ tei, int* __restrict__ flag) {
    if (blockIdx.x == 0 && threadIdx.x == 0) {
        int allzero = 1;
        for (int i = 0; i < 16; i++)
            if (tei[2 * i + 1] != 0) allzero = 0;
        flag[0] = allzero; // 1 => int64 => index shift 1
    }
}

__global__ void init_gcur_kernel(int* __restrict__ gcur) {
    int b = blockIdx.x * blockDim.x + threadIdx.x;
    if (b < NB_BKT) gcur[b] = b * BKT_CAP;
}

// ---------------------------------------------------------------------------
// Pass A: bin edges into per-bucket pair arrays with line-dense writes.
__global__ void __launch_bounds__(256) binA_kernel(
        const int* __restrict__ ei, const int* __restrict__ et,
        const int* __restrict__ dflag, int* __restrict__ gcur,
        int2* __restrict__ pairs) {
    __shared__ int hist[NB_BKT];
    __shared__ int excl[NB_BKT];
    __shared__ int cur[NB_BKT];
    __shared__ int gbase[NB_BKT];
    __shared__ int scn[256];
    __shared__ int2 tbuf[TILE];
    int t = threadIdx.x;
    int tile0 = blockIdx.x * TILE;
    int tcount = ET - tile0;
    if (tcount > TILE) tcount = TILE;
    for (int i = t; i < NB_BKT; i += 256) hist[i] = 0;
    __syncthreads();
    int sft = dflag[0];
    int myk[8], mys[8];
#pragma unroll
    for (int q = 0; q < 8; q++) {
        int li = q * 256 + t;
        myk[q] = -1;
        if (li < tcount) {
            int e = tile0 + li;
            int s = ei[(size_t)e << sft];
            int d = ei[(size_t)(ET + e) << sft];
            int r = et[(size_t)e << sft];
            int key = r * NN + d;
            myk[q] = key;
            mys[q] = s;
            atomicAdd(&hist[key >> BKT_SH], 1);
        }
    }
    __syncthreads();
    int v = (t < NB_BKT) ? hist[t] : 0;
    scn[t] = v;
    __syncthreads();
    for (int st = 1; st < 256; st <<= 1) {
        int u = (t >= st) ? scn[t - st] : 0;
        __syncthreads();
        scn[t] += u;
        __syncthreads();
    }
    if (t < NB_BKT) {
        excl[t] = scn[t] - v;
        cur[t] = scn[t] - v;
    }
    __syncthreads();
#pragma unroll
    for (int q = 0; q < 8; q++) {
        if (myk[q] >= 0) {
            int b = myk[q] >> BKT_SH;
            int p = atomicAdd(&cur[b], 1);
            tbuf[p] = make_int2(myk[q], mys[q]);
        }
    }
    __syncthreads();
    if (t < NB_BKT && hist[t] > 0) gbase[t] = atomicAdd(&gcur[t], hist[t]);
    __syncthreads();
    for (int i = t; i < tcount; i += 256) {
        int2 p = tbuf[i];
        int b = p.x >> BKT_SH;
        int gpos = gbase[b] + (i - excl[b]);
        int cap = (b + 1) * BKT_CAP - 1;
        pairs[gpos < cap ? gpos : cap] = p;
    }
}

// ---------------------------------------------------------------------------
// Pass B1: per-bucket key histogram (LDS) -> cnt + inv written densely.
__global__ void __launch_bounds__(256) histB_kernel(
        const int* __restrict__ gcur, const int2* __restrict__ pairs,
        int* __restrict__ cnt, float* __restrict__ inv) {
    __shared__ int kh[1024];
    int b = blockIdx.x;
    int t = threadIdx.x;
    for (int i = t; i < 1024; i += 256) kh[i] = 0;
    __syncthreads();
    int beg = b * BKT_CAP, end = gcur[b];
    for (int i = beg + t; i < end; i += 256)
        atomicAdd(&kh[pairs[i].x & 1023], 1);
    __syncthreads();
    int kbase = b << BKT_SH;
    for (int i = t; i < 1024; i += 256) {
        if (kbase + i < TWO_NN) {
            int c = kh[i];
            cnt[kbase + i] = c;
            inv[kbase + i] = 1.0f / (float)(c > 1 ? c : 1);
        }
    }
}

// ---------------------------------------------------------------------------
// Hierarchical exclusive scan of cnt[0..2NN) -> off
__global__ void scan_block_kernel(const int* __restrict__ cnt, int* __restrict__ bsum) {
    __shared__ int lds[256];
    int base = blockIdx.x * 1024;
    int t = threadIdx.x;
    int s = 0;
#pragma unroll
    for (int q = 0; q < 4; q++) {
        int i = base + t * 4 + q;
        s += (i < TWO_NN) ? cnt[i] : 0;
    }
    lds[t] = s;
    __syncthreads();
    for (int st = 128; st > 0; st >>= 1) {
        if (t < st) lds[t] += lds[t + st];
        __syncthreads();
    }
    if (t == 0) bsum[blockIdx.x] = lds[0];
}

__global__ void scan_bsum_kernel(int* __restrict__ bsum, int nb) {
    __shared__ int lds[256];
    int t = threadIdx.x;
    lds[t] = (t < nb) ? bsum[t] : 0;
    __syncthreads();
    for (int st = 1; st < 256; st <<= 1) {
        int v = (t >= st) ? lds[t - st] : 0;
        __syncthreads();
        lds[t] += v;
        __syncthreads();
    }
    if (t < nb) bsum[t] = (t > 0) ? lds[t - 1] : 0;
}

__global__ void scan_final_kernel(const int* __restrict__ cnt, const int* __restrict__ bsum,
                                  int* __restrict__ off) {
    __shared__ int lds[256];
    int base = blockIdx.x * 1024;
    int t = threadIdx.x;
    int v[4];
    int s = 0;
#pragma unroll
    for (int q = 0; q < 4; q++) {
        int i = base + t * 4 + q;
        v[q] = (i < TWO_NN) ? cnt[i] : 0;
        s += v[q];
    }
    lds[t] = s;
    __syncthreads();
    for (int st = 1; st < 256; st <<= 1) {
        int u = (t >= st) ? lds[t - st] : 0;
        __syncthreads();
        lds[t] += u;
        __syncthreads();
    }
    int run = bsum[blockIdx.x] + lds[t] - s;
#pragma unroll
    for (int q = 0; q < 4; q++) {
        int i = base + t * 4 + q;
        if (i < TWO_NN) off[i] = run;
        run += v[q];
    }
    if (blockIdx.x == 0 && t == 0) off[TWO_NN] = ET;
}

// ---------------------------------------------------------------------------
// Pass B2: place pairs into final CSR (bucket range contiguous -> L2-hot).
__global__ void __launch_bounds__(256) placeB_kernel(
        const int* __restrict__ gcur, const int2* __restrict__ pairs,
        const int* __restrict__ off, int* __restrict__ csr) {
    __shared__ int kc[1024];
    int b = blockIdx.x;
    int t = threadIdx.x;
    int kbase = b << BKT_SH;
    for (int i = t; i < 1024; i += 256)
        if (kbase + i < TWO_NN) kc[i] = off[kbase + i];
    __syncthreads();
    int beg = b * BKT_CAP, end = gcur[b];
    for (int i = beg + t; i < end; i += 256) {
        int2 p = pairs[i];
        int pos = atomicAdd(&kc[p.x & 1023], 1);
        csr[pos] = p.y;
    }
}

// ---------------------------------------------------------------------------
// Fused input embed (paper+mesh in one launch): fp32 out + bf16 shadow.
__global__ void __launch_bounds__(256) embed2_kernel(
        const float* __restrict__ Xp, const float* __restrict__ Xm,
        const float* __restrict__ Wp, const float* __restrict__ bp,
        const float* __restrict__ Wm, const float* __restrict__ bm,
        float* __restrict__ out, unsigned short* __restrict__ outbf) {
    __shared__ float Wl[4096 + 32];
    for (int i = threadIdx.x; i < 2048; i += 256) {
        Wl[i] = Wp[i];
        Wl[2048 + i] = Wm[i];
    }
    if (threadIdx.x < 16) {
        Wl[4096 + threadIdx.x] = bp[threadIdx.x];
        Wl[4112 + threadIdx.x] = bm[threadIdx.x];
    }
    __syncthreads();
    int n = blockIdx.x * 256 + threadIdx.x;
    if (n >= NN) return;
    const float* X;
    const float* Ws;
    const float* Bs;
    if (n < NP) { X = Xp + (size_t)n * 128; Ws = Wl; Bs = Wl + 4096; }
    else        { X = Xm + (size_t)(n - NP) * 128; Ws = Wl + 2048; Bs = Wl + 4112; }
    float acc[16];
#pragma unroll
    for (int j = 0; j < 16; j++) acc[j] = Bs[j];
    const float4* row = (const float4*)X;
    for (int k4 = 0; k4 < 32; k4++) {
        float4 xv = row[k4];
        int k = k4 * 4;
#pragma unroll
        for (int j = 0; j < 16; j++) {
            float a = acc[j];
            a = fmaf(xv.x, Ws[(k + 0) * 16 + j], a);
            a = fmaf(xv.y, Ws[(k + 1) * 16 + j], a);
            a = fmaf(xv.z, Ws[(k + 2) * 16 + j], a);
            a = fmaf(xv.w, Ws[(k + 3) * 16 + j], a);
            acc[j] = a;
        }
    }
    float4* o = (float4*)(out + (size_t)n * 16);
    ushort4* ob = (ushort4*)(outbf + (size_t)n * 16);
#pragma unroll
    for (int q = 0; q < 4; q++) {
        o[q] = make_float4(acc[4 * q], acc[4 * q + 1], acc[4 * q + 2], acc[4 * q + 3]);
        ushort4 ub;
        ub.x = f2bf(acc[4 * q]);     ub.y = f2bf(acc[4 * q + 1]);
        ub.z = f2bf(acc[4 * q + 2]); ub.w = f2bf(acc[4 * q + 3]);
        ob[q] = ub;
    }
}

// ---------------------------------------------------------------------------
// All 4 layers' weight prep in ONE launch: block l handles layer l.
// Wbuf4 layout per layer (stride 3200): [W0 | W1 | root | bias]
__global__ void prep_all_kernel(
        const float* __restrict__ ba0, const float* __restrict__ co0,
        const float* __restrict__ ro0, const float* __restrict__ bi0,
        const float* __restrict__ ba1, const float* __restrict__ co1,
        const float* __restrict__ ro1, const float* __restrict__ bi1,
        const float* __restrict__ ba2, const float* __restrict__ co2,
        const float* __restrict__ ro2, const float* __restrict__ bi2,
        const float* __restrict__ ba3, const float* __restrict__ co3,
        const float* __restrict__ ro3, const float* __restrict__ bi3,
        float* __restrict__ Wbuf4) {
    int l = blockIdx.x;
    const float* bases; const float* comp; const float* root; const float* bias;
    if (l == 0)      { bases = ba0; comp = co0; root = ro0; bias = bi0; }
    else if (l == 1) { bases = ba1; comp = co1; root = ro1; bias = bi1; }
    else if (l == 2) { bases = ba2; comp = co2; root = ro2; bias = bi2; }
    else             { bases = ba3; comp = co3; root = ro3; bias = bi3; }
    int din = (l == 0) ? 16 : 32;
    int dout = (l == 3) ? 16 : 32;
    int sz = din * dout;
    float* W = Wbuf4 + l * 3200;
    for (int i = threadIdx.x; i < sz; i += 256) {
        float b0 = bases[i];
        float b1 = bases[sz + i];
        float b2 = bases[2 * sz + i];
        float b3 = bases[3 * sz + i];
        for (int r = 0; r < 2; r++) {
            W[r * sz + i] = comp[r * 4 + 0] * b0 + comp[r * 4 + 1] * b1 +
                            comp[r * 4 + 2] * b2 + comp[r * 4 + 3] * b3;
        }
        W[2 * sz + i] = root[i];
    }
    if (threadIdx.x < dout) W[3 * sz + threadIdx.x] = bias[threadIdx.x];
}

// ---------------------------------------------------------------------------
// Fused RGCN layer: phase 1 gathers bf16 x rows per (dst, relation) into LDS
// (one bf16 din=32 row = exactly one 64B line -> 8 full distinct lines per
// wave gather instruction); phase 2 does the combine matmul from LDS and
// writes fp32 out + bf16 shadow. Eliminates the aggA/aggB global round-trip.
template <int DIN, int DOUT, int RELU, int WBF>
__global__ void __launch_bounds__(256) layer_kernel(
        const int* __restrict__ off, const int* __restrict__ csr,
        const float* __restrict__ xin, const unsigned short* __restrict__ xbf_in,
        const float* __restrict__ inv, const float* __restrict__ Wbuf,
        float* __restrict__ xout, unsigned short* __restrict__ xbf_out) {
    constexpr int SZ = DIN * DOUT;
    constexpr int QL = DIN / 4;      // gather lanes per (node, rel)
    constexpr int TPN = 2 * QL;      // phase-1 threads per node
    constexpr int NPB = 256 / TPN;   // nodes per block
    constexpr int AGST = 2 * DIN + 4; // agg LDS row stride (16B-aligned, bank-skewed)
    constexpr int XSST = DIN + 4;     // xs LDS row stride
    __shared__ float Wl[3 * SZ + DOUT];
    __shared__ float agg[NPB * AGST];
    __shared__ float xs[NPB * XSST];
    for (int i = threadIdx.x; i < 3 * SZ + DOUT; i += 256) Wl[i] = Wbuf[i];
    int t = threadIdx.x;
    int ln = t / TPN;
    int rl = t % TPN;
    int r = rl / QL;
    int lane = rl % QL;
    int d = blockIdx.x * NPB + ln;
    if (d < NN) {
        if (r == 0)
            *(float4*)(xs + ln * XSST + lane * 4) =
                *(const float4*)(xin + (size_t)d * DIN + lane * 4);
        int b = off[r * NN + d];
        int e = off[r * NN + d + 1];
        float ax = 0, ay = 0, az = 0, aw = 0;
        float bx = 0, by = 0, bz = 0, bw = 0;
        const unsigned short* hp = xbf_in + lane * 4;
        int k = b;
        for (; k + 1 < e; k += 2) {
            int s0 = csr[k];
            int s1 = csr[k + 1];
            ushort4 u0 = *(const ushort4*)(hp + (size_t)s0 * DIN);
            ushort4 u1 = *(const ushort4*)(hp + (size_t)s1 * DIN);
            ax += bf2f(u0.x); ay += bf2f(u0.y); az += bf2f(u0.z); aw += bf2f(u0.w);
            bx += bf2f(u1.x); by += bf2f(u1.y); bz += bf2f(u1.z); bw += bf2f(u1.w);
        }
        if (k < e) {
            ushort4 u0 = *(const ushort4*)(hp + (size_t)csr[k] * DIN);
            ax += bf2f(u0.x); ay += bf2f(u0.y); az += bf2f(u0.z); aw += bf2f(u0.w);
        }
        *(float4*)(agg + ln * AGST + r * DIN + lane * 4) =
            make_float4(ax + bx, ay + by, az + bz, aw + bw);
    }
    __syncthreads();
    constexpr int CPN = DOUT / 4;
    if (t < NPB * CPN) {
        int ln2 = t / CPN;
        int j0 = (t % CPN) * 4;
        int d2 = blockIdx.x * NPB + ln2;
        if (d2 < NN) {
            float iv0 = inv[d2], iv1 = inv[NN + d2];
            float acc[4];
#pragma unroll
            for (int jj = 0; jj < 4; jj++) acc[jj] = Wl[3 * SZ + j0 + jj];
#pragma unroll
            for (int k = 0; k < DIN; k++) {
                float xv = xs[ln2 * XSST + k];
                float a0 = agg[ln2 * AGST + k] * iv0;
                float a1 = agg[ln2 * AGST + DIN + k] * iv1;
                const float* w0 = &Wl[k * DOUT + j0];
                const float* w1 = &Wl[SZ + k * DOUT + j0];
                const float* wr = &Wl[2 * SZ + k * DOUT + j0];
#pragma unroll
                for (int jj = 0; jj < 4; jj++) {
                    acc[jj] = fmaf(xv, wr[jj], acc[jj]);
                    acc[jj] = fmaf(a0, w0[jj], acc[jj]);
                    acc[jj] = fmaf(a1, w1[jj], acc[jj]);
                }
            }
            if (RELU) {
#pragma unroll
                for (int jj = 0; jj < 4; jj++) acc[jj] = fmaxf(acc[jj], 0.0f);
            }
            *(float4*)(xout + (size_t)d2 * DOUT + j0) =
                make_float4(acc[0], acc[1], acc[2], acc[3]);
            if (WBF) {
                ushort4 ub;
                ub.x = f2bf(acc[0]); ub.y = f2bf(acc[1]);
                ub.z = f2bf(acc[2]); ub.w = f2bf(acc[3]);
                *(ushort4*)(xbf_out + (size_t)d2 * DOUT + j0) = ub;
            }
        }
    }
}

// ---------------------------------------------------------------------------
// Decode prep: y0 = z @ Wd0 + bd0 ; y1 = z @ Wd1 + bd1   (all 16-dim)
__global__ void decode_prep_kernel(const float* __restrict__ z,
                                   const float* __restrict__ Wd0,
                                   const float* __restrict__ bd0,
                                   const float* __restrict__ Wd1,
                                   const float* __restrict__ bd1,
                                   float* __restrict__ y0, float* __restrict__ y1) {
    __shared__ float W0l[256], W1l[256], B0[16], B1[16];
    for (int i = threadIdx.x; i < 256; i += blockDim.x) {
        W0l[i] = Wd0[i];
        W1l[i] = Wd1[i];
    }
    if (threadIdx.x < 16) {
        B0[threadIdx.x] = bd0[threadIdx.x];
        B1[threadIdx.x] = bd1[threadIdx.x];
    }
    __syncthreads();
    int n = blockIdx.x * blockDim.x + threadIdx.x;
    if (n >= NN) return;
    float zr[16];
    const float* zp = z + (size_t)n * 16;
#pragma unroll
    for (int k = 0; k < 16; k++) zr[k] = zp[k];
    float o0[16], o1[16];
#pragma unroll
    for (int j = 0; j < 16; j++) {
        float a0 = B0[j], a1 = B1[j];
#pragma unroll
        for (int k = 0; k < 16; k++) {
            a0 = fmaf(zr[k], W0l[k * 16 + j], a0);
            a1 = fmaf(zr[k], W1l[k * 16 + j], a1);
        }
        o0[j] = a0;
        o1[j] = a1;
    }
    float4* p0 = (float4*)(y0 + (size_t)n * 16);
    float4* p1 = (float4*)(y1 + (size_t)n * 16);
#pragma unroll
    for (int q = 0; q < 4; q++) {
        p0[q] = make_float4(o0[4 * q], o0[4 * q + 1], o0[4 * q + 2], o0[4 * q + 3]);
        p1[q] = make_float4(o1[4 * q], o1[4 * q + 1], o1[4 * q + 2], o1[4 * q + 3]);
    }
}

// ---------------------------------------------------------------------------
// Decode: out[i] = dot( y_{et}[src], z[dst] )  — fp32 output
__global__ void decode_kernel(const float* __restrict__ y0, const float* __restrict__ y1,
                              const float* __restrict__ z,
                              const int* __restrict__ pei, const int* __restrict__ pet,
                              const int* __restrict__ nei, const int* __restrict__ net_,
                              float* __restrict__ out,
                              const int* __restrict__ dflag) {
    int i = blockIdx.x * blockDim.x + threadIdx.x;
    if (i >= 2 * ED) return;
    int sft = dflag[0];
    const int* ei;
    const int* et;
    int e;
    if (i < ED) { ei = pei; et = pet; e = i; }
    else        { ei = nei; et = net_; e = i - ED; }
    int s = ei[(size_t)e << sft];
    int d = ei[(size_t)(ED + e) << sft];
    int r = et[(size_t)e << sft];
    const float4* yv = (const float4*)((r ? y1 : y0) + ((size_t)s << 4));
    const float4* zv = (const float4*)(z + ((size_t)d << 4));
    float acc = 0.0f;
#pragma unroll
    for (int q = 0; q < 4; q++) {
        float4 a = yv[q];
        float4 b = zv[q];
        acc += a.x * b.x + a.y * b.y + a.z * b.z + a.w * b.w;
    }
    out[i] = acc;
}

// ---------------------------------------------------------------------------
extern "C" void kernel_launch(void* const* d_in, const int* in_sizes, int n_in,
                              void* d_out, int out_size, void* d_ws, size_t ws_size,
                              hipStream_t stream) {
    const float* x_paper = (const float*)d_in[0];
    const float* x_mesh  = (const float*)d_in[1];
    const int* tei  = (const int*)d_in[2];
    const int* tet  = (const int*)d_in[3];
    const int* pei  = (const int*)d_in[4];
    const int* pet  = (const int*)d_in[5];
    const int* nei  = (const int*)d_in[6];
    const int* net_ = (const int*)d_in[7];
    const float* Wp  = (const float*)d_in[8];
    const float* bp  = (const float*)d_in[9];
    const float* Wm  = (const float*)d_in[10];
    const float* bm  = (const float*)d_in[11];
    const float* Wd0 = (const float*)d_in[12];
    const float* bd0 = (const float*)d_in[13];
    const float* Wd1 = (const float*)d_in[14];
    const float* bd1 = (const float*)d_in[15];

    // Workspace carve-up (fp32/int32 elements) — ~61 MB total
    float* ws = (float*)d_ws;
    size_t o = 0;
    float* bufA = ws + o; o += (size_t)NN * 32;
    float* bufB = ws + o; o += (size_t)NN * 32;
    unsigned short* xbfA = (unsigned short*)(ws + o); o += (size_t)NN * 16; // NN*32 bf16
    unsigned short* xbfB = (unsigned short*)(ws + o); o += (size_t)NN * 16;
    float* inv  = ws + o; o += (size_t)TWO_NN;
    int*   cnt  = (int*)(ws + o); o += (size_t)TWO_NN;
    int*   off  = (int*)(ws + o); o += (size_t)TWO_NN + 4;
    int*   bsum = (int*)(ws + o); o += 256;
    int*   csr  = (int*)(ws + o); o += (size_t)ET;
    int*   gcur = (int*)(ws + o); o += 256;
    int2*  pairs = (int2*)(ws + o); o += (size_t)2 * NB_BKT * BKT_CAP; // 17.3 MB
    float* Wbuf4 = ws + o; o += 4 * 3200;
    int*   dflag = (int*)(ws + o); o += 16;

    // 0. Dtype detect
    detect_kernel<<<1, 64, 0, stream>>>(tei, dflag);

    // 1. Binned CSR build (once; edge structure is layer-invariant)
    init_gcur_kernel<<<1, 256, 0, stream>>>(gcur);
    binA_kernel<<<N_TILES, 256, 0, stream>>>(tei, tet, dflag, gcur, pairs);
    histB_kernel<<<NB_BKT, 256, 0, stream>>>(gcur, pairs, cnt, inv);
    scan_block_kernel<<<SCAN_BLKS, 256, 0, stream>>>(cnt, bsum);
    scan_bsum_kernel<<<1, 256, 0, stream>>>(bsum, SCAN_BLKS);
    scan_final_kernel<<<SCAN_BLKS, 256, 0, stream>>>(cnt, bsum, off);
    placeB_kernel<<<NB_BKT, 256, 0, stream>>>(gcur, pairs, off, csr);

    // 2. Fused embed (paper+mesh) -> bufA fp32 + xbfA bf16
    embed2_kernel<<<(NN + 255) / 256, 256, 0, stream>>>(
        x_paper, x_mesh, Wp, bp, Wm, bm, bufA, xbfA);

    // 3. All layer weights in one launch
    prep_all_kernel<<<4, 256, 0, stream>>>(
        (const float*)d_in[16], (const float*)d_in[17], (const float*)d_in[18], (const float*)d_in[19],
        (const float*)d_in[20], (const float*)d_in[21], (const float*)d_in[22], (const float*)d_in[23],
        (const float*)d_in[24], (const float*)d_in[25], (const float*)d_in[26], (const float*)d_in[27],
        (const float*)d_in[28], (const float*)d_in[29], (const float*)d_in[30], (const float*)d_in[31],
        Wbuf4);

    // 4. Four fused RGCN layers (gather->LDS->combine), ping-pong buffers
    int blk16 = (NN + 31) / 32; // DIN=16: 32 nodes/block
    int blk32 = (NN + 15) / 16; // DIN=32: 16 nodes/block
    layer_kernel<16, 32, 1, 1><<<blk16, 256, 0, stream>>>(
        off, csr, bufA, xbfA, inv, Wbuf4 + 0 * 3200, bufB, xbfB);
    layer_kernel<32, 32, 1, 1><<<blk32, 256, 0, stream>>>(
        off, csr, bufB, xbfB, inv, Wbuf4 + 1 * 3200, bufA, xbfA);
    layer_kernel<32, 32, 1, 1><<<blk32, 256, 0, stream>>>(
        off, csr, bufA, xbfA, inv, Wbuf4 + 2 * 3200, bufB, xbfB);
    layer_kernel<32, 16, 0, 0><<<blk32, 256, 0, stream>>>(
        off, csr, bufB, xbfB, inv, Wbuf4 + 3 * 3200, bufA, xbfA /*unused*/);
    // z = bufA [NN,16]; bufB now free

    // 5. Decode (y0/y1 live in bufB)
    float* y0 = bufB;
    float* y1 = bufB + (size_t)NN * 16;
    decode_prep_kernel<<<(NN + 255) / 256, 256, 0, stream>>>(bufA, Wd0, bd0, Wd1, bd1,
                                                             y0, y1);
    decode_kernel<<<(2 * ED + 255) / 256, 256, 0, stream>>>(
        y0, y1, bufA, pei, pet, nei, net_, (float*)d_out, dflag);
}

// Round 12
// 430.499 us; speedup vs baseline: 3.4196x; 1.0389x over previous
//
#include <hip/hip_runtime.h>
#include <hip/hip_bf16.h>

// Problem constants (from reference)
constexpr int NN = 90000;   // total nodes
constexpr int NP = 60000;   // paper nodes
constexpr int NM = 30000;   // mesh nodes
constexpr int ET = 2000000; // train edges
constexpr int ED = 400000;  // decode edges (each of pos/neg)
constexpr int TWO_NN = 2 * NN;

// Binned CSR build parameters
constexpr int BKT_SH  = 10;                        // 1024 keys per bucket
constexpr int NB_BKT  = (TWO_NN + 1023) >> BKT_SH; // 176 buckets
constexpr int BKT_CAP = 12288;                     // mean 11366, +8.7 sigma
constexpr int TILE    = 2048;                      // edges per binning tile
constexpr int N_TILES = (ET + TILE - 1) / TILE;    // 977

__device__ __forceinline__ float bf2f(unsigned short u) {
    union { unsigned int i; float f; } c;
    c.i = ((unsigned int)u) << 16;
    return c.f;
}
__device__ __forceinline__ unsigned short f2bf(float f) {
    union { float f; unsigned int i; } c;
    c.f = f;
    unsigned int x = c.i;
    return (unsigned short)((x + 0x7FFFu + ((x >> 16) & 1u)) >> 16);
}

// ---------------------------------------------------------------------------
__global__ void detect_kernel(const int* __restrict__ tei, int* __restrict__ flag) {
    if (blockIdx.x == 0 && threadIdx.x == 0) {
        int allzero = 1;
        for (int i = 0; i < 16; i++)
            if (tei[2 * i + 1] != 0) allzero = 0;
        flag[0] = allzero; // 1 => int64 => index shift 1
    }
}

__global__ void init_gcur_kernel(int* __restrict__ gcur) {
    int b = blockIdx.x * blockDim.x + threadIdx.x;
    if (b < NB_BKT) gcur[b] = b * BKT_CAP;
}

// ---------------------------------------------------------------------------
// Pass A: bin edges into per-bucket pair arrays with line-dense writes.
__global__ void __launch_bounds__(256) binA_kernel(
        const int* __restrict__ ei, const int* __restrict__ et,
        const int* __restrict__ dflag, int* __restrict__ gcur,
        int2* __restrict__ pairs) {
    __shared__ int hist[NB_BKT];
    __shared__ int excl[NB_BKT];
    __shared__ int cur[NB_BKT];
    __shared__ int gbase[NB_BKT];
    __shared__ int scn[256];
    __shared__ int2 tbuf[TILE];
    int t = threadIdx.x;
    int tile0 = blockIdx.x * TILE;
    int tcount = ET - tile0;
    if (tcount > TILE) tcount = TILE;
    for (int i = t; i < NB_BKT; i += 256) hist[i] = 0;
    __syncthreads();
    int sft = dflag[0];
    int myk[8], mys[8];
#pragma unroll
    for (int q = 0; q < 8; q++) {
        int li = q * 256 + t;
        myk[q] = -1;
        if (li < tcount) {
            int e = tile0 + li;
            int s = ei[(size_t)e << sft];
            int d = ei[(size_t)(ET + e) << sft];
            int r = et[(size_t)e << sft];
            int key = r * NN + d;
            myk[q] = key;
            mys[q] = s;
            atomicAdd(&hist[key >> BKT_SH], 1);
        }
    }
    __syncthreads();
    int v = (t < NB_BKT) ? hist[t] : 0;
    scn[t] = v;
    __syncthreads();
    for (int st = 1; st < 256; st <<= 1) {
        int u = (t >= st) ? scn[t - st] : 0;
        __syncthreads();
        scn[t] += u;
        __syncthreads();
    }
    if (t < NB_BKT) {
        excl[t] = scn[t] - v;
        cur[t] = scn[t] - v;
    }
    __syncthreads();
#pragma unroll
    for (int q = 0; q < 8; q++) {
        if (myk[q] >= 0) {
            int b = myk[q] >> BKT_SH;
            int p = atomicAdd(&cur[b], 1);
            tbuf[p] = make_int2(myk[q], mys[q]);
        }
    }
    __syncthreads();
    if (t < NB_BKT && hist[t] > 0) gbase[t] = atomicAdd(&gcur[t], hist[t]);
    __syncthreads();
    for (int i = t; i < tcount; i += 256) {
        int2 p = tbuf[i];
        int b = p.x >> BKT_SH;
        int gpos = gbase[b] + (i - excl[b]);
        int cap = (b + 1) * BKT_CAP - 1;
        pairs[gpos < cap ? gpos : cap] = p;
    }
}

// ---------------------------------------------------------------------------
// Pass B1: per-bucket key histogram + block-local exclusive scan ->
// padded-bucket CSR offsets (off/end) + inv, all written densely.
// Replaces the former global 3-kernel scan (csr stays bucket-padded).
__global__ void __launch_bounds__(256) histB_kernel(
        const int* __restrict__ gcur, const int2* __restrict__ pairs,
        int* __restrict__ off, int* __restrict__ endo, float* __restrict__ inv) {
    __shared__ int kh[1024];
    __shared__ int scn[256];
    int b = blockIdx.x;
    int t = threadIdx.x;
    for (int i = t; i < 1024; i += 256) kh[i] = 0;
    __syncthreads();
    int beg = b * BKT_CAP, end = gcur[b];
    for (int i = beg + t; i < end; i += 256)
        atomicAdd(&kh[pairs[i].x & 1023], 1);
    __syncthreads();
    // exclusive scan over the bucket's 1024 counts (4 per thread)
    int v[4];
    int s = 0;
#pragma unroll
    for (int q = 0; q < 4; q++) {
        v[q] = kh[t * 4 + q];
        s += v[q];
    }
    scn[t] = s;
    __syncthreads();
    for (int st = 1; st < 256; st <<= 1) {
        int u = (t >= st) ? scn[t - st] : 0;
        __syncthreads();
        scn[t] += u;
        __syncthreads();
    }
    int run = b * BKT_CAP + scn[t] - s;
    int kbase = b << BKT_SH;
#pragma unroll
    for (int q = 0; q < 4; q++) {
        int key = kbase + t * 4 + q;
        if (key < TWO_NN) {
            off[key] = run;
            endo[key] = run + v[q];
            inv[key] = 1.0f / (float)(v[q] > 1 ? v[q] : 1);
        }
        run += v[q];
    }
}

// ---------------------------------------------------------------------------
// Pass B2: place pairs into padded CSR (bucket range contiguous -> L2-hot).
__global__ void __launch_bounds__(256) placeB_kernel(
        const int* __restrict__ gcur, const int2* __restrict__ pairs,
        const int* __restrict__ off, int* __restrict__ csr) {
    __shared__ int kc[1024];
    int b = blockIdx.x;
    int t = threadIdx.x;
    int kbase = b << BKT_SH;
    for (int i = t; i < 1024; i += 256)
        if (kbase + i < TWO_NN) kc[i] = off[kbase + i];
    __syncthreads();
    int beg = b * BKT_CAP, end = gcur[b];
    for (int i = beg + t; i < end; i += 256) {
        int2 p = pairs[i];
        int pos = atomicAdd(&kc[p.x & 1023], 1);
        csr[pos] = p.y;
    }
}

// ---------------------------------------------------------------------------
// Fused input embed (paper+mesh in one launch): fp32 out + bf16 shadow.
__global__ void __launch_bounds__(256) embed2_kernel(
        const float* __restrict__ Xp, const float* __restrict__ Xm,
        const float* __restrict__ Wp, const float* __restrict__ bp,
        const float* __restrict__ Wm, const float* __restrict__ bm,
        float* __restrict__ out, unsigned short* __restrict__ outbf) {
    __shared__ float Wl[4096 + 32];
    for (int i = threadIdx.x; i < 2048; i += 256) {
        Wl[i] = Wp[i];
        Wl[2048 + i] = Wm[i];
    }
    if (threadIdx.x < 16) {
        Wl[4096 + threadIdx.x] = bp[threadIdx.x];
        Wl[4112 + threadIdx.x] = bm[threadIdx.x];
    }
    __syncthreads();
    int n = blockIdx.x * 256 + threadIdx.x;
    if (n >= NN) return;
    const float* X;
    const float* Ws;
    const float* Bs;
    if (n < NP) { X = Xp + (size_t)n * 128; Ws = Wl; Bs = Wl + 4096; }
    else        { X = Xm + (size_t)(n - NP) * 128; Ws = Wl + 2048; Bs = Wl + 4112; }
    float acc[16];
#pragma unroll
    for (int j = 0; j < 16; j++) acc[j] = Bs[j];
    const float4* row = (const float4*)X;
    for (int k4 = 0; k4 < 32; k4++) {
        float4 xv = row[k4];
        int k = k4 * 4;
#pragma unroll
        for (int j = 0; j < 16; j++) {
            float a = acc[j];
            a = fmaf(xv.x, Ws[(k + 0) * 16 + j], a);
            a = fmaf(xv.y, Ws[(k + 1) * 16 + j], a);
            a = fmaf(xv.z, Ws[(k + 2) * 16 + j], a);
            a = fmaf(xv.w, Ws[(k + 3) * 16 + j], a);
            acc[j] = a;
        }
    }
    float4* o = (float4*)(out + (size_t)n * 16);
    ushort4* ob = (ushort4*)(outbf + (size_t)n * 16);
#pragma unroll
    for (int q = 0; q < 4; q++) {
        o[q] = make_float4(acc[4 * q], acc[4 * q + 1], acc[4 * q + 2], acc[4 * q + 3]);
        ushort4 ub;
        ub.x = f2bf(acc[4 * q]);     ub.y = f2bf(acc[4 * q + 1]);
        ub.z = f2bf(acc[4 * q + 2]); ub.w = f2bf(acc[4 * q + 3]);
        ob[q] = ub;
    }
}

// ---------------------------------------------------------------------------
// All 4 layers' weight prep in ONE launch: block l handles layer l.
// Wbuf4 layout per layer (stride 3200): [W0 | W1 | root | bias]
__global__ void prep_all_kernel(
        const float* __restrict__ ba0, const float* __restrict__ co0,
        const float* __restrict__ ro0, const float* __restrict__ bi0,
        const float* __restrict__ ba1, const float* __restrict__ co1,
        const float* __restrict__ ro1, const float* __restrict__ bi1,
        const float* __restrict__ ba2, const float* __restrict__ co2,
        const float* __restrict__ ro2, const float* __restrict__ bi2,
        const float* __restrict__ ba3, const float* __restrict__ co3,
        const float* __restrict__ ro3, const float* __restrict__ bi3,
        float* __restrict__ Wbuf4) {
    int l = blockIdx.x;
    const float* bases; const float* comp; const float* root; const float* bias;
    if (l == 0)      { bases = ba0; comp = co0; root = ro0; bias = bi0; }
    else if (l == 1) { bases = ba1; comp = co1; root = ro1; bias = bi1; }
    else if (l == 2) { bases = ba2; comp = co2; root = ro2; bias = bi2; }
    else             { bases = ba3; comp = co3; root = ro3; bias = bi3; }
    int din = (l == 0) ? 16 : 32;
    int dout = (l == 3) ? 16 : 32;
    int sz = din * dout;
    float* W = Wbuf4 + l * 3200;
    for (int i = threadIdx.x; i < sz; i += 256) {
        float b0 = bases[i];
        float b1 = bases[sz + i];
        float b2 = bases[2 * sz + i];
        float b3 = bases[3 * sz + i];
        for (int r = 0; r < 2; r++) {
            W[r * sz + i] = comp[r * 4 + 0] * b0 + comp[r * 4 + 1] * b1 +
                            comp[r * 4 + 2] * b2 + comp[r * 4 + 3] * b3;
        }
        W[2 * sz + i] = root[i];
    }
    if (threadIdx.x < dout) W[3 * sz + threadIdx.x] = bias[threadIdx.x];
}

// ---------------------------------------------------------------------------
// Fused RGCN layer. Phase 1: per-(node, rel) lane groups gather bf16 rows with
// a 4-edge-unrolled loop (4 independent accumulator quads -> 2x cache lines in
// flight vs R11's 2-unroll; discriminates MLP-bound vs miss-throughput-bound).
// Phase 2: combine matmul from LDS, fp32 out + bf16 shadow.
template <int DIN, int DOUT, int RELU, int WBF>
__global__ void __launch_bounds__(256) layer_kernel(
        const int* __restrict__ off, const int* __restrict__ endo,
        const int* __restrict__ csr,
        const float* __restrict__ xin, const unsigned short* __restrict__ xbf_in,
        const float* __restrict__ inv, const float* __restrict__ Wbuf,
        float* __restrict__ xout, unsigned short* __restrict__ xbf_out) {
    constexpr int SZ = DIN * DOUT;
    constexpr int QL = DIN / 4;       // gather lanes per (node, rel)
    constexpr int TPN = 2 * QL;       // phase-1 threads per node
    constexpr int NPB = 256 / TPN;    // nodes per block
    constexpr int AGST = 2 * DIN + 4; // agg LDS row stride
    constexpr int XSST = DIN + 4;     // xs LDS row stride
    __shared__ float Wl[3 * SZ + DOUT];
    __shared__ float agg[NPB * AGST];
    __shared__ float xs[NPB * XSST];
    for (int i = threadIdx.x; i < 3 * SZ + DOUT; i += 256) Wl[i] = Wbuf[i];
    int t = threadIdx.x;
    int ln = t / TPN;
    int rl = t % TPN;
    int r = rl / QL;
    int lane = rl % QL;
    int d = blockIdx.x * NPB + ln;
    if (d < NN) {
        if (r == 0)
            *(float4*)(xs + ln * XSST + lane * 4) =
                *(const float4*)(xin + (size_t)d * DIN + lane * 4);
        int key = r * NN + d;
        int b = off[key];
        int e = endo[key];
        float4 a0 = make_float4(0, 0, 0, 0), a1 = make_float4(0, 0, 0, 0);
        float4 a2 = make_float4(0, 0, 0, 0), a3 = make_float4(0, 0, 0, 0);
        const unsigned short* hp = xbf_in + lane * 4;
        int k = b;
        for (; k + 3 < e; k += 4) {
            int s0 = csr[k];
            int s1 = csr[k + 1];
            int s2 = csr[k + 2];
            int s3 = csr[k + 3];
            ushort4 u0 = *(const ushort4*)(hp + (size_t)s0 * DIN);
            ushort4 u1 = *(const ushort4*)(hp + (size_t)s1 * DIN);
            ushort4 u2 = *(const ushort4*)(hp + (size_t)s2 * DIN);
            ushort4 u3 = *(const ushort4*)(hp + (size_t)s3 * DIN);
            a0.x += bf2f(u0.x); a0.y += bf2f(u0.y); a0.z += bf2f(u0.z); a0.w += bf2f(u0.w);
            a1.x += bf2f(u1.x); a1.y += bf2f(u1.y); a1.z += bf2f(u1.z); a1.w += bf2f(u1.w);
            a2.x += bf2f(u2.x); a2.y += bf2f(u2.y); a2.z += bf2f(u2.z); a2.w += bf2f(u2.w);
            a3.x += bf2f(u3.x); a3.y += bf2f(u3.y); a3.z += bf2f(u3.z); a3.w += bf2f(u3.w);
        }
        for (; k < e; k++) {
            ushort4 u0 = *(const ushort4*)(hp + (size_t)csr[k] * DIN);
            a0.x += bf2f(u0.x); a0.y += bf2f(u0.y); a0.z += bf2f(u0.z); a0.w += bf2f(u0.w);
        }
        *(float4*)(agg + ln * AGST + r * DIN + lane * 4) =
            make_float4(a0.x + a1.x + a2.x + a3.x, a0.y + a1.y + a2.y + a3.y,
                        a0.z + a1.z + a2.z + a3.z, a0.w + a1.w + a2.w + a3.w);
    }
    __syncthreads();
    constexpr int CPN = DOUT / 4;
    if (t < NPB * CPN) {
        int ln2 = t / CPN;
        int j0 = (t % CPN) * 4;
        int d2 = blockIdx.x * NPB + ln2;
        if (d2 < NN) {
            float iv0 = inv[d2], iv1 = inv[NN + d2];
            float acc[4];
#pragma unroll
            for (int jj = 0; jj < 4; jj++) acc[jj] = Wl[3 * SZ + j0 + jj];
#pragma unroll
            for (int k = 0; k < DIN; k++) {
                float xv = xs[ln2 * XSST + k];
                float a0 = agg[ln2 * AGST + k] * iv0;
                float a1 = agg[ln2 * AGST + DIN + k] * iv1;
                const float* w0 = &Wl[k * DOUT + j0];
                const float* w1 = &Wl[SZ + k * DOUT + j0];
                const float* wr = &Wl[2 * SZ + k * DOUT + j0];
#pragma unroll
                for (int jj = 0; jj < 4; jj++) {
                    acc[jj] = fmaf(xv, wr[jj], acc[jj]);
                    acc[jj] = fmaf(a0, w0[jj], acc[jj]);
                    acc[jj] = fmaf(a1, w1[jj], acc[jj]);
                }
            }
            if (RELU) {
#pragma unroll
                for (int jj = 0; jj < 4; jj++) acc[jj] = fmaxf(acc[jj], 0.0f);
            }
            *(float4*)(xout + (size_t)d2 * DOUT + j0) =
                make_float4(acc[0], acc[1], acc[2], acc[3]);
            if (WBF) {
                ushort4 ub;
                ub.x = f2bf(acc[0]); ub.y = f2bf(acc[1]);
                ub.z = f2bf(acc[2]); ub.w = f2bf(acc[3]);
                *(ushort4*)(xbf_out + (size_t)d2 * DOUT + j0) = ub;
            }
        }
    }
}

// ---------------------------------------------------------------------------
// Decode prep: y0 = z @ Wd0 + bd0 ; y1 = z @ Wd1 + bd1   (all 16-dim)
__global__ void decode_prep_kernel(const float* __restrict__ z,
                                   const float* __restrict__ Wd0,
                                   const float* __restrict__ bd0,
                                   const float* __restrict__ Wd1,
                                   const float* __restrict__ bd1,
                                   float* __restrict__ y0, float* __restrict__ y1) {
    __shared__ float W0l[256], W1l[256], B0[16], B1[16];
    for (int i = threadIdx.x; i < 256; i += blockDim.x) {
        W0l[i] = Wd0[i];
        W1l[i] = Wd1[i];
    }
    if (threadIdx.x < 16) {
        B0[threadIdx.x] = bd0[threadIdx.x];
        B1[threadIdx.x] = bd1[threadIdx.x];
    }
    __syncthreads();
    int n = blockIdx.x * blockDim.x + threadIdx.x;
    if (n >= NN) return;
    float zr[16];
    const float* zp = z + (size_t)n * 16;
#pragma unroll
    for (int k = 0; k < 16; k++) zr[k] = zp[k];
    float o0[16], o1[16];
#pragma unroll
    for (int j = 0; j < 16; j++) {
        float a0 = B0[j], a1 = B1[j];
#pragma unroll
        for (int k = 0; k < 16; k++) {
            a0 = fmaf(zr[k], W0l[k * 16 + j], a0);
            a1 = fmaf(zr[k], W1l[k * 16 + j], a1);
        }
        o0[j] = a0;
        o1[j] = a1;
    }
    float4* p0 = (float4*)(y0 + (size_t)n * 16);
    float4* p1 = (float4*)(y1 + (size_t)n * 16);
#pragma unroll
    for (int q = 0; q < 4; q++) {
        p0[q] = make_float4(o0[4 * q], o0[4 * q + 1], o0[4 * q + 2], o0[4 * q + 3]);
        p1[q] = make_float4(o1[4 * q], o1[4 * q + 1], o1[4 * q + 2], o1[4 * q + 3]);
    }
}

// ---------------------------------------------------------------------------
// Decode: out[i] = dot( y_{et}[src], z[dst] )  — fp32 output
__global__ void decode_kernel(const float* __restrict__ y0, const float* __restrict__ y1,
                              const float* __restrict__ z,
                              const int* __restrict__ pei, const int* __restrict__ pet,
                              const int* __restrict__ nei, const int* __restrict__ net_,
                              float* __restrict__ out,
                              const int* __restrict__ dflag) {
    int i = blockIdx.x * blockDim.x + threadIdx.x;
    if (i >= 2 * ED) return;
    int sft = dflag[0];
    const int* ei;
    const int* et;
    int e;
    if (i < ED) { ei = pei; et = pet; e = i; }
    else        { ei = nei; et = net_; e = i - ED; }
    int s = ei[(size_t)e << sft];
    int d = ei[(size_t)(ED + e) << sft];
    int r = et[(size_t)e << sft];
    const float4* yv = (const float4*)((r ? y1 : y0) + ((size_t)s << 4));
    const float4* zv = (const float4*)(z + ((size_t)d << 4));
    float acc = 0.0f;
#pragma unroll
    for (int q = 0; q < 4; q++) {
        float4 a = yv[q];
        float4 b = zv[q];
        acc += a.x * b.x + a.y * b.y + a.z * b.z + a.w * b.w;
    }
    out[i] = acc;
}

// ---------------------------------------------------------------------------
extern "C" void kernel_launch(void* const* d_in, const int* in_sizes, int n_in,
                              void* d_out, int out_size, void* d_ws, size_t ws_size,
                              hipStream_t stream) {
    const float* x_paper = (const float*)d_in[0];
    const float* x_mesh  = (const float*)d_in[1];
    const int* tei  = (const int*)d_in[2];
    const int* tet  = (const int*)d_in[3];
    const int* pei  = (const int*)d_in[4];
    const int* pet  = (const int*)d_in[5];
    const int* nei  = (const int*)d_in[6];
    const int* net_ = (const int*)d_in[7];
    const float* Wp  = (const float*)d_in[8];
    const float* bp  = (const float*)d_in[9];
    const float* Wm  = (const float*)d_in[10];
    const float* bm  = (const float*)d_in[11];
    const float* Wd0 = (const float*)d_in[12];
    const float* bd0 = (const float*)d_in[13];
    const float* Wd1 = (const float*)d_in[14];
    const float* bd1 = (const float*)d_in[15];

    // Workspace carve-up (fp32/int32 elements) — ~62 MB total
    float* ws = (float*)d_ws;
    size_t o = 0;
    float* bufA = ws + o; o += (size_t)NN * 32;
    float* bufB = ws + o; o += (size_t)NN * 32;
    unsigned short* xbfA = (unsigned short*)(ws + o); o += (size_t)NN * 16; // NN*32 bf16
    unsigned short* xbfB = (unsigned short*)(ws + o); o += (size_t)NN * 16;
    float* inv  = ws + o; o += (size_t)TWO_NN;
    int*   off  = (int*)(ws + o); o += (size_t)TWO_NN;
    int*   endo = (int*)(ws + o); o += (size_t)TWO_NN;
    int*   csr  = (int*)(ws + o); o += (size_t)NB_BKT * BKT_CAP; // padded
    int*   gcur = (int*)(ws + o); o += 256;
    int2*  pairs = (int2*)(ws + o); o += (size_t)2 * NB_BKT * BKT_CAP; // 17.3 MB
    float* Wbuf4 = ws + o; o += 4 * 3200;
    int*   dflag = (int*)(ws + o); o += 16;

    // 0. Dtype detect
    detect_kernel<<<1, 64, 0, stream>>>(tei, dflag);

    // 1. Binned padded-bucket CSR build (once; edge structure layer-invariant)
    init_gcur_kernel<<<1, 256, 0, stream>>>(gcur);
    binA_kernel<<<N_TILES, 256, 0, stream>>>(tei, tet, dflag, gcur, pairs);
    histB_kernel<<<NB_BKT, 256, 0, stream>>>(gcur, pairs, off, endo, inv);
    placeB_kernel<<<NB_BKT, 256, 0, stream>>>(gcur, pairs, off, csr);

    // 2. Fused embed (paper+mesh) -> bufA fp32 + xbfA bf16
    embed2_kernel<<<(NN + 255) / 256, 256, 0, stream>>>(
        x_paper, x_mesh, Wp, bp, Wm, bm, bufA, xbfA);

    // 3. All layer weights in one launch
    prep_all_kernel<<<4, 256, 0, stream>>>(
        (const float*)d_in[16], (const float*)d_in[17], (const float*)d_in[18], (const float*)d_in[19],
        (const float*)d_in[20], (const float*)d_in[21], (const float*)d_in[22], (const float*)d_in[23],
        (const float*)d_in[24], (const float*)d_in[25], (const float*)d_in[26], (const float*)d_in[27],
        (const float*)d_in[28], (const float*)d_in[29], (const float*)d_in[30], (const float*)d_in[31],
        Wbuf4);

    // 4. Four fused RGCN layers (gather->LDS->combine), ping-pong buffers
    int blk16 = (NN + 31) / 32; // DIN=16: 32 nodes/block
    int blk32 = (NN + 15) / 16; // DIN=32: 16 nodes/block
    layer_kernel<16, 32, 1, 1><<<blk16, 256, 0, stream>>>(
        off, endo, csr, bufA, xbfA, inv, Wbuf4 + 0 * 3200, bufB, xbfB);
    layer_kernel<32, 32, 1, 1><<<blk32, 256, 0, stream>>>(
        off, endo, csr, bufB, xbfB, inv, Wbuf4 + 1 * 3200, bufA, xbfA);
    layer_kernel<32, 32, 1, 1><<<blk32, 256, 0, stream>>>(
        off, endo, csr, bufA, xbfA, inv, Wbuf4 + 2 * 3200, bufB, xbfB);
    layer_kernel<32, 16, 0, 0><<<blk32, 256, 0, stream>>>(
        off, endo, csr, bufB, xbfB, inv, Wbuf4 + 3 * 3200, bufA, xbfA /*unused*/);
    // z = bufA [NN,16]; bufB now free

    // 5. Decode (y0/y1 live in bufB)
    float* y0 = bufB;
    float* y1 = bufB + (size_t)NN * 16;
    decode_prep_kernel<<<(NN + 255) / 256, 256, 0, stream>>>(bufA, Wd0, bd0, Wd1, bd1,
                                                             y0, y1);
    decode_kernel<<<(2 * ED + 255) / 256, 256, 0, stream>>>(
        y0, y1, bufA, pei, pet, nei, net_, (float*)d_out, dflag);
}

// Round 13
// 400.381 us; speedup vs baseline: 3.6769x; 1.0752x over previous
//
#include <hip/hip_runtime.h>
#include <hip/hip_bf16.h>

// Problem constants (from reference)
constexpr int NN = 90000;   // total nodes
constexpr int NP = 60000;   // paper nodes
constexpr int NM = 30000;   // mesh nodes
constexpr int ET = 2000000; // train edges
constexpr int ED = 400000;  // decode edges (each of pos/neg)
constexpr int TWO_NN = 2 * NN;

// Binned CSR build parameters
constexpr int BKT_SH  = 10;                        // 1024 keys per bucket
constexpr int NB_BKT  = (TWO_NN + 1023) >> BKT_SH; // 176 buckets
constexpr int BKT_CAP = 12288;                     // mean 11366, +8.7 sigma
constexpr int TILE    = 2048;                      // edges per binning tile
constexpr int N_TILES = (ET + TILE - 1) / TILE;    // 977

__device__ __forceinline__ float bflo(unsigned int u) {
    union { unsigned int i; float f; } c;
    c.i = u << 16;
    return c.f;
}
__device__ __forceinline__ float bfhi(unsigned int u) {
    union { unsigned int i; float f; } c;
    c.i = u & 0xffff0000u;
    return c.f;
}
__device__ __forceinline__ unsigned short f2bf(float f) {
    union { float f; unsigned int i; } c;
    c.f = f;
    unsigned int x = c.i;
    return (unsigned short)((x + 0x7FFFu + ((x >> 16) & 1u)) >> 16);
}

// ---------------------------------------------------------------------------
// Init: gcur cursors + int32/int64 dtype flag (merged; saves a launch).
__global__ void init_kernel(const int* __restrict__ tei, int* __restrict__ gcur,
                            int* __restrict__ dflag) {
    int b = blockIdx.x * blockDim.x + threadIdx.x;
    if (b < NB_BKT) gcur[b] = b * BKT_CAP;
    if (b == 0) {
        int allzero = 1;
        for (int i = 0; i < 16; i++)
            if (tei[2 * i + 1] != 0) allzero = 0;
        dflag[0] = allzero; // 1 => int64 => index shift 1
    }
}

// ---------------------------------------------------------------------------
// Pass A: bin edges into per-bucket pair arrays with line-dense writes.
__global__ void __launch_bounds__(256) binA_kernel(
        const int* __restrict__ ei, const int* __restrict__ et,
        const int* __restrict__ dflag, int* __restrict__ gcur,
        int2* __restrict__ pairs) {
    __shared__ int hist[NB_BKT];
    __shared__ int excl[NB_BKT];
    __shared__ int cur[NB_BKT];
    __shared__ int gbase[NB_BKT];
    __shared__ int scn[256];
    __shared__ int2 tbuf[TILE];
    int t = threadIdx.x;
    int tile0 = blockIdx.x * TILE;
    int tcount = ET - tile0;
    if (tcount > TILE) tcount = TILE;
    for (int i = t; i < NB_BKT; i += 256) hist[i] = 0;
    __syncthreads();
    int sft = dflag[0];
    int myk[8], mys[8];
#pragma unroll
    for (int q = 0; q < 8; q++) {
        int li = q * 256 + t;
        myk[q] = -1;
        if (li < tcount) {
            int e = tile0 + li;
            int s = ei[(size_t)e << sft];
            int d = ei[(size_t)(ET + e) << sft];
            int r = et[(size_t)e << sft];
            int key = r * NN + d;
            myk[q] = key;
            mys[q] = s;
            atomicAdd(&hist[key >> BKT_SH], 1);
        }
    }
    __syncthreads();
    int v = (t < NB_BKT) ? hist[t] : 0;
    scn[t] = v;
    __syncthreads();
    for (int st = 1; st < 256; st <<= 1) {
        int u = (t >= st) ? scn[t - st] : 0;
        __syncthreads();
        scn[t] += u;
        __syncthreads();
    }
    if (t < NB_BKT) {
        excl[t] = scn[t] - v;
        cur[t] = scn[t] - v;
    }
    __syncthreads();
#pragma unroll
    for (int q = 0; q < 8; q++) {
        if (myk[q] >= 0) {
            int b = myk[q] >> BKT_SH;
            int p = atomicAdd(&cur[b], 1);
            tbuf[p] = make_int2(myk[q], mys[q]);
        }
    }
    __syncthreads();
    if (t < NB_BKT && hist[t] > 0) gbase[t] = atomicAdd(&gcur[t], hist[t]);
    __syncthreads();
    for (int i = t; i < tcount; i += 256) {
        int2 p = tbuf[i];
        int b = p.x >> BKT_SH;
        int gpos = gbase[b] + (i - excl[b]);
        int cap = (b + 1) * BKT_CAP - 1;
        pairs[gpos < cap ? gpos : cap] = p;
    }
}

// ---------------------------------------------------------------------------
// Pass B1: per-bucket key histogram + block-local exclusive scan ->
// padded-bucket CSR offsets (off/end) + inv, written densely.
__global__ void __launch_bounds__(256) histB_kernel(
        const int* __restrict__ gcur, const int2* __restrict__ pairs,
        int* __restrict__ off, int* __restrict__ endo, float* __restrict__ inv) {
    __shared__ int kh[1024];
    __shared__ int scn[256];
    int b = blockIdx.x;
    int t = threadIdx.x;
    for (int i = t; i < 1024; i += 256) kh[i] = 0;
    __syncthreads();
    int beg = b * BKT_CAP, end = gcur[b];
    for (int i = beg + t; i < end; i += 256)
        atomicAdd(&kh[pairs[i].x & 1023], 1);
    __syncthreads();
    int v[4];
    int s = 0;
#pragma unroll
    for (int q = 0; q < 4; q++) {
        v[q] = kh[t * 4 + q];
        s += v[q];
    }
    scn[t] = s;
    __syncthreads();
    for (int st = 1; st < 256; st <<= 1) {
        int u = (t >= st) ? scn[t - st] : 0;
        __syncthreads();
        scn[t] += u;
        __syncthreads();
    }
    int run = b * BKT_CAP + scn[t] - s;
    int kbase = b << BKT_SH;
#pragma unroll
    for (int q = 0; q < 4; q++) {
        int key = kbase + t * 4 + q;
        if (key < TWO_NN) {
            off[key] = run;
            endo[key] = run + v[q];
            inv[key] = 1.0f / (float)(v[q] > 1 ? v[q] : 1);
        }
        run += v[q];
    }
}

// ---------------------------------------------------------------------------
// Pass B2: place pairs into padded CSR (bucket range contiguous -> L2-hot).
__global__ void __launch_bounds__(256) placeB_kernel(
        const int* __restrict__ gcur, const int2* __restrict__ pairs,
        const int* __restrict__ off, int* __restrict__ csr) {
    __shared__ int kc[1024];
    int b = blockIdx.x;
    int t = threadIdx.x;
    int kbase = b << BKT_SH;
    for (int i = t; i < 1024; i += 256)
        if (kbase + i < TWO_NN) kc[i] = off[kbase + i];
    __syncthreads();
    int beg = b * BKT_CAP, end = gcur[b];
    for (int i = beg + t; i < end; i += 256) {
        int2 p = pairs[i];
        int pos = atomicAdd(&kc[p.x & 1023], 1);
        csr[pos] = p.y;
    }
}

// ---------------------------------------------------------------------------
// Fused input embed (paper+mesh in one launch): fp32 out + bf16 shadow.
__global__ void __launch_bounds__(256) embed2_kernel(
        const float* __restrict__ Xp, const float* __restrict__ Xm,
        const float* __restrict__ Wp, const float* __restrict__ bp,
        const float* __restrict__ Wm, const float* __restrict__ bm,
        float* __restrict__ out, unsigned short* __restrict__ outbf) {
    __shared__ float Wl[4096 + 32];
    for (int i = threadIdx.x; i < 2048; i += 256) {
        Wl[i] = Wp[i];
        Wl[2048 + i] = Wm[i];
    }
    if (threadIdx.x < 16) {
        Wl[4096 + threadIdx.x] = bp[threadIdx.x];
        Wl[4112 + threadIdx.x] = bm[threadIdx.x];
    }
    __syncthreads();
    int n = blockIdx.x * 256 + threadIdx.x;
    if (n >= NN) return;
    const float* X;
    const float* Ws;
    const float* Bs;
    if (n < NP) { X = Xp + (size_t)n * 128; Ws = Wl; Bs = Wl + 4096; }
    else        { X = Xm + (size_t)(n - NP) * 128; Ws = Wl + 2048; Bs = Wl + 4112; }
    float acc[16];
#pragma unroll
    for (int j = 0; j < 16; j++) acc[j] = Bs[j];
    const float4* row = (const float4*)X;
    for (int k4 = 0; k4 < 32; k4++) {
        float4 xv = row[k4];
        int k = k4 * 4;
#pragma unroll
        for (int j = 0; j < 16; j++) {
            float a = acc[j];
            a = fmaf(xv.x, Ws[(k + 0) * 16 + j], a);
            a = fmaf(xv.y, Ws[(k + 1) * 16 + j], a);
            a = fmaf(xv.z, Ws[(k + 2) * 16 + j], a);
            a = fmaf(xv.w, Ws[(k + 3) * 16 + j], a);
            acc[j] = a;
        }
    }
    float4* o = (float4*)(out + (size_t)n * 16);
    ushort4* ob = (ushort4*)(outbf + (size_t)n * 16);
#pragma unroll
    for (int q = 0; q < 4; q++) {
        o[q] = make_float4(acc[4 * q], acc[4 * q + 1], acc[4 * q + 2], acc[4 * q + 3]);
        ushort4 ub;
        ub.x = f2bf(acc[4 * q]);     ub.y = f2bf(acc[4 * q + 1]);
        ub.z = f2bf(acc[4 * q + 2]); ub.w = f2bf(acc[4 * q + 3]);
        ob[q] = ub;
    }
}

// ---------------------------------------------------------------------------
// All 4 layers' weight prep in ONE launch: block l handles layer l.
// Wbuf4 layout per layer (stride 3200): [W0 | W1 | root | bias]
__global__ void prep_all_kernel(
        const float* __restrict__ ba0, const float* __restrict__ co0,
        const float* __restrict__ ro0, const float* __restrict__ bi0,
        const float* __restrict__ ba1, const float* __restrict__ co1,
        const float* __restrict__ ro1, const float* __restrict__ bi1,
        const float* __restrict__ ba2, const float* __restrict__ co2,
        const float* __restrict__ ro2, const float* __restrict__ bi2,
        const float* __restrict__ ba3, const float* __restrict__ co3,
        const float* __restrict__ ro3, const float* __restrict__ bi3,
        float* __restrict__ Wbuf4) {
    int l = blockIdx.x;
    const float* bases; const float* comp; const float* root; const float* bias;
    if (l == 0)      { bases = ba0; comp = co0; root = ro0; bias = bi0; }
    else if (l == 1) { bases = ba1; comp = co1; root = ro1; bias = bi1; }
    else if (l == 2) { bases = ba2; comp = co2; root = ro2; bias = bi2; }
    else             { bases = ba3; comp = co3; root = ro3; bias = bi3; }
    int din = (l == 0) ? 16 : 32;
    int dout = (l == 3) ? 16 : 32;
    int sz = din * dout;
    float* W = Wbuf4 + l * 3200;
    for (int i = threadIdx.x; i < sz; i += 256) {
        float b0 = bases[i];
        float b1 = bases[sz + i];
        float b2 = bases[2 * sz + i];
        float b3 = bases[3 * sz + i];
        for (int r = 0; r < 2; r++) {
            W[r * sz + i] = comp[r * 4 + 0] * b0 + comp[r * 4 + 1] * b1 +
                            comp[r * 4 + 2] * b2 + comp[r * 4 + 3] * b3;
        }
        W[2 * sz + i] = root[i];
    }
    if (threadIdx.x < dout) W[3 * sz + threadIdx.x] = bias[threadIdx.x];
}

// ---------------------------------------------------------------------------
// Fused RGCN layer. Phase 1: 16 B/lane bf16 gathers (QL=DIN/8 lanes per
// (node, rel) group; halves gather wave-instructions vs 8 B/lane). Phase 2:
// combine matmul from LDS, fp32 out + bf16 shadow.
template <int DIN, int DOUT, int RELU, int WBF>
__global__ void __launch_bounds__(256) layer_kernel(
        const int* __restrict__ off, const int* __restrict__ endo,
        const int* __restrict__ csr,
        const float* __restrict__ xin, const unsigned short* __restrict__ xbf_in,
        const float* __restrict__ inv, const float* __restrict__ Wbuf,
        float* __restrict__ xout, unsigned short* __restrict__ xbf_out) {
    constexpr int SZ = DIN * DOUT;
    constexpr int QL = DIN / 8;       // gather lanes per (node, rel): 16 B each
    constexpr int TPN = 2 * QL;       // phase-1 threads per node (== DIN/4)
    constexpr int NPB = 256 / TPN;    // nodes per block
    constexpr int AGST = 2 * DIN + 4; // agg LDS row stride
    constexpr int XSST = DIN + 4;     // xs LDS row stride
    __shared__ float Wl[3 * SZ + DOUT];
    __shared__ float agg[NPB * AGST];
    __shared__ float xs[NPB * XSST];
    for (int i = threadIdx.x; i < 3 * SZ + DOUT; i += 256) Wl[i] = Wbuf[i];
    int t = threadIdx.x;
    int ln = t / TPN;
    int rl = t % TPN;
    int r = rl / QL;
    int lane = rl % QL;
    int d = blockIdx.x * NPB + ln;
    if (d < NN) {
        // stage own row (all TPN threads: TPN == DIN/4 float4 chunks)
        *(float4*)(xs + ln * XSST + rl * 4) =
            *(const float4*)(xin + (size_t)d * DIN + rl * 4);
        int key = r * NN + d;
        int b = off[key];
        int e = endo[key];
        float a0[8] = {0, 0, 0, 0, 0, 0, 0, 0};
        float a1[8] = {0, 0, 0, 0, 0, 0, 0, 0};
        const unsigned short* hp = xbf_in + lane * 8;
        int k = b;
        for (; k + 1 < e; k += 2) {
            int s0 = csr[k];
            int s1 = csr[k + 1];
            uint4 u0 = *(const uint4*)(hp + (size_t)s0 * DIN);
            uint4 u1 = *(const uint4*)(hp + (size_t)s1 * DIN);
            a0[0] += bflo(u0.x); a0[1] += bfhi(u0.x);
            a0[2] += bflo(u0.y); a0[3] += bfhi(u0.y);
            a0[4] += bflo(u0.z); a0[5] += bfhi(u0.z);
            a0[6] += bflo(u0.w); a0[7] += bfhi(u0.w);
            a1[0] += bflo(u1.x); a1[1] += bfhi(u1.x);
            a1[2] += bflo(u1.y); a1[3] += bfhi(u1.y);
            a1[4] += bflo(u1.z); a1[5] += bfhi(u1.z);
            a1[6] += bflo(u1.w); a1[7] += bfhi(u1.w);
        }
        if (k < e) {
            uint4 u0 = *(const uint4*)(hp + (size_t)csr[k] * DIN);
            a0[0] += bflo(u0.x); a0[1] += bfhi(u0.x);
            a0[2] += bflo(u0.y); a0[3] += bfhi(u0.y);
            a0[4] += bflo(u0.z); a0[5] += bfhi(u0.z);
            a0[6] += bflo(u0.w); a0[7] += bfhi(u0.w);
        }
        float* ap = agg + ln * AGST + r * DIN + lane * 8;
        *(float4*)ap = make_float4(a0[0] + a1[0], a0[1] + a1[1],
                                   a0[2] + a1[2], a0[3] + a1[3]);
        *(float4*)(ap + 4) = make_float4(a0[4] + a1[4], a0[5] + a1[5],
                                         a0[6] + a1[6], a0[7] + a1[7]);
    }
    __syncthreads();
    constexpr int CPN = DOUT / 4;
    for (int tt = t; tt < NPB * CPN; tt += 256) {
        int ln2 = tt / CPN;
        int j0 = (tt % CPN) * 4;
        int d2 = blockIdx.x * NPB + ln2;
        if (d2 < NN) {
            float iv0 = inv[d2], iv1 = inv[NN + d2];
            float acc[4];
#pragma unroll
            for (int jj = 0; jj < 4; jj++) acc[jj] = Wl[3 * SZ + j0 + jj];
#pragma unroll
            for (int k = 0; k < DIN; k++) {
                float xv = xs[ln2 * XSST + k];
                float m0 = agg[ln2 * AGST + k] * iv0;
                float m1 = agg[ln2 * AGST + DIN + k] * iv1;
                const float* w0 = &Wl[k * DOUT + j0];
                const float* w1 = &Wl[SZ + k * DOUT + j0];
                const float* wr = &Wl[2 * SZ + k * DOUT + j0];
#pragma unroll
                for (int jj = 0; jj < 4; jj++) {
                    acc[jj] = fmaf(xv, wr[jj], acc[jj]);
                    acc[jj] = fmaf(m0, w0[jj], acc[jj]);
                    acc[jj] = fmaf(m1, w1[jj], acc[jj]);
                }
            }
            if (RELU) {
#pragma unroll
                for (int jj = 0; jj < 4; jj++) acc[jj] = fmaxf(acc[jj], 0.0f);
            }
            *(float4*)(xout + (size_t)d2 * DOUT + j0) =
                make_float4(acc[0], acc[1], acc[2], acc[3]);
            if (WBF) {
                ushort4 ub;
                ub.x = f2bf(acc[0]); ub.y = f2bf(acc[1]);
                ub.z = f2bf(acc[2]); ub.w = f2bf(acc[3]);
                *(ushort4*)(xbf_out + (size_t)d2 * DOUT + j0) = ub;
            }
        }
    }
}

// ---------------------------------------------------------------------------
// Fused decode: out[i] = dot( z[s]@Wd_r + bd_r , z[d] ).
// Single 5.76 MB z table for all gathers (vs 17 MB y0/y1+z before) ->
// much higher L2 hit rate; eliminates decode_prep entirely.
__global__ void __launch_bounds__(256) decode_fused_kernel(
        const float* __restrict__ z,
        const float* __restrict__ Wd0, const float* __restrict__ bd0,
        const float* __restrict__ Wd1, const float* __restrict__ bd1,
        const int* __restrict__ pei, const int* __restrict__ pet,
        const int* __restrict__ nei, const int* __restrict__ net_,
        float* __restrict__ out, const int* __restrict__ dflag) {
    __shared__ float W[2][256];
    __shared__ float B[2][16];
    for (int i = threadIdx.x; i < 256; i += 256) {
        W[0][i] = Wd0[i];
        W[1][i] = Wd1[i];
    }
    if (threadIdx.x < 16) {
        B[0][threadIdx.x] = bd0[threadIdx.x];
        B[1][threadIdx.x] = bd1[threadIdx.x];
    }
    __syncthreads();
    int i = blockIdx.x * 256 + threadIdx.x;
    if (i >= 2 * ED) return;
    int sft = dflag[0];
    const int* ei;
    const int* et;
    int e;
    if (i < ED) { ei = pei; et = pet; e = i; }
    else        { ei = nei; et = net_; e = i - ED; }
    int s = ei[(size_t)e << sft];
    int d = ei[(size_t)(ED + e) << sft];
    int r = et[(size_t)e << sft];
    float zs[16], zd[16];
    const float4* sp = (const float4*)(z + ((size_t)s << 4));
    const float4* dp = (const float4*)(z + ((size_t)d << 4));
#pragma unroll
    for (int q = 0; q < 4; q++) {
        float4 a = sp[q];
        float4 b = dp[q];
        zs[4 * q] = a.x; zs[4 * q + 1] = a.y; zs[4 * q + 2] = a.z; zs[4 * q + 3] = a.w;
        zd[4 * q] = b.x; zd[4 * q + 1] = b.y; zd[4 * q + 2] = b.z; zd[4 * q + 3] = b.w;
    }
    const float* Wr = W[r];
    const float* Br = B[r];
    float acc = 0.0f;
#pragma unroll
    for (int j = 0; j < 16; j++) {
        float yj = Br[j];
#pragma unroll
        for (int k = 0; k < 16; k++) yj = fmaf(zs[k], Wr[k * 16 + j], yj);
        acc = fmaf(yj, zd[j], acc);
    }
    out[i] = acc;
}

// ---------------------------------------------------------------------------
extern "C" void kernel_launch(void* const* d_in, const int* in_sizes, int n_in,
                              void* d_out, int out_size, void* d_ws, size_t ws_size,
                              hipStream_t stream) {
    const float* x_paper = (const float*)d_in[0];
    const float* x_mesh  = (const float*)d_in[1];
    const int* tei  = (const int*)d_in[2];
    const int* tet  = (const int*)d_in[3];
    const int* pei  = (const int*)d_in[4];
    const int* pet  = (const int*)d_in[5];
    const int* nei  = (const int*)d_in[6];
    const int* net_ = (const int*)d_in[7];
    const float* Wp  = (const float*)d_in[8];
    const float* bp  = (const float*)d_in[9];
    const float* Wm  = (const float*)d_in[10];
    const float* bm  = (const float*)d_in[11];
    const float* Wd0 = (const float*)d_in[12];
    const float* bd0 = (const float*)d_in[13];
    const float* Wd1 = (const float*)d_in[14];
    const float* bd1 = (const float*)d_in[15];

    // Workspace carve-up (fp32/int32 elements) — ~62 MB total
    float* ws = (float*)d_ws;
    size_t o = 0;
    float* bufA = ws + o; o += (size_t)NN * 32;
    float* bufB = ws + o; o += (size_t)NN * 32;
    unsigned short* xbfA = (unsigned short*)(ws + o); o += (size_t)NN * 16;
    unsigned short* xbfB = (unsigned short*)(ws + o); o += (size_t)NN * 16;
    float* inv  = ws + o; o += (size_t)TWO_NN;
    int*   off  = (int*)(ws + o); o += (size_t)TWO_NN;
    int*   endo = (int*)(ws + o); o += (size_t)TWO_NN;
    int*   csr  = (int*)(ws + o); o += (size_t)NB_BKT * BKT_CAP; // padded
    int*   gcur = (int*)(ws + o); o += 256;
    int2*  pairs = (int2*)(ws + o); o += (size_t)2 * NB_BKT * BKT_CAP; // 17.3 MB
    float* Wbuf4 = ws + o; o += 4 * 3200;
    int*   dflag = (int*)(ws + o); o += 16;

    // 0. Init (gcur + dtype flag, merged)
    init_kernel<<<1, 256, 0, stream>>>(tei, gcur, dflag);

    // 1. Binned padded-bucket CSR build (once; edge structure layer-invariant)
    binA_kernel<<<N_TILES, 256, 0, stream>>>(tei, tet, dflag, gcur, pairs);
    histB_kernel<<<NB_BKT, 256, 0, stream>>>(gcur, pairs, off, endo, inv);
    placeB_kernel<<<NB_BKT, 256, 0, stream>>>(gcur, pairs, off, csr);

    // 2. Fused embed (paper+mesh) -> bufA fp32 + xbfA bf16
    embed2_kernel<<<(NN + 255) / 256, 256, 0, stream>>>(
        x_paper, x_mesh, Wp, bp, Wm, bm, bufA, xbfA);

    // 3. All layer weights in one launch
    prep_all_kernel<<<4, 256, 0, stream>>>(
        (const float*)d_in[16], (const float*)d_in[17], (const float*)d_in[18], (const float*)d_in[19],
        (const float*)d_in[20], (const float*)d_in[21], (const float*)d_in[22], (const float*)d_in[23],
        (const float*)d_in[24], (const float*)d_in[25], (const float*)d_in[26], (const float*)d_in[27],
        (const float*)d_in[28], (const float*)d_in[29], (const float*)d_in[30], (const float*)d_in[31],
        Wbuf4);

    // 4. Four fused RGCN layers (gather->LDS->combine), ping-pong buffers
    int blk16 = (NN + 63) / 64; // DIN=16: NPB=64
    int blk32 = (NN + 31) / 32; // DIN=32: NPB=32
    layer_kernel<16, 32, 1, 1><<<blk16, 256, 0, stream>>>(
        off, endo, csr, bufA, xbfA, inv, Wbuf4 + 0 * 3200, bufB, xbfB);
    layer_kernel<32, 32, 1, 1><<<blk32, 256, 0, stream>>>(
        off, endo, csr, bufB, xbfB, inv, Wbuf4 + 1 * 3200, bufA, xbfA);
    layer_kernel<32, 32, 1, 1><<<blk32, 256, 0, stream>>>(
        off, endo, csr, bufA, xbfA, inv, Wbuf4 + 2 * 3200, bufB, xbfB);
    layer_kernel<32, 16, 0, 0><<<blk32, 256, 0, stream>>>(
        off, endo, csr, bufB, xbfB, inv, Wbuf4 + 3 * 3200, bufA, xbfA /*unused*/);
    // z = bufA [NN,16]

    // 5. Fused decode (no prep; single z table)
    decode_fused_kernel<<<(2 * ED + 255) / 256, 256, 0, stream>>>(
        bufA, Wd0, bd0, Wd1, bd1, pei, pet, nei, net_, (float*)d_out, dflag);
}

// Round 14
// 392.309 us; speedup vs baseline: 3.7525x; 1.0206x over previous
//
#include <hip/hip_runtime.h>
#include <hip/hip_bf16.h>

// Problem constants (from reference)
constexpr int NN = 90000;   // total nodes
constexpr int NP = 60000;   // paper nodes
constexpr int NM = 30000;   // mesh nodes
constexpr int ET = 2000000; // train edges
constexpr int ED = 400000;  // decode edges (each of pos/neg)
constexpr int TWO_NN = 2 * NN;

// Binned CSR build parameters
constexpr int BKT_SH  = 10;                        // 1024 keys per bucket
constexpr int NB_BKT  = (TWO_NN + 1023) >> BKT_SH; // 176 buckets
constexpr int BKT_CAP = 12288;                     // mean 11366, +8.7 sigma
constexpr int TILE    = 2048;                      // edges per binning tile
constexpr int N_TILES = (ET + TILE - 1) / TILE;    // 977

__device__ __forceinline__ float bflo(unsigned int u) {
    union { unsigned int i; float f; } c;
    c.i = u << 16;
    return c.f;
}
__device__ __forceinline__ float bfhi(unsigned int u) {
    union { unsigned int i; float f; } c;
    c.i = u & 0xffff0000u;
    return c.f;
}
__device__ __forceinline__ unsigned short f2bf(float f) {
    union { float f; unsigned int i; } c;
    c.f = f;
    unsigned int x = c.i;
    return (unsigned short)((x + 0x7FFFu + ((x >> 16) & 1u)) >> 16);
}

// ---------------------------------------------------------------------------
// Init: gcur cursors + int32/int64 dtype flag (merged).
__global__ void init_kernel(const int* __restrict__ tei, int* __restrict__ gcur,
                            int* __restrict__ dflag) {
    int b = blockIdx.x * blockDim.x + threadIdx.x;
    if (b < NB_BKT) gcur[b] = b * BKT_CAP;
    if (b == 0) {
        int allzero = 1;
        for (int i = 0; i < 16; i++)
            if (tei[2 * i + 1] != 0) allzero = 0;
        dflag[0] = allzero; // 1 => int64 => index shift 1
    }
}

// ---------------------------------------------------------------------------
// Pass A: bin edges into per-bucket pair arrays with line-dense writes.
__global__ void __launch_bounds__(256) binA_kernel(
        const int* __restrict__ ei, const int* __restrict__ et,
        const int* __restrict__ dflag, int* __restrict__ gcur,
        int2* __restrict__ pairs) {
    __shared__ int hist[NB_BKT];
    __shared__ int excl[NB_BKT];
    __shared__ int cur[NB_BKT];
    __shared__ int gbase[NB_BKT];
    __shared__ int scn[256];
    __shared__ int2 tbuf[TILE];
    int t = threadIdx.x;
    int tile0 = blockIdx.x * TILE;
    int tcount = ET - tile0;
    if (tcount > TILE) tcount = TILE;
    for (int i = t; i < NB_BKT; i += 256) hist[i] = 0;
    __syncthreads();
    int sft = dflag[0];
    int myk[8], mys[8];
#pragma unroll
    for (int q = 0; q < 8; q++) {
        int li = q * 256 + t;
        myk[q] = -1;
        if (li < tcount) {
            int e = tile0 + li;
            int s = ei[(size_t)e << sft];
            int d = ei[(size_t)(ET + e) << sft];
            int r = et[(size_t)e << sft];
            int key = r * NN + d;
            myk[q] = key;
            mys[q] = s;
            atomicAdd(&hist[key >> BKT_SH], 1);
        }
    }
    __syncthreads();
    int v = (t < NB_BKT) ? hist[t] : 0;
    scn[t] = v;
    __syncthreads();
    for (int st = 1; st < 256; st <<= 1) {
        int u = (t >= st) ? scn[t - st] : 0;
        __syncthreads();
        scn[t] += u;
        __syncthreads();
    }
    if (t < NB_BKT) {
        excl[t] = scn[t] - v;
        cur[t] = scn[t] - v;
    }
    __syncthreads();
#pragma unroll
    for (int q = 0; q < 8; q++) {
        if (myk[q] >= 0) {
            int b = myk[q] >> BKT_SH;
            int p = atomicAdd(&cur[b], 1);
            tbuf[p] = make_int2(myk[q], mys[q]);
        }
    }
    __syncthreads();
    if (t < NB_BKT && hist[t] > 0) gbase[t] = atomicAdd(&gcur[t], hist[t]);
    __syncthreads();
    for (int i = t; i < tcount; i += 256) {
        int2 p = tbuf[i];
        int b = p.x >> BKT_SH;
        int gpos = gbase[b] + (i - excl[b]);
        int cap = (b + 1) * BKT_CAP - 1;
        pairs[gpos < cap ? gpos : cap] = p;
    }
}

// ---------------------------------------------------------------------------
// Pass B (merged hist+place): per-bucket block stages its pairs in LDS once,
// builds key histogram + block-local exclusive scan -> off/endo/inv, then
// places src values into the padded CSR. Pairs read once (was twice).
__global__ void __launch_bounds__(256) histplace_kernel(
        const int* __restrict__ gcur, const int2* __restrict__ pairs,
        int* __restrict__ off, int* __restrict__ endo, float* __restrict__ inv,
        int* __restrict__ csr) {
    __shared__ int2 pl[BKT_CAP];   // 96 KB
    __shared__ int kh[1024];
    __shared__ int scn[256];
    int b = blockIdx.x;
    int t = threadIdx.x;
    int beg = b * BKT_CAP;
    int n = gcur[b] - beg;
    for (int i = t; i < 1024; i += 256) kh[i] = 0;
    for (int i = t; i < n; i += 256) pl[i] = pairs[beg + i];
    __syncthreads();
    for (int i = t; i < n; i += 256) atomicAdd(&kh[pl[i].x & 1023], 1);
    __syncthreads();
    int v[4];
    int s = 0;
#pragma unroll
    for (int q = 0; q < 4; q++) {
        v[q] = kh[t * 4 + q];
        s += v[q];
    }
    scn[t] = s;
    __syncthreads();
    for (int st = 1; st < 256; st <<= 1) {
        int u = (t >= st) ? scn[t - st] : 0;
        __syncthreads();
        scn[t] += u;
        __syncthreads();
    }
    int run = beg + scn[t] - s;
    int kbase = b << BKT_SH;
    int kc[4];
#pragma unroll
    for (int q = 0; q < 4; q++) {
        int key = kbase + t * 4 + q;
        if (key < TWO_NN) {
            off[key] = run;
            endo[key] = run + v[q];
            inv[key] = 1.0f / (float)(v[q] > 1 ? v[q] : 1);
        }
        kc[q] = run;
        run += v[q];
    }
    __syncthreads();
    // reuse kh as per-key cursors
#pragma unroll
    for (int q = 0; q < 4; q++) kh[t * 4 + q] = kc[q];
    __syncthreads();
    for (int i = t; i < n; i += 256) {
        int2 p = pl[i];
        int pos = atomicAdd(&kh[p.x & 1023], 1);
        csr[pos] = p.y;
    }
}

// ---------------------------------------------------------------------------
// Fused input embed (paper+mesh): writes bf16 activations only.
__global__ void __launch_bounds__(256) embed2_kernel(
        const float* __restrict__ Xp, const float* __restrict__ Xm,
        const float* __restrict__ Wp, const float* __restrict__ bp,
        const float* __restrict__ Wm, const float* __restrict__ bm,
        unsigned short* __restrict__ outbf) {
    __shared__ float Wl[4096 + 32];
    for (int i = threadIdx.x; i < 2048; i += 256) {
        Wl[i] = Wp[i];
        Wl[2048 + i] = Wm[i];
    }
    if (threadIdx.x < 16) {
        Wl[4096 + threadIdx.x] = bp[threadIdx.x];
        Wl[4112 + threadIdx.x] = bm[threadIdx.x];
    }
    __syncthreads();
    int n = blockIdx.x * 256 + threadIdx.x;
    if (n >= NN) return;
    const float* X;
    const float* Ws;
    const float* Bs;
    if (n < NP) { X = Xp + (size_t)n * 128; Ws = Wl; Bs = Wl + 4096; }
    else        { X = Xm + (size_t)(n - NP) * 128; Ws = Wl + 2048; Bs = Wl + 4112; }
    float acc[16];
#pragma unroll
    for (int j = 0; j < 16; j++) acc[j] = Bs[j];
    const float4* row = (const float4*)X;
    for (int k4 = 0; k4 < 32; k4++) {
        float4 xv = row[k4];
        int k = k4 * 4;
#pragma unroll
        for (int j = 0; j < 16; j++) {
            float a = acc[j];
            a = fmaf(xv.x, Ws[(k + 0) * 16 + j], a);
            a = fmaf(xv.y, Ws[(k + 1) * 16 + j], a);
            a = fmaf(xv.z, Ws[(k + 2) * 16 + j], a);
            a = fmaf(xv.w, Ws[(k + 3) * 16 + j], a);
            acc[j] = a;
        }
    }
    ushort4* ob = (ushort4*)(outbf + (size_t)n * 16);
#pragma unroll
    for (int q = 0; q < 4; q++) {
        ushort4 ub;
        ub.x = f2bf(acc[4 * q]);     ub.y = f2bf(acc[4 * q + 1]);
        ub.z = f2bf(acc[4 * q + 2]); ub.w = f2bf(acc[4 * q + 3]);
        ob[q] = ub;
    }
}

// ---------------------------------------------------------------------------
// All 4 layers' weight prep in ONE launch: block l handles layer l.
// Wbuf4 layout per layer (stride 3200): [W0 | W1 | root | bias]
__global__ void prep_all_kernel(
        const float* __restrict__ ba0, const float* __restrict__ co0,
        const float* __restrict__ ro0, const float* __restrict__ bi0,
        const float* __restrict__ ba1, const float* __restrict__ co1,
        const float* __restrict__ ro1, const float* __restrict__ bi1,
        const float* __restrict__ ba2, const float* __restrict__ co2,
        const float* __restrict__ ro2, const float* __restrict__ bi2,
        const float* __restrict__ ba3, const float* __restrict__ co3,
        const float* __restrict__ ro3, const float* __restrict__ bi3,
        float* __restrict__ Wbuf4) {
    int l = blockIdx.x;
    const float* bases; const float* comp; const float* root; const float* bias;
    if (l == 0)      { bases = ba0; comp = co0; root = ro0; bias = bi0; }
    else if (l == 1) { bases = ba1; comp = co1; root = ro1; bias = bi1; }
    else if (l == 2) { bases = ba2; comp = co2; root = ro2; bias = bi2; }
    else             { bases = ba3; comp = co3; root = ro3; bias = bi3; }
    int din = (l == 0) ? 16 : 32;
    int dout = (l == 3) ? 16 : 32;
    int sz = din * dout;
    float* W = Wbuf4 + l * 3200;
    for (int i = threadIdx.x; i < sz; i += 256) {
        float b0 = bases[i];
        float b1 = bases[sz + i];
        float b2 = bases[2 * sz + i];
        float b3 = bases[3 * sz + i];
        for (int r = 0; r < 2; r++) {
            W[r * sz + i] = comp[r * 4 + 0] * b0 + comp[r * 4 + 1] * b1 +
                            comp[r * 4 + 2] * b2 + comp[r * 4 + 3] * b3;
        }
        W[2 * sz + i] = root[i];
    }
    if (threadIdx.x < dout) W[3 * sz + threadIdx.x] = bias[threadIdx.x];
}

// ---------------------------------------------------------------------------
// Fused RGCN layer, bf16-only activations. Phase 1: 16 B/lane bf16 gathers;
// own row staged from the SAME bf16 table (fp32 activation stream removed —
// R13 showed FETCH at the compulsory floor; only byte reduction helps).
// Phase 2: combine matmul from LDS. FP32OUT=1 (last layer) writes fp32 z;
// otherwise writes bf16 only.
template <int DIN, int DOUT, int RELU, int FP32OUT>
__global__ void __launch_bounds__(256) layer_kernel(
        const int* __restrict__ off, const int* __restrict__ endo,
        const int* __restrict__ csr,
        const unsigned short* __restrict__ xbf_in,
        const float* __restrict__ inv, const float* __restrict__ Wbuf,
        float* __restrict__ xout, unsigned short* __restrict__ xbf_out) {
    constexpr int SZ = DIN * DOUT;
    constexpr int QL = DIN / 8;       // gather lanes per (node, rel): 16 B each
    constexpr int TPN = 2 * QL;       // phase-1 threads per node
    constexpr int NPB = 256 / TPN;    // nodes per block
    constexpr int AGST = 2 * DIN + 4; // agg LDS row stride
    constexpr int XSST = DIN + 4;     // xs LDS row stride
    __shared__ float Wl[3 * SZ + DOUT];
    __shared__ float agg[NPB * AGST];
    __shared__ float xs[NPB * XSST];
    for (int i = threadIdx.x; i < 3 * SZ + DOUT; i += 256) Wl[i] = Wbuf[i];
    int t = threadIdx.x;
    int ln = t / TPN;
    int rl = t % TPN;
    int r = rl / QL;
    int lane = rl % QL;
    int d = blockIdx.x * NPB + ln;
    if (d < NN) {
        // stage own row from the bf16 table (QL threads x 16 B)
        if (r == 0) {
            uint4 u = *(const uint4*)(xbf_in + (size_t)d * DIN + lane * 8);
            float* xp = xs + ln * XSST + lane * 8;
            xp[0] = bflo(u.x); xp[1] = bfhi(u.x);
            xp[2] = bflo(u.y); xp[3] = bfhi(u.y);
            xp[4] = bflo(u.z); xp[5] = bfhi(u.z);
            xp[6] = bflo(u.w); xp[7] = bfhi(u.w);
        }
        int key = r * NN + d;
        int b = off[key];
        int e = endo[key];
        float a0[8] = {0, 0, 0, 0, 0, 0, 0, 0};
        float a1[8] = {0, 0, 0, 0, 0, 0, 0, 0};
        const unsigned short* hp = xbf_in + lane * 8;
        int k = b;
        for (; k + 1 < e; k += 2) {
            int s0 = csr[k];
            int s1 = csr[k + 1];
            uint4 u0 = *(const uint4*)(hp + (size_t)s0 * DIN);
            uint4 u1 = *(const uint4*)(hp + (size_t)s1 * DIN);
            a0[0] += bflo(u0.x); a0[1] += bfhi(u0.x);
            a0[2] += bflo(u0.y); a0[3] += bfhi(u0.y);
            a0[4] += bflo(u0.z); a0[5] += bfhi(u0.z);
            a0[6] += bflo(u0.w); a0[7] += bfhi(u0.w);
            a1[0] += bflo(u1.x); a1[1] += bfhi(u1.x);
            a1[2] += bflo(u1.y); a1[3] += bfhi(u1.y);
            a1[4] += bflo(u1.z); a1[5] += bfhi(u1.z);
            a1[6] += bflo(u1.w); a1[7] += bfhi(u1.w);
        }
        if (k < e) {
            uint4 u0 = *(const uint4*)(hp + (size_t)csr[k] * DIN);
            a0[0] += bflo(u0.x); a0[1] += bfhi(u0.x);
            a0[2] += bflo(u0.y); a0[3] += bfhi(u0.y);
            a0[4] += bflo(u0.z); a0[5] += bfhi(u0.z);
            a0[6] += bflo(u0.w); a0[7] += bfhi(u0.w);
        }
        float* ap = agg + ln * AGST + r * DIN + lane * 8;
        *(float4*)ap = make_float4(a0[0] + a1[0], a0[1] + a1[1],
                                   a0[2] + a1[2], a0[3] + a1[3]);
        *(float4*)(ap + 4) = make_float4(a0[4] + a1[4], a0[5] + a1[5],
                                         a0[6] + a1[6], a0[7] + a1[7]);
    }
    __syncthreads();
    constexpr int CPN = DOUT / 4;
    for (int tt = t; tt < NPB * CPN; tt += 256) {
        int ln2 = tt / CPN;
        int j0 = (tt % CPN) * 4;
        int d2 = blockIdx.x * NPB + ln2;
        if (d2 < NN) {
            float iv0 = inv[d2], iv1 = inv[NN + d2];
            float acc[4];
#pragma unroll
            for (int jj = 0; jj < 4; jj++) acc[jj] = Wl[3 * SZ + j0 + jj];
#pragma unroll
            for (int k = 0; k < DIN; k++) {
                float xv = xs[ln2 * XSST + k];
                float m0 = agg[ln2 * AGST + k] * iv0;
                float m1 = agg[ln2 * AGST + DIN + k] * iv1;
                const float* w0 = &Wl[k * DOUT + j0];
                const float* w1 = &Wl[SZ + k * DOUT + j0];
                const float* wr = &Wl[2 * SZ + k * DOUT + j0];
#pragma unroll
                for (int jj = 0; jj < 4; jj++) {
                    acc[jj] = fmaf(xv, wr[jj], acc[jj]);
                    acc[jj] = fmaf(m0, w0[jj], acc[jj]);
                    acc[jj] = fmaf(m1, w1[jj], acc[jj]);
                }
            }
            if (RELU) {
#pragma unroll
                for (int jj = 0; jj < 4; jj++) acc[jj] = fmaxf(acc[jj], 0.0f);
            }
            if (FP32OUT) {
                *(float4*)(xout + (size_t)d2 * DOUT + j0) =
                    make_float4(acc[0], acc[1], acc[2], acc[3]);
            } else {
                ushort4 ub;
                ub.x = f2bf(acc[0]); ub.y = f2bf(acc[1]);
                ub.z = f2bf(acc[2]); ub.w = f2bf(acc[3]);
                *(ushort4*)(xbf_out + (size_t)d2 * DOUT + j0) = ub;
            }
        }
    }
}

// ---------------------------------------------------------------------------
// Fused decode: out[i] = dot( z[s]@Wd_r + bd_r , z[d] ), z fp32 (exact).
__global__ void __launch_bounds__(256) decode_fused_kernel(
        const float* __restrict__ z,
        const float* __restrict__ Wd0, const float* __restrict__ bd0,
        const float* __restrict__ Wd1, const float* __restrict__ bd1,
        const int* __restrict__ pei, const int* __restrict__ pet,
        const int* __restrict__ nei, const int* __restrict__ net_,
        float* __restrict__ out, const int* __restrict__ dflag) {
    __shared__ float W[2][256];
    __shared__ float B[2][16];
    for (int i = threadIdx.x; i < 256; i += 256) {
        W[0][i] = Wd0[i];
        W[1][i] = Wd1[i];
    }
    if (threadIdx.x < 16) {
        B[0][threadIdx.x] = bd0[threadIdx.x];
        B[1][threadIdx.x] = bd1[threadIdx.x];
    }
    __syncthreads();
    int i = blockIdx.x * 256 + threadIdx.x;
    if (i >= 2 * ED) return;
    int sft = dflag[0];
    const int* ei;
    const int* et;
    int e;
    if (i < ED) { ei = pei; et = pet; e = i; }
    else        { ei = nei; et = net_; e = i - ED; }
    int s = ei[(size_t)e << sft];
    int d = ei[(size_t)(ED + e) << sft];
    int r = et[(size_t)e << sft];
    float zs[16], zd[16];
    const float4* sp = (const float4*)(z + ((size_t)s << 4));
    const float4* dp = (const float4*)(z + ((size_t)d << 4));
#pragma unroll
    for (int q = 0; q < 4; q++) {
        float4 a = sp[q];
        float4 b = dp[q];
        zs[4 * q] = a.x; zs[4 * q + 1] = a.y; zs[4 * q + 2] = a.z; zs[4 * q + 3] = a.w;
        zd[4 * q] = b.x; zd[4 * q + 1] = b.y; zd[4 * q + 2] = b.z; zd[4 * q + 3] = b.w;
    }
    const float* Wr = W[r];
    const float* Br = B[r];
    float acc = 0.0f;
#pragma unroll
    for (int j = 0; j < 16; j++) {
        float yj = Br[j];
#pragma unroll
        for (int k = 0; k < 16; k++) yj = fmaf(zs[k], Wr[k * 16 + j], yj);
        acc = fmaf(yj, zd[j], acc);
    }
    out[i] = acc;
}

// ---------------------------------------------------------------------------
extern "C" void kernel_launch(void* const* d_in, const int* in_sizes, int n_in,
                              void* d_out, int out_size, void* d_ws, size_t ws_size,
                              hipStream_t stream) {
    const float* x_paper = (const float*)d_in[0];
    const float* x_mesh  = (const float*)d_in[1];
    const int* tei  = (const int*)d_in[2];
    const int* tet  = (const int*)d_in[3];
    const int* pei  = (const int*)d_in[4];
    const int* pet  = (const int*)d_in[5];
    const int* nei  = (const int*)d_in[6];
    const int* net_ = (const int*)d_in[7];
    const float* Wp  = (const float*)d_in[8];
    const float* bp  = (const float*)d_in[9];
    const float* Wm  = (const float*)d_in[10];
    const float* bm  = (const float*)d_in[11];
    const float* Wd0 = (const float*)d_in[12];
    const float* bd0 = (const float*)d_in[13];
    const float* Wd1 = (const float*)d_in[14];
    const float* bd1 = (const float*)d_in[15];

    // Workspace carve-up (fp32/int32 elements) — ~50 MB total
    float* ws = (float*)d_ws;
    size_t o = 0;
    float* zbuf = ws + o; o += (size_t)NN * 16; // fp32 z (layer-4 out)
    unsigned short* xbfA = (unsigned short*)(ws + o); o += (size_t)NN * 16;
    unsigned short* xbfB = (unsigned short*)(ws + o); o += (size_t)NN * 16;
    float* inv  = ws + o; o += (size_t)TWO_NN;
    int*   off  = (int*)(ws + o); o += (size_t)TWO_NN;
    int*   endo = (int*)(ws + o); o += (size_t)TWO_NN;
    int*   csr  = (int*)(ws + o); o += (size_t)NB_BKT * BKT_CAP; // padded
    int*   gcur = (int*)(ws + o); o += 256;
    int2*  pairs = (int2*)(ws + o); o += (size_t)2 * NB_BKT * BKT_CAP; // 17.3 MB
    float* Wbuf4 = ws + o; o += 4 * 3200;
    int*   dflag = (int*)(ws + o); o += 16;

    // 0. Init (gcur + dtype flag)
    init_kernel<<<1, 256, 0, stream>>>(tei, gcur, dflag);

    // 1. Binned padded-bucket CSR build (once)
    binA_kernel<<<N_TILES, 256, 0, stream>>>(tei, tet, dflag, gcur, pairs);
    histplace_kernel<<<NB_BKT, 256, 0, stream>>>(gcur, pairs, off, endo, inv, csr);

    // 2. Fused embed -> xbfA (bf16 only)
    embed2_kernel<<<(NN + 255) / 256, 256, 0, stream>>>(
        x_paper, x_mesh, Wp, bp, Wm, bm, xbfA);

    // 3. All layer weights in one launch
    prep_all_kernel<<<4, 256, 0, stream>>>(
        (const float*)d_in[16], (const float*)d_in[17], (const float*)d_in[18], (const float*)d_in[19],
        (const float*)d_in[20], (const float*)d_in[21], (const float*)d_in[22], (const float*)d_in[23],
        (const float*)d_in[24], (const float*)d_in[25], (const float*)d_in[26], (const float*)d_in[27],
        (const float*)d_in[28], (const float*)d_in[29], (const float*)d_in[30], (const float*)d_in[31],
        Wbuf4);

    // 4. Four fused RGCN layers, bf16 activations (last writes fp32 z)
    int blk16 = (NN + 63) / 64; // DIN=16: NPB=64
    int blk32 = (NN + 31) / 32; // DIN=32: NPB=32
    layer_kernel<16, 32, 1, 0><<<blk16, 256, 0, stream>>>(
        off, endo, csr, xbfA, inv, Wbuf4 + 0 * 3200, nullptr, xbfB);
    layer_kernel<32, 32, 1, 0><<<blk32, 256, 0, stream>>>(
        off, endo, csr, xbfB, inv, Wbuf4 + 1 * 3200, nullptr, xbfA);
    layer_kernel<32, 32, 1, 0><<<blk32, 256, 0, stream>>>(
        off, endo, csr, xbfA, inv, Wbuf4 + 2 * 3200, nullptr, xbfB);
    layer_kernel<32, 16, 0, 1><<<blk32, 256, 0, stream>>>(
        off, endo, csr, xbfB, inv, Wbuf4 + 3 * 3200, zbuf, nullptr);

    // 5. Fused decode (fp32 z table)
    decode_fused_kernel<<<(2 * ED + 255) / 256, 256, 0, stream>>>(
        zbuf, Wd0, bd0, Wd1, bd1, pei, pet, nei, net_, (float*)d_out, dflag);
}

// Round 15
// 381.245 us; speedup vs baseline: 3.8614x; 1.0290x over previous
//
#include <hip/hip_runtime.h>
#include <hip/hip_bf16.h>

// Problem constants (from reference)
constexpr int NN = 90000;   // total nodes
constexpr int NP = 60000;   // paper nodes
constexpr int NM = 30000;   // mesh nodes
constexpr int ET = 2000000; // train edges
constexpr int ED = 400000;  // decode edges (each of pos/neg)
constexpr int TWO_NN = 2 * NN;

// Binned CSR build parameters
constexpr int BKT_SH  = 10;                        // 1024 keys per bucket
constexpr int NB_BKT  = (TWO_NN + 1023) >> BKT_SH; // 176 buckets
constexpr int BKT_CAP = 12288;                     // mean 11366, +8.7 sigma
constexpr int TILE    = 2048;                      // edges per binning tile
constexpr int N_TILES = (ET + TILE - 1) / TILE;    // 977

__device__ __forceinline__ float bflo(unsigned int u) {
    union { unsigned int i; float f; } c;
    c.i = u << 16;
    return c.f;
}
__device__ __forceinline__ float bfhi(unsigned int u) {
    union { unsigned int i; float f; } c;
    c.i = u & 0xffff0000u;
    return c.f;
}
__device__ __forceinline__ unsigned short f2bf(float f) {
    union { float f; unsigned int i; } c;
    c.f = f;
    unsigned int x = c.i;
    return (unsigned short)((x + 0x7FFFu + ((x >> 16) & 1u)) >> 16);
}

// ---------------------------------------------------------------------------
// Init: gcur cursors + int32/int64 dtype flag (merged).
__global__ void init_kernel(const int* __restrict__ tei, int* __restrict__ gcur,
                            int* __restrict__ dflag) {
    int b = blockIdx.x * blockDim.x + threadIdx.x;
    if (b < NB_BKT) gcur[b] = b * BKT_CAP;
    if (b == 0) {
        int allzero = 1;
        for (int i = 0; i < 16; i++)
            if (tei[2 * i + 1] != 0) allzero = 0;
        dflag[0] = allzero; // 1 => int64 => index shift 1
    }
}

// ---------------------------------------------------------------------------
// Pass A: bin edges into per-bucket pair arrays with line-dense writes.
__global__ void __launch_bounds__(256) binA_kernel(
        const int* __restrict__ ei, const int* __restrict__ et,
        const int* __restrict__ dflag, int* __restrict__ gcur,
        int2* __restrict__ pairs) {
    __shared__ int hist[NB_BKT];
    __shared__ int excl[NB_BKT];
    __shared__ int cur[NB_BKT];
    __shared__ int gbase[NB_BKT];
    __shared__ int scn[256];
    __shared__ int2 tbuf[TILE];
    int t = threadIdx.x;
    int tile0 = blockIdx.x * TILE;
    int tcount = ET - tile0;
    if (tcount > TILE) tcount = TILE;
    for (int i = t; i < NB_BKT; i += 256) hist[i] = 0;
    __syncthreads();
    int sft = dflag[0];
    int myk[8], mys[8];
#pragma unroll
    for (int q = 0; q < 8; q++) {
        int li = q * 256 + t;
        myk[q] = -1;
        if (li < tcount) {
            int e = tile0 + li;
            int s = ei[(size_t)e << sft];
            int d = ei[(size_t)(ET + e) << sft];
            int r = et[(size_t)e << sft];
            int key = r * NN + d;
            myk[q] = key;
            mys[q] = s;
            atomicAdd(&hist[key >> BKT_SH], 1);
        }
    }
    __syncthreads();
    int v = (t < NB_BKT) ? hist[t] : 0;
    scn[t] = v;
    __syncthreads();
    for (int st = 1; st < 256; st <<= 1) {
        int u = (t >= st) ? scn[t - st] : 0;
        __syncthreads();
        scn[t] += u;
        __syncthreads();
    }
    if (t < NB_BKT) {
        excl[t] = scn[t] - v;
        cur[t] = scn[t] - v;
    }
    __syncthreads();
#pragma unroll
    for (int q = 0; q < 8; q++) {
        if (myk[q] >= 0) {
            int b = myk[q] >> BKT_SH;
            int p = atomicAdd(&cur[b], 1);
            tbuf[p] = make_int2(myk[q], mys[q]);
        }
    }
    __syncthreads();
    if (t < NB_BKT && hist[t] > 0) gbase[t] = atomicAdd(&gcur[t], hist[t]);
    __syncthreads();
    for (int i = t; i < tcount; i += 256) {
        int2 p = tbuf[i];
        int b = p.x >> BKT_SH;
        int gpos = gbase[b] + (i - excl[b]);
        int cap = (b + 1) * BKT_CAP - 1;
        pairs[gpos < cap ? gpos : cap] = p;
    }
}

// ---------------------------------------------------------------------------
// Pass B (merged hist+place), low-LDS version: pairs read twice from global
// (bucket region ~91 KB stays L2-hot between passes). R14's 96 KB LDS staging
// capped occupancy at 1 block/CU with only 176 blocks -> latency-exposed.
__global__ void __launch_bounds__(256) histplace_kernel(
        const int* __restrict__ gcur, const int2* __restrict__ pairs,
        int* __restrict__ off, int* __restrict__ endo, float* __restrict__ inv,
        int* __restrict__ csr) {
    __shared__ int kh[1024];
    __shared__ int scn[256];
    int b = blockIdx.x;
    int t = threadIdx.x;
    int beg = b * BKT_CAP, end = gcur[b];
    for (int i = t; i < 1024; i += 256) kh[i] = 0;
    __syncthreads();
    for (int i = beg + t; i < end; i += 256)
        atomicAdd(&kh[pairs[i].x & 1023], 1);
    __syncthreads();
    int v[4];
    int s = 0;
#pragma unroll
    for (int q = 0; q < 4; q++) {
        v[q] = kh[t * 4 + q];
        s += v[q];
    }
    scn[t] = s;
    __syncthreads();
    for (int st = 1; st < 256; st <<= 1) {
        int u = (t >= st) ? scn[t - st] : 0;
        __syncthreads();
        scn[t] += u;
        __syncthreads();
    }
    int run = beg + scn[t] - s;
    int kbase = b << BKT_SH;
    int kc[4];
#pragma unroll
    for (int q = 0; q < 4; q++) {
        int key = kbase + t * 4 + q;
        if (key < TWO_NN) {
            off[key] = run;
            endo[key] = run + v[q];
            inv[key] = 1.0f / (float)(v[q] > 1 ? v[q] : 1);
        }
        kc[q] = run;
        run += v[q];
    }
    __syncthreads();
#pragma unroll
    for (int q = 0; q < 4; q++) kh[t * 4 + q] = kc[q];
    __syncthreads();
    for (int i = beg + t; i < end; i += 256) {
        int2 p = pairs[i];
        int pos = atomicAdd(&kh[p.x & 1023], 1);
        csr[pos] = p.y;
    }
}

// ---------------------------------------------------------------------------
// Fused input embed (paper+mesh): writes bf16 activations only.
__global__ void __launch_bounds__(256) embed2_kernel(
        const float* __restrict__ Xp, const float* __restrict__ Xm,
        const float* __restrict__ Wp, const float* __restrict__ bp,
        const float* __restrict__ Wm, const float* __restrict__ bm,
        unsigned short* __restrict__ outbf) {
    __shared__ float Wl[4096 + 32];
    for (int i = threadIdx.x; i < 2048; i += 256) {
        Wl[i] = Wp[i];
        Wl[2048 + i] = Wm[i];
    }
    if (threadIdx.x < 16) {
        Wl[4096 + threadIdx.x] = bp[threadIdx.x];
        Wl[4112 + threadIdx.x] = bm[threadIdx.x];
    }
    __syncthreads();
    int n = blockIdx.x * 256 + threadIdx.x;
    if (n >= NN) return;
    const float* X;
    const float* Ws;
    const float* Bs;
    if (n < NP) { X = Xp + (size_t)n * 128; Ws = Wl; Bs = Wl + 4096; }
    else        { X = Xm + (size_t)(n - NP) * 128; Ws = Wl + 2048; Bs = Wl + 4112; }
    float acc[16];
#pragma unroll
    for (int j = 0; j < 16; j++) acc[j] = Bs[j];
    const float4* row = (const float4*)X;
    for (int k4 = 0; k4 < 32; k4++) {
        float4 xv = row[k4];
        int k = k4 * 4;
#pragma unroll
        for (int j = 0; j < 16; j++) {
            float a = acc[j];
            a = fmaf(xv.x, Ws[(k + 0) * 16 + j], a);
            a = fmaf(xv.y, Ws[(k + 1) * 16 + j], a);
            a = fmaf(xv.z, Ws[(k + 2) * 16 + j], a);
            a = fmaf(xv.w, Ws[(k + 3) * 16 + j], a);
            acc[j] = a;
        }
    }
    ushort4* ob = (ushort4*)(outbf + (size_t)n * 16);
#pragma unroll
    for (int q = 0; q < 4; q++) {
        ushort4 ub;
        ub.x = f2bf(acc[4 * q]);     ub.y = f2bf(acc[4 * q + 1]);
        ub.z = f2bf(acc[4 * q + 2]); ub.w = f2bf(acc[4 * q + 3]);
        ob[q] = ub;
    }
}

// ---------------------------------------------------------------------------
// All 4 layers' weight prep in ONE launch: block l handles layer l.
// Wbuf4 layout per layer (stride 3200): [W0 | W1 | root | bias]
__global__ void prep_all_kernel(
        const float* __restrict__ ba0, const float* __restrict__ co0,
        const float* __restrict__ ro0, const float* __restrict__ bi0,
        const float* __restrict__ ba1, const float* __restrict__ co1,
        const float* __restrict__ ro1, const float* __restrict__ bi1,
        const float* __restrict__ ba2, const float* __restrict__ co2,
        const float* __restrict__ ro2, const float* __restrict__ bi2,
        const float* __restrict__ ba3, const float* __restrict__ co3,
        const float* __restrict__ ro3, const float* __restrict__ bi3,
        float* __restrict__ Wbuf4) {
    int l = blockIdx.x;
    const float* bases; const float* comp; const float* root; const float* bias;
    if (l == 0)      { bases = ba0; comp = co0; root = ro0; bias = bi0; }
    else if (l == 1) { bases = ba1; comp = co1; root = ro1; bias = bi1; }
    else if (l == 2) { bases = ba2; comp = co2; root = ro2; bias = bi2; }
    else             { bases = ba3; comp = co3; root = ro3; bias = bi3; }
    int din = (l == 0) ? 16 : 32;
    int dout = (l == 3) ? 16 : 32;
    int sz = din * dout;
    float* W = Wbuf4 + l * 3200;
    for (int i = threadIdx.x; i < sz; i += 256) {
        float b0 = bases[i];
        float b1 = bases[sz + i];
        float b2 = bases[2 * sz + i];
        float b3 = bases[3 * sz + i];
        for (int r = 0; r < 2; r++) {
            W[r * sz + i] = comp[r * 4 + 0] * b0 + comp[r * 4 + 1] * b1 +
                            comp[r * 4 + 2] * b2 + comp[r * 4 + 3] * b3;
        }
        W[2 * sz + i] = root[i];
    }
    if (threadIdx.x < dout) W[3 * sz + threadIdx.x] = bias[threadIdx.x];
}

// ---------------------------------------------------------------------------
// Fused RGCN layer, bf16-only activations (R13/R14: FETCH at compulsory floor;
// layer is bound by random-line miss throughput). Phase 1: 16 B/lane bf16
// gathers; Phase 2: combine matmul from LDS; bf16 out.
template <int DIN, int DOUT, int RELU>
__global__ void __launch_bounds__(256) layer_kernel(
        const int* __restrict__ off, const int* __restrict__ endo,
        const int* __restrict__ csr,
        const unsigned short* __restrict__ xbf_in,
        const float* __restrict__ inv, const float* __restrict__ Wbuf,
        unsigned short* __restrict__ xbf_out) {
    constexpr int SZ = DIN * DOUT;
    constexpr int QL = DIN / 8;       // gather lanes per (node, rel): 16 B each
    constexpr int TPN = 2 * QL;       // phase-1 threads per node
    constexpr int NPB = 256 / TPN;    // nodes per block
    constexpr int AGST = 2 * DIN + 4; // agg LDS row stride
    constexpr int XSST = DIN + 4;     // xs LDS row stride
    __shared__ float Wl[3 * SZ + DOUT];
    __shared__ float agg[NPB * AGST];
    __shared__ float xs[NPB * XSST];
    for (int i = threadIdx.x; i < 3 * SZ + DOUT; i += 256) Wl[i] = Wbuf[i];
    int t = threadIdx.x;
    int ln = t / TPN;
    int rl = t % TPN;
    int r = rl / QL;
    int lane = rl % QL;
    int d = blockIdx.x * NPB + ln;
    if (d < NN) {
        if (r == 0) {
            uint4 u = *(const uint4*)(xbf_in + (size_t)d * DIN + lane * 8);
            float* xp = xs + ln * XSST + lane * 8;
            xp[0] = bflo(u.x); xp[1] = bfhi(u.x);
            xp[2] = bflo(u.y); xp[3] = bfhi(u.y);
            xp[4] = bflo(u.z); xp[5] = bfhi(u.z);
            xp[6] = bflo(u.w); xp[7] = bfhi(u.w);
        }
        int key = r * NN + d;
        int b = off[key];
        int e = endo[key];
        float a0[8] = {0, 0, 0, 0, 0, 0, 0, 0};
        float a1[8] = {0, 0, 0, 0, 0, 0, 0, 0};
        const unsigned short* hp = xbf_in + lane * 8;
        int k = b;
        for (; k + 1 < e; k += 2) {
            int s0 = csr[k];
            int s1 = csr[k + 1];
            uint4 u0 = *(const uint4*)(hp + (size_t)s0 * DIN);
            uint4 u1 = *(const uint4*)(hp + (size_t)s1 * DIN);
            a0[0] += bflo(u0.x); a0[1] += bfhi(u0.x);
            a0[2] += bflo(u0.y); a0[3] += bfhi(u0.y);
            a0[4] += bflo(u0.z); a0[5] += bfhi(u0.z);
            a0[6] += bflo(u0.w); a0[7] += bfhi(u0.w);
            a1[0] += bflo(u1.x); a1[1] += bfhi(u1.x);
            a1[2] += bflo(u1.y); a1[3] += bfhi(u1.y);
            a1[4] += bflo(u1.z); a1[5] += bfhi(u1.z);
            a1[6] += bflo(u1.w); a1[7] += bfhi(u1.w);
        }
        if (k < e) {
            uint4 u0 = *(const uint4*)(hp + (size_t)csr[k] * DIN);
            a0[0] += bflo(u0.x); a0[1] += bfhi(u0.x);
            a0[2] += bflo(u0.y); a0[3] += bfhi(u0.y);
            a0[4] += bflo(u0.z); a0[5] += bfhi(u0.z);
            a0[6] += bflo(u0.w); a0[7] += bfhi(u0.w);
        }
        float* ap = agg + ln * AGST + r * DIN + lane * 8;
        *(float4*)ap = make_float4(a0[0] + a1[0], a0[1] + a1[1],
                                   a0[2] + a1[2], a0[3] + a1[3]);
        *(float4*)(ap + 4) = make_float4(a0[4] + a1[4], a0[5] + a1[5],
                                         a0[6] + a1[6], a0[7] + a1[7]);
    }
    __syncthreads();
    constexpr int CPN = DOUT / 4;
    for (int tt = t; tt < NPB * CPN; tt += 256) {
        int ln2 = tt / CPN;
        int j0 = (tt % CPN) * 4;
        int d2 = blockIdx.x * NPB + ln2;
        if (d2 < NN) {
            float iv0 = inv[d2], iv1 = inv[NN + d2];
            float acc[4];
#pragma unroll
            for (int jj = 0; jj < 4; jj++) acc[jj] = Wl[3 * SZ + j0 + jj];
#pragma unroll
            for (int k = 0; k < DIN; k++) {
                float xv = xs[ln2 * XSST + k];
                float m0 = agg[ln2 * AGST + k] * iv0;
                float m1 = agg[ln2 * AGST + DIN + k] * iv1;
                const float* w0 = &Wl[k * DOUT + j0];
                const float* w1 = &Wl[SZ + k * DOUT + j0];
                const float* wr = &Wl[2 * SZ + k * DOUT + j0];
#pragma unroll
                for (int jj = 0; jj < 4; jj++) {
                    acc[jj] = fmaf(xv, wr[jj], acc[jj]);
                    acc[jj] = fmaf(m0, w0[jj], acc[jj]);
                    acc[jj] = fmaf(m1, w1[jj], acc[jj]);
                }
            }
            if (RELU) {
#pragma unroll
                for (int jj = 0; jj < 4; jj++) acc[jj] = fmaxf(acc[jj], 0.0f);
            }
            ushort4 ub;
            ub.x = f2bf(acc[0]); ub.y = f2bf(acc[1]);
            ub.z = f2bf(acc[2]); ub.w = f2bf(acc[3]);
            *(ushort4*)(xbf_out + (size_t)d2 * DOUT + j0) = ub;
        }
    }
}

// ---------------------------------------------------------------------------
// Fused decode on bf16 z: out[i] = dot( z[s]@Wd_r + bd_r , z[d] ).
// bf16 z table = 2.88 MB -> fits per-XCD L2 (fp32 5.76 MB did not; R14 decode
// was at the random-miss ceiling). Accumulation stays fp32.
__global__ void __launch_bounds__(256) decode_fused_kernel(
        const unsigned short* __restrict__ zbf,
        const float* __restrict__ Wd0, const float* __restrict__ bd0,
        const float* __restrict__ Wd1, const float* __restrict__ bd1,
        const int* __restrict__ pei, const int* __restrict__ pet,
        const int* __restrict__ nei, const int* __restrict__ net_,
        float* __restrict__ out, const int* __restrict__ dflag) {
    __shared__ float W[2][256];
    __shared__ float B[2][16];
    for (int i = threadIdx.x; i < 256; i += 256) {
        W[0][i] = Wd0[i];
        W[1][i] = Wd1[i];
    }
    if (threadIdx.x < 16) {
        B[0][threadIdx.x] = bd0[threadIdx.x];
        B[1][threadIdx.x] = bd1[threadIdx.x];
    }
    __syncthreads();
    int i = blockIdx.x * 256 + threadIdx.x;
    if (i >= 2 * ED) return;
    int sft = dflag[0];
    const int* ei;
    const int* et;
    int e;
    if (i < ED) { ei = pei; et = pet; e = i; }
    else        { ei = nei; et = net_; e = i - ED; }
    int s = ei[(size_t)e << sft];
    int d = ei[(size_t)(ED + e) << sft];
    int r = et[(size_t)e << sft];
    float zs[16], zd[16];
    const uint4* sp = (const uint4*)(zbf + ((size_t)s << 4)); // 32 B = 2 uint4
    const uint4* dp = (const uint4*)(zbf + ((size_t)d << 4));
#pragma unroll
    for (int h = 0; h < 2; h++) {
        uint4 us = sp[h];
        uint4 ud = dp[h];
        int o8 = h * 8;
        zs[o8 + 0] = bflo(us.x); zs[o8 + 1] = bfhi(us.x);
        zs[o8 + 2] = bflo(us.y); zs[o8 + 3] = bfhi(us.y);
        zs[o8 + 4] = bflo(us.z); zs[o8 + 5] = bfhi(us.z);
        zs[o8 + 6] = bflo(us.w); zs[o8 + 7] = bfhi(us.w);
        zd[o8 + 0] = bflo(ud.x); zd[o8 + 1] = bfhi(ud.x);
        zd[o8 + 2] = bflo(ud.y); zd[o8 + 3] = bfhi(ud.y);
        zd[o8 + 4] = bflo(ud.z); zd[o8 + 5] = bfhi(ud.z);
        zd[o8 + 6] = bflo(ud.w); zd[o8 + 7] = bfhi(ud.w);
    }
    const float* Wr = W[r];
    const float* Br = B[r];
    float acc = 0.0f;
#pragma unroll
    for (int j = 0; j < 16; j++) {
        float yj = Br[j];
#pragma unroll
        for (int k = 0; k < 16; k++) yj = fmaf(zs[k], Wr[k * 16 + j], yj);
        acc = fmaf(yj, zd[j], acc);
    }
    out[i] = acc;
}

// ---------------------------------------------------------------------------
extern "C" void kernel_launch(void* const* d_in, const int* in_sizes, int n_in,
                              void* d_out, int out_size, void* d_ws, size_t ws_size,
                              hipStream_t stream) {
    const float* x_paper = (const float*)d_in[0];
    const float* x_mesh  = (const float*)d_in[1];
    const int* tei  = (const int*)d_in[2];
    const int* tet  = (const int*)d_in[3];
    const int* pei  = (const int*)d_in[4];
    const int* pet  = (const int*)d_in[5];
    const int* nei  = (const int*)d_in[6];
    const int* net_ = (const int*)d_in[7];
    const float* Wp  = (const float*)d_in[8];
    const float* bp  = (const float*)d_in[9];
    const float* Wm  = (const float*)d_in[10];
    const float* bm  = (const float*)d_in[11];
    const float* Wd0 = (const float*)d_in[12];
    const float* bd0 = (const float*)d_in[13];
    const float* Wd1 = (const float*)d_in[14];
    const float* bd1 = (const float*)d_in[15];

    // Workspace carve-up (fp32/int32 elements) — ~45 MB total
    float* ws = (float*)d_ws;
    size_t o = 0;
    unsigned short* xbfA = (unsigned short*)(ws + o); o += (size_t)NN * 16;
    unsigned short* xbfB = (unsigned short*)(ws + o); o += (size_t)NN * 16;
    float* inv  = ws + o; o += (size_t)TWO_NN;
    int*   off  = (int*)(ws + o); o += (size_t)TWO_NN;
    int*   endo = (int*)(ws + o); o += (size_t)TWO_NN;
    int*   csr  = (int*)(ws + o); o += (size_t)NB_BKT * BKT_CAP; // padded
    int*   gcur = (int*)(ws + o); o += 256;
    int2*  pairs = (int2*)(ws + o); o += (size_t)2 * NB_BKT * BKT_CAP; // 17.3 MB
    float* Wbuf4 = ws + o; o += 4 * 3200;
    int*   dflag = (int*)(ws + o); o += 16;

    // 0. Init (gcur + dtype flag)
    init_kernel<<<1, 256, 0, stream>>>(tei, gcur, dflag);

    // 1. Binned padded-bucket CSR build (once)
    binA_kernel<<<N_TILES, 256, 0, stream>>>(tei, tet, dflag, gcur, pairs);
    histplace_kernel<<<NB_BKT, 256, 0, stream>>>(gcur, pairs, off, endo, inv, csr);

    // 2. Fused embed -> xbfA (bf16 only)
    embed2_kernel<<<(NN + 255) / 256, 256, 0, stream>>>(
        x_paper, x_mesh, Wp, bp, Wm, bm, xbfA);

    // 3. All layer weights in one launch
    prep_all_kernel<<<4, 256, 0, stream>>>(
        (const float*)d_in[16], (const float*)d_in[17], (const float*)d_in[18], (const float*)d_in[19],
        (const float*)d_in[20], (const float*)d_in[21], (const float*)d_in[22], (const float*)d_in[23],
        (const float*)d_in[24], (const float*)d_in[25], (const float*)d_in[26], (const float*)d_in[27],
        (const float*)d_in[28], (const float*)d_in[29], (const float*)d_in[30], (const float*)d_in[31],
        Wbuf4);

    // 4. Four fused RGCN layers, bf16 activations throughout
    int blk16 = (NN + 63) / 64; // DIN=16: NPB=64
    int blk32 = (NN + 31) / 32; // DIN=32: NPB=32
    layer_kernel<16, 32, 1><<<blk16, 256, 0, stream>>>(
        off, endo, csr, xbfA, inv, Wbuf4 + 0 * 3200, xbfB);
    layer_kernel<32, 32, 1><<<blk32, 256, 0, stream>>>(
        off, endo, csr, xbfB, inv, Wbuf4 + 1 * 3200, xbfA);
    layer_kernel<32, 32, 1><<<blk32, 256, 0, stream>>>(
        off, endo, csr, xbfA, inv, Wbuf4 + 2 * 3200, xbfB);
    layer_kernel<32, 16, 0><<<blk32, 256, 0, stream>>>(
        off, endo, csr, xbfB, inv, Wbuf4 + 3 * 3200, xbfA);
    // z (bf16) = xbfA [NN,16]

    // 5. Fused decode on bf16 z
    decode_fused_kernel<<<(2 * ED + 255) / 256, 256, 0, stream>>>(
        xbfA, Wd0, bd0, Wd1, bd1, pei, pet, nei, net_, (float*)d_out, dflag);
}

// Round 16
// 369.074 us; speedup vs baseline: 3.9888x; 1.0330x over previous
//
#include <hip/hip_runtime.h>
#include <hip/hip_bf16.h>

// Problem constants (from reference)
constexpr int NN = 90000;   // total nodes
constexpr int NP = 60000;   // paper nodes
constexpr int NM = 30000;   // mesh nodes
constexpr int ET = 2000000; // train edges
constexpr int ED = 400000;  // decode edges (each of pos/neg)
constexpr int TWO_NN = 2 * NN;

// Binned CSR build parameters (R16: 512-key buckets for 2x block parallelism)
constexpr int BKT_SH  = 9;                           // 512 keys per bucket
constexpr int NB_BKT  = (TWO_NN + 511) >> BKT_SH;    // 352 buckets
constexpr int BKT_CAP = 6400;                        // mean 5683, +9.5 sigma
constexpr int TILE    = 2048;                        // edges per binning tile
constexpr int N_TILES = (ET + TILE - 1) / TILE;      // 977

__device__ __forceinline__ float bflo(unsigned int u) {
    union { unsigned int i; float f; } c;
    c.i = u << 16;
    return c.f;
}
__device__ __forceinline__ float bfhi(unsigned int u) {
    union { unsigned int i; float f; } c;
    c.i = u & 0xffff0000u;
    return c.f;
}
__device__ __forceinline__ unsigned short f2bf(float f) {
    union { float f; unsigned int i; } c;
    c.f = f;
    unsigned int x = c.i;
    return (unsigned short)((x + 0x7FFFu + ((x >> 16) & 1u)) >> 16);
}

// ---------------------------------------------------------------------------
// Init: gcur cursors + int32/int64 dtype flag (merged).
__global__ void init_kernel(const int* __restrict__ tei, int* __restrict__ gcur,
                            int* __restrict__ dflag) {
    int b = blockIdx.x * blockDim.x + threadIdx.x;
    if (b < NB_BKT) gcur[b] = b * BKT_CAP;
    if (b == 0) {
        int allzero = 1;
        for (int i = 0; i < 16; i++)
            if (tei[2 * i + 1] != 0) allzero = 0;
        dflag[0] = allzero; // 1 => int64 => index shift 1
    }
}

// ---------------------------------------------------------------------------
// Pass A: bin edges into per-bucket pair arrays with line-dense writes.
// R16: per-wave privatized histograms + placement cursors (histw[4][NB]) —
// LDS-atomic conflicts only within a wave (~1.5/bin avg vs ~12 shared).
__global__ void __launch_bounds__(256) binA_kernel(
        const int* __restrict__ ei, const int* __restrict__ et,
        const int* __restrict__ dflag, int* __restrict__ gcur,
        int2* __restrict__ pairs) {
    __shared__ int histw[4][NB_BKT];
    __shared__ int wbase[4][NB_BKT];
    __shared__ int tot[NB_BKT];
    __shared__ int excl[NB_BKT];
    __shared__ int gbase[NB_BKT];
    __shared__ int scn[256];
    __shared__ int2 tbuf[TILE];
    int t = threadIdx.x;
    int w = t >> 6; // wave id (4 waves of 64)
    int tile0 = blockIdx.x * TILE;
    int tcount = ET - tile0;
    if (tcount > TILE) tcount = TILE;
    for (int i = t; i < 4 * NB_BKT; i += 256) ((int*)histw)[i] = 0;
    __syncthreads();
    int sft = dflag[0];
    int myk[8], mys[8];
#pragma unroll
    for (int q = 0; q < 8; q++) {
        int li = q * 256 + t;
        myk[q] = -1;
        if (li < tcount) {
            int e = tile0 + li;
            int s = ei[(size_t)e << sft];
            int d = ei[(size_t)(ET + e) << sft];
            int r = et[(size_t)e << sft];
            int key = r * NN + d;
            myk[q] = key;
            mys[q] = s;
            atomicAdd(&histw[w][key >> BKT_SH], 1);
        }
    }
    __syncthreads();
    // combine per-wave histograms -> tot, per-wave placement offsets
    for (int i = t; i < NB_BKT; i += 256) {
        int h0 = histw[0][i], h1 = histw[1][i], h2 = histw[2][i], h3 = histw[3][i];
        wbase[0][i] = 0;
        wbase[1][i] = h0;
        wbase[2][i] = h0 + h1;
        wbase[3][i] = h0 + h1 + h2;
        tot[i] = h0 + h1 + h2 + h3;
    }
    __syncthreads();
    // exclusive scan of tot over 352 bins (2 bins per thread, t<176)
    int v0 = (t < NB_BKT / 2) ? tot[2 * t] : 0;
    int v1 = (t < NB_BKT / 2) ? tot[2 * t + 1] : 0;
    int s = v0 + v1;
    scn[t] = s;
    __syncthreads();
    for (int st = 1; st < 256; st <<= 1) {
        int u = (t >= st) ? scn[t - st] : 0;
        __syncthreads();
        scn[t] += u;
        __syncthreads();
    }
    int base = scn[t] - s;
    if (t < NB_BKT / 2) {
        excl[2 * t] = base;
        excl[2 * t + 1] = base + v0;
    }
    __syncthreads();
    // finalize per-wave bases; reset histw for reuse as placement cursors
    for (int i = t; i < NB_BKT; i += 256) {
        int e0 = excl[i];
        wbase[0][i] += e0;
        wbase[1][i] += e0;
        wbase[2][i] += e0;
        wbase[3][i] += e0;
        histw[0][i] = 0; histw[1][i] = 0; histw[2][i] = 0; histw[3][i] = 0;
    }
    __syncthreads();
    // place into LDS tile buffer (bucket-contiguous; per-wave cursor)
#pragma unroll
    for (int q = 0; q < 8; q++) {
        if (myk[q] >= 0) {
            int b = myk[q] >> BKT_SH;
            int p = wbase[w][b] + atomicAdd(&histw[w][b], 1);
            tbuf[p] = make_int2(myk[q], mys[q]);
        }
    }
    __syncthreads();
    // reserve global runs
    for (int i = t; i < NB_BKT; i += 256)
        if (tot[i] > 0) gbase[i] = atomicAdd(&gcur[i], tot[i]);
    __syncthreads();
    // flush: consecutive i -> mostly consecutive global positions
    for (int i = t; i < tcount; i += 256) {
        int2 p = tbuf[i];
        int b = p.x >> BKT_SH;
        int gpos = gbase[b] + (i - excl[b]);
        int cap = (b + 1) * BKT_CAP - 1;
        pairs[gpos < cap ? gpos : cap] = p;
    }
}

// ---------------------------------------------------------------------------
// Pass B (merged hist+place): per-bucket key histogram + block-local scan ->
// off/endo/inv, then place into padded CSR. 352 blocks (512 keys each).
__global__ void __launch_bounds__(256) histplace_kernel(
        const int* __restrict__ gcur, const int2* __restrict__ pairs,
        int* __restrict__ off, int* __restrict__ endo, float* __restrict__ inv,
        int* __restrict__ csr) {
    __shared__ int kh[512];
    __shared__ int scn[256];
    int b = blockIdx.x;
    int t = threadIdx.x;
    int beg = b * BKT_CAP, end = gcur[b];
    for (int i = t; i < 512; i += 256) kh[i] = 0;
    __syncthreads();
    for (int i = beg + t; i < end; i += 256)
        atomicAdd(&kh[pairs[i].x & 511], 1);
    __syncthreads();
    int v[2];
    int s = 0;
#pragma unroll
    for (int q = 0; q < 2; q++) {
        v[q] = kh[t * 2 + q];
        s += v[q];
    }
    scn[t] = s;
    __syncthreads();
    for (int st = 1; st < 256; st <<= 1) {
        int u = (t >= st) ? scn[t - st] : 0;
        __syncthreads();
        scn[t] += u;
        __syncthreads();
    }
    int run = beg + scn[t] - s;
    int kbase = b << BKT_SH;
    int kc[2];
#pragma unroll
    for (int q = 0; q < 2; q++) {
        int key = kbase + t * 2 + q;
        if (key < TWO_NN) {
            off[key] = run;
            endo[key] = run + v[q];
            inv[key] = 1.0f / (float)(v[q] > 1 ? v[q] : 1);
        }
        kc[q] = run;
        run += v[q];
    }
    __syncthreads();
#pragma unroll
    for (int q = 0; q < 2; q++) kh[t * 2 + q] = kc[q];
    __syncthreads();
    for (int i = beg + t; i < end; i += 256) {
        int2 p = pairs[i];
        int pos = atomicAdd(&kh[p.x & 511], 1);
        csr[pos] = p.y;
    }
}

// ---------------------------------------------------------------------------
// Fused input embed (paper+mesh): writes bf16 activations only.
__global__ void __launch_bounds__(256) embed2_kernel(
        const float* __restrict__ Xp, const float* __restrict__ Xm,
        const float* __restrict__ Wp, const float* __restrict__ bp,
        const float* __restrict__ Wm, const float* __restrict__ bm,
        unsigned short* __restrict__ outbf) {
    __shared__ float Wl[4096 + 32];
    for (int i = threadIdx.x; i < 2048; i += 256) {
        Wl[i] = Wp[i];
        Wl[2048 + i] = Wm[i];
    }
    if (threadIdx.x < 16) {
        Wl[4096 + threadIdx.x] = bp[threadIdx.x];
        Wl[4112 + threadIdx.x] = bm[threadIdx.x];
    }
    __syncthreads();
    int n = blockIdx.x * 256 + threadIdx.x;
    if (n >= NN) return;
    const float* X;
    const float* Ws;
    const float* Bs;
    if (n < NP) { X = Xp + (size_t)n * 128; Ws = Wl; Bs = Wl + 4096; }
    else        { X = Xm + (size_t)(n - NP) * 128; Ws = Wl + 2048; Bs = Wl + 4112; }
    float acc[16];
#pragma unroll
    for (int j = 0; j < 16; j++) acc[j] = Bs[j];
    const float4* row = (const float4*)X;
    for (int k4 = 0; k4 < 32; k4++) {
        float4 xv = row[k4];
        int k = k4 * 4;
#pragma unroll
        for (int j = 0; j < 16; j++) {
            float a = acc[j];
            a = fmaf(xv.x, Ws[(k + 0) * 16 + j], a);
            a = fmaf(xv.y, Ws[(k + 1) * 16 + j], a);
            a = fmaf(xv.z, Ws[(k + 2) * 16 + j], a);
            a = fmaf(xv.w, Ws[(k + 3) * 16 + j], a);
            acc[j] = a;
        }
    }
    ushort4* ob = (ushort4*)(outbf + (size_t)n * 16);
#pragma unroll
    for (int q = 0; q < 4; q++) {
        ushort4 ub;
        ub.x = f2bf(acc[4 * q]);     ub.y = f2bf(acc[4 * q + 1]);
        ub.z = f2bf(acc[4 * q + 2]); ub.w = f2bf(acc[4 * q + 3]);
        ob[q] = ub;
    }
}

// ---------------------------------------------------------------------------
// All 4 layers' weight prep in ONE launch: block l handles layer l.
// Wbuf4 layout per layer (stride 3200): [W0 | W1 | root | bias]
__global__ void prep_all_kernel(
        const float* __restrict__ ba0, const float* __restrict__ co0,
        const float* __restrict__ ro0, const float* __restrict__ bi0,
        const float* __restrict__ ba1, const float* __restrict__ co1,
        const float* __restrict__ ro1, const float* __restrict__ bi1,
        const float* __restrict__ ba2, const float* __restrict__ co2,
        const float* __restrict__ ro2, const float* __restrict__ bi2,
        const float* __restrict__ ba3, const float* __restrict__ co3,
        const float* __restrict__ ro3, const float* __restrict__ bi3,
        float* __restrict__ Wbuf4) {
    int l = blockIdx.x;
    const float* bases; const float* comp; const float* root; const float* bias;
    if (l == 0)      { bases = ba0; comp = co0; root = ro0; bias = bi0; }
    else if (l == 1) { bases = ba1; comp = co1; root = ro1; bias = bi1; }
    else if (l == 2) { bases = ba2; comp = co2; root = ro2; bias = bi2; }
    else             { bases = ba3; comp = co3; root = ro3; bias = bi3; }
    int din = (l == 0) ? 16 : 32;
    int dout = (l == 3) ? 16 : 32;
    int sz = din * dout;
    float* W = Wbuf4 + l * 3200;
    for (int i = threadIdx.x; i < sz; i += 256) {
        float b0 = bases[i];
        float b1 = bases[sz + i];
        float b2 = bases[2 * sz + i];
        float b3 = bases[3 * sz + i];
        for (int r = 0; r < 2; r++) {
            W[r * sz + i] = comp[r * 4 + 0] * b0 + comp[r * 4 + 1] * b1 +
                            comp[r * 4 + 2] * b2 + comp[r * 4 + 3] * b3;
        }
        W[2 * sz + i] = root[i];
    }
    if (threadIdx.x < dout) W[3 * sz + threadIdx.x] = bias[threadIdx.x];
}

// ---------------------------------------------------------------------------
// Fused RGCN layer, bf16-only activations (R13-R15: FETCH at compulsory floor;
// bound by outstanding-miss concurrency). 16 B/lane gathers; combine from LDS.
template <int DIN, int DOUT, int RELU>
__global__ void __launch_bounds__(256) layer_kernel(
        const int* __restrict__ off, const int* __restrict__ endo,
        const int* __restrict__ csr,
        const unsigned short* __restrict__ xbf_in,
        const float* __restrict__ inv, const float* __restrict__ Wbuf,
        unsigned short* __restrict__ xbf_out) {
    constexpr int SZ = DIN * DOUT;
    constexpr int QL = DIN / 8;       // gather lanes per (node, rel): 16 B each
    constexpr int TPN = 2 * QL;       // phase-1 threads per node
    constexpr int NPB = 256 / TPN;    // nodes per block
    constexpr int AGST = 2 * DIN + 4; // agg LDS row stride
    constexpr int XSST = DIN + 4;     // xs LDS row stride
    __shared__ float Wl[3 * SZ + DOUT];
    __shared__ float agg[NPB * AGST];
    __shared__ float xs[NPB * XSST];
    for (int i = threadIdx.x; i < 3 * SZ + DOUT; i += 256) Wl[i] = Wbuf[i];
    int t = threadIdx.x;
    int ln = t / TPN;
    int rl = t % TPN;
    int r = rl / QL;
    int lane = rl % QL;
    int d = blockIdx.x * NPB + ln;
    if (d < NN) {
        if (r == 0) {
            uint4 u = *(const uint4*)(xbf_in + (size_t)d * DIN + lane * 8);
            float* xp = xs + ln * XSST + lane * 8;
            xp[0] = bflo(u.x); xp[1] = bfhi(u.x);
            xp[2] = bflo(u.y); xp[3] = bfhi(u.y);
            xp[4] = bflo(u.z); xp[5] = bfhi(u.z);
            xp[6] = bflo(u.w); xp[7] = bfhi(u.w);
        }
        int key = r * NN + d;
        int b = off[key];
        int e = endo[key];
        float a0[8] = {0, 0, 0, 0, 0, 0, 0, 0};
        float a1[8] = {0, 0, 0, 0, 0, 0, 0, 0};
        const unsigned short* hp = xbf_in + lane * 8;
        int k = b;
        for (; k + 1 < e; k += 2) {
            int s0 = csr[k];
            int s1 = csr[k + 1];
            uint4 u0 = *(const uint4*)(hp + (size_t)s0 * DIN);
            uint4 u1 = *(const uint4*)(hp + (size_t)s1 * DIN);
            a0[0] += bflo(u0.x); a0[1] += bfhi(u0.x);
            a0[2] += bflo(u0.y); a0[3] += bfhi(u0.y);
            a0[4] += bflo(u0.z); a0[5] += bfhi(u0.z);
            a0[6] += bflo(u0.w); a0[7] += bfhi(u0.w);
            a1[0] += bflo(u1.x); a1[1] += bfhi(u1.x);
            a1[2] += bflo(u1.y); a1[3] += bfhi(u1.y);
            a1[4] += bflo(u1.z); a1[5] += bfhi(u1.z);
            a1[6] += bflo(u1.w); a1[7] += bfhi(u1.w);
        }
        if (k < e) {
            uint4 u0 = *(const uint4*)(hp + (size_t)csr[k] * DIN);
            a0[0] += bflo(u0.x); a0[1] += bfhi(u0.x);
            a0[2] += bflo(u0.y); a0[3] += bfhi(u0.y);
            a0[4] += bflo(u0.z); a0[5] += bfhi(u0.z);
            a0[6] += bflo(u0.w); a0[7] += bfhi(u0.w);
        }
        float* ap = agg + ln * AGST + r * DIN + lane * 8;
        *(float4*)ap = make_float4(a0[0] + a1[0], a0[1] + a1[1],
                                   a0[2] + a1[2], a0[3] + a1[3]);
        *(float4*)(ap + 4) = make_float4(a0[4] + a1[4], a0[5] + a1[5],
                                         a0[6] + a1[6], a0[7] + a1[7]);
    }
    __syncthreads();
    constexpr int CPN = DOUT / 4;
    for (int tt = t; tt < NPB * CPN; tt += 256) {
        int ln2 = tt / CPN;
        int j0 = (tt % CPN) * 4;
        int d2 = blockIdx.x * NPB + ln2;
        if (d2 < NN) {
            float iv0 = inv[d2], iv1 = inv[NN + d2];
            float acc[4];
#pragma unroll
            for (int jj = 0; jj < 4; jj++) acc[jj] = Wl[3 * SZ + j0 + jj];
#pragma unroll
            for (int k = 0; k < DIN; k++) {
                float xv = xs[ln2 * XSST + k];
                float m0 = agg[ln2 * AGST + k] * iv0;
                float m1 = agg[ln2 * AGST + DIN + k] * iv1;
                const float* w0 = &Wl[k * DOUT + j0];
                const float* w1 = &Wl[SZ + k * DOUT + j0];
                const float* wr = &Wl[2 * SZ + k * DOUT + j0];
#pragma unroll
                for (int jj = 0; jj < 4; jj++) {
                    acc[jj] = fmaf(xv, wr[jj], acc[jj]);
                    acc[jj] = fmaf(m0, w0[jj], acc[jj]);
                    acc[jj] = fmaf(m1, w1[jj], acc[jj]);
                }
            }
            if (RELU) {
#pragma unroll
                for (int jj = 0; jj < 4; jj++) acc[jj] = fmaxf(acc[jj], 0.0f);
            }
            ushort4 ub;
            ub.x = f2bf(acc[0]); ub.y = f2bf(acc[1]);
            ub.z = f2bf(acc[2]); ub.w = f2bf(acc[3]);
            *(ushort4*)(xbf_out + (size_t)d2 * DOUT + j0) = ub;
        }
    }
}

// ---------------------------------------------------------------------------
// Fused decode on bf16 z: out[i] = dot( z[s]@Wd_r + bd_r , z[d] ).
__global__ void __launch_bounds__(256) decode_fused_kernel(
        const unsigned short* __restrict__ zbf,
        const float* __restrict__ Wd0, const float* __restrict__ bd0,
        const float* __restrict__ Wd1, const float* __restrict__ bd1,
        const int* __restrict__ pei, const int* __restrict__ pet,
        const int* __restrict__ nei, const int* __restrict__ net_,
        float* __restrict__ out, const int* __restrict__ dflag) {
    __shared__ float W[2][256];
    __shared__ float B[2][16];
    for (int i = threadIdx.x; i < 256; i += 256) {
        W[0][i] = Wd0[i];
        W[1][i] = Wd1[i];
    }
    if (threadIdx.x < 16) {
        B[0][threadIdx.x] = bd0[threadIdx.x];
        B[1][threadIdx.x] = bd1[threadIdx.x];
    }
    __syncthreads();
    int i = blockIdx.x * 256 + threadIdx.x;
    if (i >= 2 * ED) return;
    int sft = dflag[0];
    const int* ei;
    const int* et;
    int e;
    if (i < ED) { ei = pei; et = pet; e = i; }
    else        { ei = nei; et = net_; e = i - ED; }
    int s = ei[(size_t)e << sft];
    int d = ei[(size_t)(ED + e) << sft];
    int r = et[(size_t)e << sft];
    float zs[16], zd[16];
    const uint4* sp = (const uint4*)(zbf + ((size_t)s << 4));
    const uint4* dp = (const uint4*)(zbf + ((size_t)d << 4));
#pragma unroll
    for (int h = 0; h < 2; h++) {
        uint4 us = sp[h];
        uint4 ud = dp[h];
        int o8 = h * 8;
        zs[o8 + 0] = bflo(us.x); zs[o8 + 1] = bfhi(us.x);
        zs[o8 + 2] = bflo(us.y); zs[o8 + 3] = bfhi(us.y);
        zs[o8 + 4] = bflo(us.z); zs[o8 + 5] = bfhi(us.z);
        zs[o8 + 6] = bflo(us.w); zs[o8 + 7] = bfhi(us.w);
        zd[o8 + 0] = bflo(ud.x); zd[o8 + 1] = bfhi(ud.x);
        zd[o8 + 2] = bflo(ud.y); zd[o8 + 3] = bfhi(ud.y);
        zd[o8 + 4] = bflo(ud.z); zd[o8 + 5] = bfhi(ud.z);
        zd[o8 + 6] = bflo(ud.w); zd[o8 + 7] = bfhi(ud.w);
    }
    const float* Wr = W[r];
    const float* Br = B[r];
    float acc = 0.0f;
#pragma unroll
    for (int j = 0; j < 16; j++) {
        float yj = Br[j];
#pragma unroll
        for (int k = 0; k < 16; k++) yj = fmaf(zs[k], Wr[k * 16 + j], yj);
        acc = fmaf(yj, zd[j], acc);
    }
    out[i] = acc;
}

// ---------------------------------------------------------------------------
extern "C" void kernel_launch(void* const* d_in, const int* in_sizes, int n_in,
                              void* d_out, int out_size, void* d_ws, size_t ws_size,
                              hipStream_t stream) {
    const float* x_paper = (const float*)d_in[0];
    const float* x_mesh  = (const float*)d_in[1];
    const int* tei  = (const int*)d_in[2];
    const int* tet  = (const int*)d_in[3];
    const int* pei  = (const int*)d_in[4];
    const int* pet  = (const int*)d_in[5];
    const int* nei  = (const int*)d_in[6];
    const int* net_ = (const int*)d_in[7];
    const float* Wp  = (const float*)d_in[8];
    const float* bp  = (const float*)d_in[9];
    const float* Wm  = (const float*)d_in[10];
    const float* bm  = (const float*)d_in[11];
    const float* Wd0 = (const float*)d_in[12];
    const float* bd0 = (const float*)d_in[13];
    const float* Wd1 = (const float*)d_in[14];
    const float* bd1 = (const float*)d_in[15];

    // Workspace carve-up (fp32/int32 elements) — ~42 MB total
    float* ws = (float*)d_ws;
    size_t o = 0;
    unsigned short* xbfA = (unsigned short*)(ws + o); o += (size_t)NN * 16;
    unsigned short* xbfB = (unsigned short*)(ws + o); o += (size_t)NN * 16;
    float* inv  = ws + o; o += (size_t)TWO_NN;
    int*   off  = (int*)(ws + o); o += (size_t)TWO_NN;
    int*   endo = (int*)(ws + o); o += (size_t)TWO_NN;
    int*   csr  = (int*)(ws + o); o += (size_t)NB_BKT * BKT_CAP; // padded (9 MB)
    int*   gcur = (int*)(ws + o); o += 512;
    int2*  pairs = (int2*)(ws + o); o += (size_t)2 * NB_BKT * BKT_CAP; // 18 MB
    float* Wbuf4 = ws + o; o += 4 * 3200;
    int*   dflag = (int*)(ws + o); o += 16;

    // 0. Init (gcur + dtype flag)
    init_kernel<<<(NB_BKT + 255) / 256, 256, 0, stream>>>(tei, gcur, dflag);

    // 1. Binned padded-bucket CSR build (once)
    binA_kernel<<<N_TILES, 256, 0, stream>>>(tei, tet, dflag, gcur, pairs);
    histplace_kernel<<<NB_BKT, 256, 0, stream>>>(gcur, pairs, off, endo, inv, csr);

    // 2. Fused embed -> xbfA (bf16 only)
    embed2_kernel<<<(NN + 255) / 256, 256, 0, stream>>>(
        x_paper, x_mesh, Wp, bp, Wm, bm, xbfA);

    // 3. All layer weights in one launch
    prep_all_kernel<<<4, 256, 0, stream>>>(
        (const float*)d_in[16], (const float*)d_in[17], (const float*)d_in[18], (const float*)d_in[19],
        (const float*)d_in[20], (const float*)d_in[21], (const float*)d_in[22], (const float*)d_in[23],
        (const float*)d_in[24], (const float*)d_in[25], (const float*)d_in[26], (const float*)d_in[27],
        (const float*)d_in[28], (const float*)d_in[29], (const float*)d_in[30], (const float*)d_in[31],
        Wbuf4);

    // 4. Four fused RGCN layers, bf16 activations throughout
    int blk16 = (NN + 63) / 64; // DIN=16: NPB=64
    int blk32 = (NN + 31) / 32; // DIN=32: NPB=32
    layer_kernel<16, 32, 1><<<blk16, 256, 0, stream>>>(
        off, endo, csr, xbfA, inv, Wbuf4 + 0 * 3200, xbfB);
    layer_kernel<32, 32, 1><<<blk32, 256, 0, stream>>>(
        off, endo, csr, xbfB, inv, Wbuf4 + 1 * 3200, xbfA);
    layer_kernel<32, 32, 1><<<blk32, 256, 0, stream>>>(
        off, endo, csr, xbfA, inv, Wbuf4 + 2 * 3200, xbfB);
    layer_kernel<32, 16, 0><<<blk32, 256, 0, stream>>>(
        off, endo, csr, xbfB, inv, Wbuf4 + 3 * 3200, xbfA);
    // z (bf16) = xbfA [NN,16]

    // 5. Fused decode on bf16 z
    decode_fused_kernel<<<(2 * ED + 255) / 256, 256, 0, stream>>>(
        xbfA, Wd0, bd0, Wd1, bd1, pei, pet, nei, net_, (float*)d_out, dflag);
}